// Round 1
// baseline (3352.694 us; speedup 1.0000x reference)
//
#include <hip/hip_runtime.h>
#include <math.h>

namespace {

constexpr int B  = 2, S = 2048, NH = 16, HD = 64, HID = 1024;
constexpr int BH = B * NH;          // 32
constexpr int NSTEP = 16;           // 128-row scan blocks

// ws layout in floats. qkv region (12.58M floats) is reused for MinvT + A.
constexpr size_t OFF_QKV  = 0;
constexpr size_t OFF_MINV = 0;                 // [BH][32][64][64] = 4,194,304
constexpr size_t OFF_A    = 4194304;           // [BH][S][HD]      = 4,194,304
constexpr size_t OFF_Q    = 12582912;          // [BH][S][HD]
constexpr size_t OFF_K    = 16777216;
constexpr size_t OFF_V    = 20971520;
constexpr size_t OFF_M    = 25165824;          // [BH*S]
constexpr size_t OFF_ZI   = 25231360;
constexpr size_t OFF_PD   = 25296896;
constexpr size_t OFF_UP   = 25362432;          // [BH][15][128][64]
constexpr size_t WS_FLOATS = 29294592;         // ~117 MB

// ---------------------------------------------------------------------------
// NT GEMM: C[M][N] = A[M][K] @ B[N][K]^T + bias.  GATHER=1 gathers A rows from
// the [BH][S][HD] attention-output layout (k index = h*64+d).
// ---------------------------------------------------------------------------
template<int GATHER>
__global__ __launch_bounds__(256) void gemm_nt(
    const float* __restrict__ Am, const float* __restrict__ Bm,
    const float* __restrict__ bias, float* __restrict__ C,
    int M, int N, int K) {
  __shared__ float as[16][128];
  __shared__ float bs[16][128];
  const int t  = threadIdx.x;
  const int m0 = blockIdx.y * 128, n0 = blockIdx.x * 128;
  const int tm = (t & 15) * 8, tn = (t >> 4) * 8;
  float acc[8][8];
#pragma unroll
  for (int i = 0; i < 8; ++i)
#pragma unroll
    for (int j = 0; j < 8; ++j) acc[i][j] = 0.f;

  for (int kb = 0; kb < K; kb += 16) {
#pragma unroll
    for (int v = 0; v < 2; ++v) {
      const int idx = t + v * 256;           // 0..511 float4 slots
      const int row = idx >> 2, kq = idx & 3;
      const float* srcA;
      if (GATHER) {
        const int m = m0 + row;
        const int b = m >> 11, ss = m & (S - 1);
        const int kk = kb + kq * 4;
        const int h = kk >> 6, d = kk & 63;
        srcA = Am + (((size_t)(b * NH + h) * S + ss) << 6) + d;
      } else {
        srcA = Am + (size_t)(m0 + row) * K + kb + kq * 4;
      }
      const float4 f = *(const float4*)srcA;
      as[kq*4+0][row] = f.x; as[kq*4+1][row] = f.y;
      as[kq*4+2][row] = f.z; as[kq*4+3][row] = f.w;
      const float4 g = *(const float4*)(Bm + (size_t)(n0 + row) * K + kb + kq * 4);
      bs[kq*4+0][row] = g.x; bs[kq*4+1][row] = g.y;
      bs[kq*4+2][row] = g.z; bs[kq*4+3][row] = g.w;
    }
    __syncthreads();
#pragma unroll
    for (int kk = 0; kk < 16; ++kk) {
      const float4 a0 = *(const float4*)&as[kk][tm];
      const float4 a1 = *(const float4*)&as[kk][tm + 4];
      const float4 b0 = *(const float4*)&bs[kk][tn];
      const float4 b1 = *(const float4*)&bs[kk][tn + 4];
      const float av[8] = {a0.x, a0.y, a0.z, a0.w, a1.x, a1.y, a1.z, a1.w};
      const float bv[8] = {b0.x, b0.y, b0.z, b0.w, b1.x, b1.y, b1.z, b1.w};
#pragma unroll
      for (int i = 0; i < 8; ++i)
#pragma unroll
        for (int j = 0; j < 8; ++j) acc[i][j] += av[i] * bv[j];
    }
    __syncthreads();
  }
#pragma unroll
  for (int i = 0; i < 8; ++i) {
    float* dst = C + (size_t)(m0 + tm + i) * N + n0 + tn;
#pragma unroll
    for (int j = 0; j < 8; j += 4) {
      float4 o;
      o.x = acc[i][j+0] + bias[n0+tn+j+0];
      o.y = acc[i][j+1] + bias[n0+tn+j+1];
      o.z = acc[i][j+2] + bias[n0+tn+j+2];
      o.w = acc[i][j+3] + bias[n0+tn+j+3];
      *(float4*)(dst + j) = o;
    }
  }
}

// ---------------------------------------------------------------------------
// RoPE + transpose [b][s][3][h][d] -> Q/K/V [bh][s][d].  Q pre-scaled by 1/8.
// ---------------------------------------------------------------------------
__global__ __launch_bounds__(256) void k2_rope(
    const float* __restrict__ qkv, float* __restrict__ Q,
    float* __restrict__ Kb, float* __restrict__ V) {
  const int g  = blockIdx.x * 256 + threadIdx.x;   // (bh, s)
  const int s  = g & (S - 1);
  const int bh = g >> 11;
  const int b  = bh >> 4, h = bh & 15;
  const float* base = qkv + ((size_t)b * S + s) * 3072 + h * 64;
  float q[64], k[64], v[64];
#pragma unroll
  for (int f = 0; f < 16; ++f) {
    const float4 x = *(const float4*)(base + f * 4);
    q[f*4+0]=x.x; q[f*4+1]=x.y; q[f*4+2]=x.z; q[f*4+3]=x.w;
    const float4 y = *(const float4*)(base + 1024 + f * 4);
    k[f*4+0]=y.x; k[f*4+1]=y.y; k[f*4+2]=y.z; k[f*4+3]=y.w;
    const float4 z = *(const float4*)(base + 2048 + f * 4);
    v[f*4+0]=z.x; v[f*4+1]=z.y; v[f*4+2]=z.z; v[f*4+3]=z.w;
  }
  // 10000^{j/8} = 10^{j/2}, correctly-rounded fp32 (matches numpy fp32 table)
  const float PW[8] = {1.0f, 3.1622776601683795f, 10.0f, 31.622776601683793f,
                       100.0f, 316.22776601683796f, 1000.0f, 3162.2776601683795f};
  float qr[16], kr[16];
#pragma unroll
  for (int d = 0; d < 16; ++d) {
    const int j = d & 7;
    const float invf = 1.0f / PW[j];
    const float fr = (float)s * invf;
    float sn, c;
    sincosf(fr, &sn, &c);
    const float rq = (d < 8) ? -q[d + 8] : q[d - 8];
    const float rk = (d < 8) ? -k[d + 8] : k[d - 8];
    qr[d] = q[d] * c + rq * sn;
    kr[d] = k[d] * c + rk * sn;
  }
#pragma unroll
  for (int d = 0; d < 16; ++d) { q[d] = qr[d]; k[d] = kr[d]; }
#pragma unroll
  for (int d = 0; d < 64; ++d) q[d] *= 0.125f;   // fold softmax scale into Q
  float* qd = Q  + (((size_t)bh * S + s) << 6);
  float* kd = Kb + (((size_t)bh * S + s) << 6);
  float* vd = V  + (((size_t)bh * S + s) << 6);
#pragma unroll
  for (int f = 0; f < 16; ++f) {
    *(float4*)(qd + f*4) = make_float4(q[f*4], q[f*4+1], q[f*4+2], q[f*4+3]);
    *(float4*)(kd + f*4) = make_float4(k[f*4], k[f*4+1], k[f*4+2], k[f*4+3]);
    *(float4*)(vd + f*4) = make_float4(v[f*4], v[f*4+1], v[f*4+2], v[f*4+3]);
  }
}

// ---------------------------------------------------------------------------
// Row softmax stats: m (row max), 1/Z, and diag prob P_ii. 64 rows/WG.
// ---------------------------------------------------------------------------
__global__ __launch_bounds__(256) void k3_stats(
    const float* __restrict__ Q, const float* __restrict__ Kb,
    float* __restrict__ mrow, float* __restrict__ zinv, float* __restrict__ pd) {
  const int bh = blockIdx.y;
  const int bx = blockIdx.x;
  const int r0 = bx * 64;
  __shared__ float qs[64][68];
  __shared__ float ks[64][68];
  const int t = threadIdx.x;
  const int row = t >> 2, c4 = t & 3;
  for (int v4 = t; v4 < 1024; v4 += 256) {
    const int r = v4 >> 4, f = v4 & 15;
    const float4 x = *(const float4*)(Q + (((size_t)bh * S + r0 + r) << 6) + f * 4);
    *(float4*)&qs[r][f*4] = x;
  }
  float m = -1e30f, Z = 0.f, sdiag = 0.f;
  for (int cb = 0; cb <= bx; ++cb) {
    __syncthreads();
    for (int v4 = t; v4 < 1024; v4 += 256) {
      const int r = v4 >> 4, f = v4 & 15;
      const float4 x = *(const float4*)(Kb + (((size_t)bh * S + cb * 64 + r) << 6) + f * 4);
      *(float4*)&ks[r][f*4] = x;
    }
    __syncthreads();
    const int cmax = (cb == bx) ? (row + 1) : 64;
    for (int cc = c4; cc < cmax; cc += 4) {
      float sdot = 0.f;
#pragma unroll
      for (int i4 = 0; i4 < 16; ++i4) {
        const float4 qv = *(const float4*)&qs[row][i4*4];
        const float4 kv = *(const float4*)&ks[cc][i4*4];
        sdot += qv.x*kv.x + qv.y*kv.y + qv.z*kv.z + qv.w*kv.w;
      }
      if (cb == bx && cc == row) sdiag = sdot;
      const float mn = fmaxf(m, sdot);
      Z = Z * __expf(m - mn) + __expf(sdot - mn);
      m = mn;
    }
  }
#pragma unroll
  for (int off = 1; off < 4; off <<= 1) {
    const float mo = __shfl_xor(m, off, 64);
    const float Zo = __shfl_xor(Z, off, 64);
    const float mn = fmaxf(m, mo);
    Z = Z * __expf(m - mn) + Zo * __expf(mo - mn);
    m = mn;
  }
  const int R = bh * S + r0 + row;
  if (c4 == (row & 3)) pd[R] = __expf(sdiag - m) / Z;
  if (c4 == 0) { mrow[R] = m; zinv[R] = 1.f / Z; }
}

// ---------------------------------------------------------------------------
// Per-64-block unit-lower-triangular inverse of (I - N), N = strict-lower P.
// Output TRANSPOSED: MinvT[bh][ib][j][r] = Minv[r][j]  (for conflict-free use).
// One wave per block; thread c owns column c.
// ---------------------------------------------------------------------------
__global__ __launch_bounds__(64) void k4_minv(
    const float* __restrict__ Q, const float* __restrict__ Kb,
    const float* __restrict__ mrow, const float* __restrict__ zinv,
    float* __restrict__ MinvT) {
  const int bh = blockIdx.y, ib = blockIdx.x;
  const int r0 = ib * 64;
  __shared__ float qs[64][64];
  __shared__ float Nb[64][64];
  __shared__ float X[64][64];
  const int c = threadIdx.x;
  float kc[64];
#pragma unroll
  for (int f = 0; f < 16; ++f) {
    const float4 x = *(const float4*)(Kb + (((size_t)bh * S + r0 + c) << 6) + f * 4);
    kc[f*4+0]=x.x; kc[f*4+1]=x.y; kc[f*4+2]=x.z; kc[f*4+3]=x.w;
  }
  for (int v4 = c; v4 < 1024; v4 += 64) {
    const int r = v4 >> 4, f = v4 & 15;
    *(float4*)&qs[r][f*4] = *(const float4*)(Q + (((size_t)bh * S + r0 + r) << 6) + f * 4);
  }
  __syncthreads();
  for (int r = 0; r < 64; ++r) {
    float sdot = 0.f;
#pragma unroll
    for (int i4 = 0; i4 < 16; ++i4) {
      const float4 qv = *(const float4*)&qs[r][i4*4];
      sdot += qv.x*kc[i4*4] + qv.y*kc[i4*4+1] + qv.z*kc[i4*4+2] + qv.w*kc[i4*4+3];
    }
    const int R = bh * S + r0 + r;
    Nb[r][c] = (c < r) ? __expf(sdot - mrow[R]) * zinv[R] : 0.f;
  }
  __syncthreads();
  for (int r = 0; r < 64; ++r) X[r][c] = (r == c) ? 1.f : 0.f;
  __syncthreads();
  for (int r = 1; r < 64; ++r) {         // forward substitution, X = (I-N)^-1
    float a = 0.f;
    for (int j = 0; j < r; ++j) a += Nb[r][j] * X[j][c];
    X[r][c] += a;
    __syncthreads();
  }
  float* dst = MinvT + (((size_t)bh * 32 + ib) * 64 + c) * 64;
  for (int r4 = 0; r4 < 64; r4 += 4) {
    float4 o; o.x = X[r4][c]; o.y = X[r4+1][c]; o.z = X[r4+2][c]; o.w = X[r4+3][c];
    *(float4*)(dst + r4) = o;
  }
}

// ---------------------------------------------------------------------------
// Scan step k, off-diagonal accumulate: upart[bh][j] = P[k-rows, j-block] @ A_j
// Grid: (j < k, bh). Thread = (row, 32-d half).
// ---------------------------------------------------------------------------
__global__ __launch_bounds__(256) void k5_acc(
    const float* __restrict__ Q, const float* __restrict__ Kb,
    const float* __restrict__ Abuf, const float* __restrict__ mrow,
    const float* __restrict__ zinv, float* __restrict__ upart, int kstep) {
  const int bh = blockIdx.y, j = blockIdx.x;
  __shared__ float ks[128][64];
  __shared__ float as[128][64];
  const int t = threadIdx.x;
  const int r = t >> 1, dq = (t & 1) * 32;
  const int R = kstep * 128 + r;
  for (int v4 = t; v4 < 2048; v4 += 256) {
    const int rr = v4 >> 4, f = v4 & 15;
    *(float4*)&ks[rr][f*4] = *(const float4*)(Kb   + (((size_t)bh * S + j*128 + rr) << 6) + f * 4);
    *(float4*)&as[rr][f*4] = *(const float4*)(Abuf + (((size_t)bh * S + j*128 + rr) << 6) + f * 4);
  }
  float q[64];
#pragma unroll
  for (int f = 0; f < 16; ++f) {
    const float4 x = *(const float4*)(Q + (((size_t)bh * S + R) << 6) + f * 4);
    q[f*4+0]=x.x; q[f*4+1]=x.y; q[f*4+2]=x.z; q[f*4+3]=x.w;
  }
  const float m = mrow[bh * S + R], zi = zinv[bh * S + R];
  float acc[32];
#pragma unroll
  for (int i = 0; i < 32; ++i) acc[i] = 0.f;
  __syncthreads();
  for (int cc = 0; cc < 128; ++cc) {
    float sdot = 0.f;
#pragma unroll
    for (int i4 = 0; i4 < 16; ++i4) {
      const float4 kv = *(const float4*)&ks[cc][i4*4];
      sdot += q[i4*4]*kv.x + q[i4*4+1]*kv.y + q[i4*4+2]*kv.z + q[i4*4+3]*kv.w;
    }
    const float p = __expf(sdot - m) * zi;
#pragma unroll
    for (int i4 = 0; i4 < 8; ++i4) {
      const float4 av = *(const float4*)&as[cc][dq + i4*4];
      acc[i4*4+0] += p * av.x; acc[i4*4+1] += p * av.y;
      acc[i4*4+2] += p * av.z; acc[i4*4+3] += p * av.w;
    }
  }
  float* dst = upart + ((((size_t)bh * 15 + j) * 128 + r) << 6) + dq;
#pragma unroll
  for (int i = 0; i < 32; i += 4)
    *(float4*)(dst + i) = make_float4(acc[i], acc[i+1], acc[i+2], acc[i+3]);
}

// ---------------------------------------------------------------------------
// Scan step k finalize: u = pd*v + sum(upart); A_lo = Minv@u_lo;
// u_hi += P(hi,lo)@A_lo; A_hi = Minv@u_hi.  One WG per bh.
// ---------------------------------------------------------------------------
__global__ __launch_bounds__(256) void k5_fin(
    const float* __restrict__ Q, const float* __restrict__ Kb,
    const float* __restrict__ V, const float* __restrict__ pd,
    const float* __restrict__ mrow, const float* __restrict__ zinv,
    const float* __restrict__ upart, const float* __restrict__ MinvT,
    float* __restrict__ Abuf, int kstep) {
  const int bh = blockIdx.x;
  __shared__ float u[128][65];     // padded: phase-2 RMW is 2-way (free)
  __shared__ float mvT[64][64];    // MinvT block; reused as K-staging
  const int t = threadIdx.x;
  const int base = kstep * 128;

  // phase 0: u = pd*v + sum of partials
  for (int v4 = t; v4 < 2048; v4 += 256) {
    const int r = v4 >> 4, f = v4 & 15;
    const int R = base + r;
    const float4 x = *(const float4*)(V + (((size_t)bh * S + R) << 6) + f * 4);
    const float p = pd[bh * S + R];
    float a0 = p * x.x, a1 = p * x.y, a2 = p * x.z, a3 = p * x.w;
    for (int j = 0; j < kstep; ++j) {
      const float4 y = *(const float4*)(upart + ((((size_t)bh * 15 + j) * 128 + r) << 6) + f * 4);
      a0 += y.x; a1 += y.y; a2 += y.z; a3 += y.w;
    }
    u[r][f*4+0] = a0; u[r][f*4+1] = a1; u[r][f*4+2] = a2; u[r][f*4+3] = a3;
  }
  for (int v4 = t; v4 < 1024; v4 += 256) {
    const int j = v4 >> 4, f = v4 & 15;
    *(float4*)&mvT[j][f*4] =
      *(const float4*)(MinvT + ((((size_t)bh * 32 + kstep*2) * 64 + j) << 6) + f * 4);
  }
  __syncthreads();
  // phase 1: A_lo[r][d] = sum_j Minv[r][j] * u[j][d]; write to global
  {
    const int r = t & 63, d0 = (t >> 6) * 16;
    float acc[16];
#pragma unroll
    for (int i = 0; i < 16; ++i) acc[i] = 0.f;
    for (int j = 0; j < 64; ++j) {
      const float w = mvT[j][r];
#pragma unroll
      for (int i = 0; i < 16; ++i) acc[i] += w * u[j][d0 + i];
    }
    float* dst = Abuf + (((size_t)bh * S + base + r) << 6) + d0;
#pragma unroll
    for (int i = 0; i < 16; i += 4)
      *(float4*)(dst + i) = make_float4(acc[i], acc[i+1], acc[i+2], acc[i+3]);
  }
  __threadfence();   // make A_lo global writes visible for phase 2 reads
  __syncthreads();
  for (int v4 = t; v4 < 1024; v4 += 256) {   // stage K rows base..base+63
    const int j = v4 >> 4, f = v4 & 15;
    *(float4*)&mvT[j][f*4] =
      *(const float4*)(Kb + (((size_t)bh * S + base + j) << 6) + f * 4);
  }
  __syncthreads();
  // phase 2: u_hi += P(hi,lo) @ A_lo (A_lo read back from global)
  {
    const int rp = t >> 2, dq = (t & 3) * 16;
    const int R = base + 64 + rp;
    float q[64];
#pragma unroll
    for (int f = 0; f < 16; ++f) {
      const float4 x = *(const float4*)(Q + (((size_t)bh * S + R) << 6) + f * 4);
      q[f*4+0]=x.x; q[f*4+1]=x.y; q[f*4+2]=x.z; q[f*4+3]=x.w;
    }
    const float m = mrow[bh * S + R], zi = zinv[bh * S + R];
    float acc[16];
#pragma unroll
    for (int i = 0; i < 16; ++i) acc[i] = 0.f;
    for (int j = 0; j < 64; ++j) {
      float sdot = 0.f;
#pragma unroll
      for (int i4 = 0; i4 < 16; ++i4) {
        const float4 kv = *(const float4*)&mvT[j][i4*4];
        sdot += q[i4*4]*kv.x + q[i4*4+1]*kv.y + q[i4*4+2]*kv.z + q[i4*4+3]*kv.w;
      }
      const float p = __expf(sdot - m) * zi;
      const float4 a0 = *(const float4*)(Abuf + (((size_t)bh * S + base + j) << 6) + dq);
      const float4 a1 = *(const float4*)(Abuf + (((size_t)bh * S + base + j) << 6) + dq + 4);
      const float4 a2 = *(const float4*)(Abuf + (((size_t)bh * S + base + j) << 6) + dq + 8);
      const float4 a3 = *(const float4*)(Abuf + (((size_t)bh * S + base + j) << 6) + dq + 12);
      acc[0] += p*a0.x; acc[1] += p*a0.y; acc[2]  += p*a0.z; acc[3]  += p*a0.w;
      acc[4] += p*a1.x; acc[5] += p*a1.y; acc[6]  += p*a1.z; acc[7]  += p*a1.w;
      acc[8] += p*a2.x; acc[9] += p*a2.y; acc[10] += p*a2.z; acc[11] += p*a2.w;
      acc[12]+= p*a3.x; acc[13]+= p*a3.y; acc[14] += p*a3.z; acc[15] += p*a3.w;
    }
#pragma unroll
    for (int i = 0; i < 16; ++i) u[64 + rp][dq + i] += acc[i];
  }
  __syncthreads();
  for (int v4 = t; v4 < 1024; v4 += 256) {   // stage MinvT block 2k+1
    const int j = v4 >> 4, f = v4 & 15;
    *(float4*)&mvT[j][f*4] =
      *(const float4*)(MinvT + ((((size_t)bh * 32 + kstep*2 + 1) * 64 + j) << 6) + f * 4);
  }
  __syncthreads();
  // phase 3: A_hi = Minv @ u_hi
  {
    const int r = t & 63, d0 = (t >> 6) * 16;
    float acc[16];
#pragma unroll
    for (int i = 0; i < 16; ++i) acc[i] = 0.f;
    for (int j = 0; j < 64; ++j) {
      const float w = mvT[j][r];
#pragma unroll
      for (int i = 0; i < 16; ++i) acc[i] += w * u[64 + j][d0 + i];
    }
    float* dst = Abuf + (((size_t)bh * S + base + 64 + r) << 6) + d0;
#pragma unroll
    for (int i = 0; i < 16; i += 4)
      *(float4*)(dst + i) = make_float4(acc[i], acc[i+1], acc[i+2], acc[i+3]);
  }
}

} // namespace

extern "C" void kernel_launch(void* const* d_in, const int* in_sizes, int n_in,
                              void* d_out, int out_size, void* d_ws, size_t ws_size,
                              hipStream_t stream) {
  const float* hs   = (const float*)d_in[0];
  const float* Wqkv = (const float*)d_in[1];
  const float* bqkv = (const float*)d_in[2];
  const float* Wd   = (const float*)d_in[3];
  const float* bd   = (const float*)d_in[4];
  float* out = (float*)d_out;
  float* W   = (float*)d_ws;
  if (ws_size < WS_FLOATS * sizeof(float)) return;  // insufficient scratch

  float* qkv   = W + OFF_QKV;
  float* MinvT = W + OFF_MINV;
  float* Abuf  = W + OFF_A;
  float* Qb    = W + OFF_Q;
  float* Kbuf  = W + OFF_K;
  float* Vb    = W + OFF_V;
  float* mrow  = W + OFF_M;
  float* zi    = W + OFF_ZI;
  float* pdg   = W + OFF_PD;
  float* up    = W + OFF_UP;

  gemm_nt<0><<<dim3(24, 32), 256, 0, stream>>>(hs, Wqkv, bqkv, qkv, B*S, 3*HID, HID);
  k2_rope<<<dim3(BH * S / 256), 256, 0, stream>>>(qkv, Qb, Kbuf, Vb);
  k3_stats<<<dim3(S / 64, BH), 256, 0, stream>>>(Qb, Kbuf, mrow, zi, pdg);
  k4_minv<<<dim3(S / 64, BH), 64, 0, stream>>>(Qb, Kbuf, mrow, zi, MinvT);
  for (int k = 0; k < NSTEP; ++k) {
    if (k > 0)
      k5_acc<<<dim3(k, BH), 256, 0, stream>>>(Qb, Kbuf, Abuf, mrow, zi, up, k);
    k5_fin<<<dim3(BH), 256, 0, stream>>>(Qb, Kbuf, Vb, pdg, mrow, zi, up, MinvT, Abuf, k);
  }
  gemm_nt<1><<<dim3(8, 32), 256, 0, stream>>>(Abuf, Wd, bd, out, B*S, HID, HID);
}

// Round 2
// 2216.278 us; speedup vs baseline: 1.5128x; 1.5128x over previous
//
#include <hip/hip_runtime.h>
#include <math.h>

namespace {

constexpr int B  = 2, S = 2048, NH = 16, HD = 64, HID = 1024;
constexpr int BH = B * NH;          // 32
constexpr int NSTEP = 16;           // 128-row scan blocks

// ws layout in floats. qkv region (12.58M floats) is reused for partZ/MinvT + A.
constexpr size_t OFF_QKV  = 0;
constexpr size_t OFF_PART = 0;                 // [BH][32][8][64]  = 524,288 (stats partials)
constexpr size_t OFF_MINV = 0;                 // [BH][32][64][64] = 4,194,304
constexpr size_t OFF_A    = 4194304;           // [BH][S][HD]      = 4,194,304
constexpr size_t OFF_Q    = 12582912;          // [BH][S][HD]
constexpr size_t OFF_K    = 16777216;
constexpr size_t OFF_V    = 20971520;
constexpr size_t OFF_ZI   = 25231360;          // [BH*S]
constexpr size_t OFF_PD   = 25296896;          // [BH*S]
constexpr size_t OFF_UP   = 25362432;          // [BH][15][128][64]
constexpr size_t WS_FLOATS = 29294592;         // ~117 MB

// ---------------------------------------------------------------------------
// NT GEMM: C[M][N] = A[M][K] @ B[N][K]^T + bias.  GATHER=1 gathers A rows from
// the [BH][S][HD] attention-output layout (k index = h*64+d).
// ---------------------------------------------------------------------------
template<int GATHER>
__global__ __launch_bounds__(256) void gemm_nt(
    const float* __restrict__ Am, const float* __restrict__ Bm,
    const float* __restrict__ bias, float* __restrict__ C,
    int M, int N, int K) {
  __shared__ float as[16][128];
  __shared__ float bs[16][128];
  const int t  = threadIdx.x;
  const int m0 = blockIdx.y * 128, n0 = blockIdx.x * 128;
  const int tm = (t & 15) * 8, tn = (t >> 4) * 8;
  float acc[8][8];
#pragma unroll
  for (int i = 0; i < 8; ++i)
#pragma unroll
    for (int j = 0; j < 8; ++j) acc[i][j] = 0.f;

  for (int kb = 0; kb < K; kb += 16) {
#pragma unroll
    for (int v = 0; v < 2; ++v) {
      const int idx = t + v * 256;           // 0..511 float4 slots
      const int row = idx >> 2, kq = idx & 3;
      const float* srcA;
      if (GATHER) {
        const int m = m0 + row;
        const int b = m >> 11, ss = m & (S - 1);
        const int kk = kb + kq * 4;
        const int h = kk >> 6, d = kk & 63;
        srcA = Am + (((size_t)(b * NH + h) * S + ss) << 6) + d;
      } else {
        srcA = Am + (size_t)(m0 + row) * K + kb + kq * 4;
      }
      const float4 f = *(const float4*)srcA;
      as[kq*4+0][row] = f.x; as[kq*4+1][row] = f.y;
      as[kq*4+2][row] = f.z; as[kq*4+3][row] = f.w;
      const float4 g = *(const float4*)(Bm + (size_t)(n0 + row) * K + kb + kq * 4);
      bs[kq*4+0][row] = g.x; bs[kq*4+1][row] = g.y;
      bs[kq*4+2][row] = g.z; bs[kq*4+3][row] = g.w;
    }
    __syncthreads();
#pragma unroll
    for (int kk = 0; kk < 16; ++kk) {
      const float4 a0 = *(const float4*)&as[kk][tm];
      const float4 a1 = *(const float4*)&as[kk][tm + 4];
      const float4 b0 = *(const float4*)&bs[kk][tn];
      const float4 b1 = *(const float4*)&bs[kk][tn + 4];
      const float av[8] = {a0.x, a0.y, a0.z, a0.w, a1.x, a1.y, a1.z, a1.w};
      const float bv[8] = {b0.x, b0.y, b0.z, b0.w, b1.x, b1.y, b1.z, b1.w};
#pragma unroll
      for (int i = 0; i < 8; ++i)
#pragma unroll
        for (int j = 0; j < 8; ++j) acc[i][j] += av[i] * bv[j];
    }
    __syncthreads();
  }
#pragma unroll
  for (int i = 0; i < 8; ++i) {
    float* dst = C + (size_t)(m0 + tm + i) * N + n0 + tn;
#pragma unroll
    for (int j = 0; j < 8; j += 4) {
      float4 o;
      o.x = acc[i][j+0] + bias[n0+tn+j+0];
      o.y = acc[i][j+1] + bias[n0+tn+j+1];
      o.z = acc[i][j+2] + bias[n0+tn+j+2];
      o.w = acc[i][j+3] + bias[n0+tn+j+3];
      *(float4*)(dst + j) = o;
    }
  }
}

// ---------------------------------------------------------------------------
// RoPE + transpose [b][s][3][h][d] -> Q/K/V [bh][s][d].  Q pre-scaled by 1/8.
// ---------------------------------------------------------------------------
__global__ __launch_bounds__(256) void k2_rope(
    const float* __restrict__ qkv, float* __restrict__ Q,
    float* __restrict__ Kb, float* __restrict__ V) {
  const int g  = blockIdx.x * 256 + threadIdx.x;   // (bh, s)
  const int s  = g & (S - 1);
  const int bh = g >> 11;
  const int b  = bh >> 4, h = bh & 15;
  const float* base = qkv + ((size_t)b * S + s) * 3072 + h * 64;
  float q[64], k[64], v[64];
#pragma unroll
  for (int f = 0; f < 16; ++f) {
    const float4 x = *(const float4*)(base + f * 4);
    q[f*4+0]=x.x; q[f*4+1]=x.y; q[f*4+2]=x.z; q[f*4+3]=x.w;
    const float4 y = *(const float4*)(base + 1024 + f * 4);
    k[f*4+0]=y.x; k[f*4+1]=y.y; k[f*4+2]=y.z; k[f*4+3]=y.w;
    const float4 z = *(const float4*)(base + 2048 + f * 4);
    v[f*4+0]=z.x; v[f*4+1]=z.y; v[f*4+2]=z.z; v[f*4+3]=z.w;
  }
  // 10000^{j/8} = 10^{j/2}, correctly-rounded fp32 (matches numpy fp32 table)
  const float PW[8] = {1.0f, 3.1622776601683795f, 10.0f, 31.622776601683793f,
                       100.0f, 316.22776601683796f, 1000.0f, 3162.2776601683795f};
  float qr[16], kr[16];
#pragma unroll
  for (int d = 0; d < 16; ++d) {
    const int j = d & 7;
    const float invf = 1.0f / PW[j];
    const float fr = (float)s * invf;
    float sn, c;
    sincosf(fr, &sn, &c);
    const float rq = (d < 8) ? -q[d + 8] : q[d - 8];
    const float rk = (d < 8) ? -k[d + 8] : k[d - 8];
    qr[d] = q[d] * c + rq * sn;
    kr[d] = k[d] * c + rk * sn;
  }
#pragma unroll
  for (int d = 0; d < 16; ++d) { q[d] = qr[d]; k[d] = kr[d]; }
#pragma unroll
  for (int d = 0; d < 64; ++d) q[d] *= 0.125f;   // fold softmax scale into Q
  float* qd = Q  + (((size_t)bh * S + s) << 6);
  float* kd = Kb + (((size_t)bh * S + s) << 6);
  float* vd = V  + (((size_t)bh * S + s) << 6);
#pragma unroll
  for (int f = 0; f < 16; ++f) {
    *(float4*)(qd + f*4) = make_float4(q[f*4], q[f*4+1], q[f*4+2], q[f*4+3]);
    *(float4*)(kd + f*4) = make_float4(k[f*4], k[f*4+1], k[f*4+2], k[f*4+3]);
    *(float4*)(vd + f*4) = make_float4(v[f*4], v[f*4+1], v[f*4+2], v[f*4+3]);
  }
}

// ---------------------------------------------------------------------------
// Stats pass 1 (load-balanced 2D): partial Z per (bh, rowblk64, colchunk256),
// plus raw diagonal score into sdg. No row-max: scores ~N(0,1), exp safe.
// ---------------------------------------------------------------------------
__global__ __launch_bounds__(256) void k3_stats(
    const float* __restrict__ Q, const float* __restrict__ Kb,
    float* __restrict__ partZ, float* __restrict__ sdg) {
  const int chunk = blockIdx.x, rb = blockIdx.y, bh = blockIdx.z;
  const int r0 = rb * 64, c0 = chunk * 256;
  if (c0 > r0 + 63) return;          // fully masked block
  __shared__ float ks[64][68];       // +4 pad: distinct banks per row
  const int t = threadIdx.x;
  const int row = t >> 2, c4 = t & 3;
  const int rG = r0 + row;
  float q[64];
  const float* qp = Q + (((size_t)bh * S + rG) << 6);
#pragma unroll
  for (int f = 0; f < 16; ++f) {
    const float4 x = *(const float4*)(qp + f * 4);
    q[f*4]=x.x; q[f*4+1]=x.y; q[f*4+2]=x.z; q[f*4+3]=x.w;
  }
  float Z = 0.f, sd = 0.f;
  bool hasd = false;
  const int ntile = min(4, ((r0 + 63 - c0) >> 6) + 1);
  for (int ct = 0; ct < ntile; ++ct) {
    const int cb = c0 + ct * 64;
    __syncthreads();
    for (int v4 = t; v4 < 1024; v4 += 256) {
      const int r = v4 >> 4, f = v4 & 15;
      *(float4*)&ks[r][f*4] = *(const float4*)(Kb + (((size_t)bh*S + cb + r) << 6) + f*4);
    }
    __syncthreads();
    const int cmax = min(64, rG - cb + 1);
    for (int cc = c4; cc < cmax; cc += 4) {
      float s = 0.f;
#pragma unroll
      for (int i4 = 0; i4 < 16; ++i4) {
        const float4 kv = *(const float4*)&ks[cc][i4*4];
        s += q[i4*4]*kv.x + q[i4*4+1]*kv.y + q[i4*4+2]*kv.z + q[i4*4+3]*kv.w;
      }
      if (cb + cc == rG) { sd = s; hasd = true; }
      Z += __expf(s);
    }
  }
  Z += __shfl_xor(Z, 1, 64);
  Z += __shfl_xor(Z, 2, 64);
  if (c4 == 0) partZ[(((size_t)bh*32 + rb)*8 + chunk)*64 + row] = Z;
  if (hasd) sdg[(size_t)bh * S + rG] = sd;
}

// ---------------------------------------------------------------------------
// Stats pass 2: reduce partial Z over active chunks -> zinv, pd.
// pdg holds raw diag score on entry, diag prob on exit.
// ---------------------------------------------------------------------------
__global__ __launch_bounds__(256) void k3_reduce(
    const float* __restrict__ partZ, float* __restrict__ zinv,
    float* __restrict__ pdg) {
  const int R = blockIdx.x * 256 + threadIdx.x;   // 0..BH*S-1
  const int bh = R >> 11, r = R & 2047;
  const int rb = r >> 6, row = r & 63;
  const int cmaxc = r >> 8;
  float Z = 0.f;
  for (int c = 0; c <= cmaxc; ++c)
    Z += partZ[(((size_t)bh*32 + rb)*8 + c)*64 + row];
  const float zi = 1.f / Z;
  zinv[R] = zi;
  pdg[R] = __expf(pdg[R]) * zi;
}

// ---------------------------------------------------------------------------
// Per-64-block unit-lower-triangular inverse of (I - N), N = strict-lower P.
// Output TRANSPOSED: MinvT[bh][ib][j][r] = Minv[r][j].
// ---------------------------------------------------------------------------
__global__ __launch_bounds__(64) void k4_minv(
    const float* __restrict__ Q, const float* __restrict__ Kb,
    const float* __restrict__ zinv, float* __restrict__ MinvT) {
  const int bh = blockIdx.y, ib = blockIdx.x;
  const int r0 = ib * 64;
  __shared__ float qs[64][64];
  __shared__ float Nb[64][64];
  __shared__ float X[64][64];
  const int c = threadIdx.x;
  float kc[64];
#pragma unroll
  for (int f = 0; f < 16; ++f) {
    const float4 x = *(const float4*)(Kb + (((size_t)bh * S + r0 + c) << 6) + f * 4);
    kc[f*4+0]=x.x; kc[f*4+1]=x.y; kc[f*4+2]=x.z; kc[f*4+3]=x.w;
  }
  for (int v4 = c; v4 < 1024; v4 += 64) {
    const int r = v4 >> 4, f = v4 & 15;
    *(float4*)&qs[r][f*4] = *(const float4*)(Q + (((size_t)bh * S + r0 + r) << 6) + f * 4);
  }
  __syncthreads();
  for (int r = 0; r < 64; ++r) {
    float sdot = 0.f;
#pragma unroll
    for (int i4 = 0; i4 < 16; ++i4) {
      const float4 qv = *(const float4*)&qs[r][i4*4];
      sdot += qv.x*kc[i4*4] + qv.y*kc[i4*4+1] + qv.z*kc[i4*4+2] + qv.w*kc[i4*4+3];
    }
    Nb[r][c] = (c < r) ? __expf(sdot) * zinv[bh * S + r0 + r] : 0.f;
  }
  __syncthreads();
  for (int r = 0; r < 64; ++r) X[r][c] = (r == c) ? 1.f : 0.f;
  __syncthreads();
  for (int r = 1; r < 64; ++r) {         // forward substitution, X = (I-N)^-1
    float a = 0.f;
    for (int j = 0; j < r; ++j) a += Nb[r][j] * X[j][c];
    X[r][c] += a;
    __syncthreads();
  }
  float* dst = MinvT + (((size_t)bh * 32 + ib) * 64 + c) * 64;
  for (int r4 = 0; r4 < 64; r4 += 4) {
    float4 o; o.x = X[r4][c]; o.y = X[r4+1][c]; o.z = X[r4+2][c]; o.w = X[r4+3][c];
    *(float4*)(dst + r4) = o;
  }
}

// ---------------------------------------------------------------------------
// Scan step k, off-diagonal accumulate: upart[bh][j] = P[k-rows, j-block] @ A_j
// ---------------------------------------------------------------------------
__global__ __launch_bounds__(256) void k5_acc(
    const float* __restrict__ Q, const float* __restrict__ Kb,
    const float* __restrict__ Abuf, const float* __restrict__ zinv,
    float* __restrict__ upart, int kstep) {
  const int bh = blockIdx.y, j = blockIdx.x;
  __shared__ float ks[128][64];
  __shared__ float as[128][64];
  const int t = threadIdx.x;
  const int r = t >> 1, dq = (t & 1) * 32;
  const int R = kstep * 128 + r;
  for (int v4 = t; v4 < 2048; v4 += 256) {
    const int rr = v4 >> 4, f = v4 & 15;
    *(float4*)&ks[rr][f*4] = *(const float4*)(Kb   + (((size_t)bh * S + j*128 + rr) << 6) + f * 4);
    *(float4*)&as[rr][f*4] = *(const float4*)(Abuf + (((size_t)bh * S + j*128 + rr) << 6) + f * 4);
  }
  float q[64];
#pragma unroll
  for (int f = 0; f < 16; ++f) {
    const float4 x = *(const float4*)(Q + (((size_t)bh * S + R) << 6) + f * 4);
    q[f*4+0]=x.x; q[f*4+1]=x.y; q[f*4+2]=x.z; q[f*4+3]=x.w;
  }
  const float zi = zinv[bh * S + R];
  float acc[32];
#pragma unroll
  for (int i = 0; i < 32; ++i) acc[i] = 0.f;
  __syncthreads();
  for (int cc = 0; cc < 128; ++cc) {
    float sdot = 0.f;
#pragma unroll
    for (int i4 = 0; i4 < 16; ++i4) {
      const float4 kv = *(const float4*)&ks[cc][i4*4];
      sdot += q[i4*4]*kv.x + q[i4*4+1]*kv.y + q[i4*4+2]*kv.z + q[i4*4+3]*kv.w;
    }
    const float p = __expf(sdot) * zi;
#pragma unroll
    for (int i4 = 0; i4 < 8; ++i4) {
      const float4 av = *(const float4*)&as[cc][dq + i4*4];
      acc[i4*4+0] += p * av.x; acc[i4*4+1] += p * av.y;
      acc[i4*4+2] += p * av.z; acc[i4*4+3] += p * av.w;
    }
  }
  float* dst = upart + ((((size_t)bh * 15 + j) * 128 + r) << 6) + dq;
#pragma unroll
  for (int i = 0; i < 32; i += 4)
    *(float4*)(dst + i) = make_float4(acc[i], acc[i+1], acc[i+2], acc[i+3]);
}

// ---------------------------------------------------------------------------
// Scan step k finalize, parallel over 16-d chunks (grid 4 x BH):
//   u = pd*v + sum(upart);  A_lo = Minv@u_lo (kept in LDS);
//   u_hi += P(hi,lo)@A_lo;  A_hi = Minv@u_hi.
// ---------------------------------------------------------------------------
__global__ __launch_bounds__(256) void k5_fin(
    const float* __restrict__ Q, const float* __restrict__ Kb,
    const float* __restrict__ V, const float* __restrict__ pd,
    const float* __restrict__ zinv, const float* __restrict__ upart,
    const float* __restrict__ MinvT, float* __restrict__ Abuf, int kstep) {
  const int dc0 = blockIdx.x * 16;
  const int bh  = blockIdx.y;
  const int t = threadIdx.x;
  const int base = kstep * 128;
  __shared__ float u[128][16];
  __shared__ float alo[64][17];
  __shared__ float kst[64][68];     // MinvT / K staging (sequential reuse)
  __shared__ float pbuf[64][65];

  // phase 0: u = pd*v + sum partials (this d-chunk); stage MinvT(2k)
  for (int v4 = t; v4 < 512; v4 += 256) {
    const int r = v4 >> 2, f = v4 & 3;
    const int R = base + r;
    const float4 x = *(const float4*)(V + (((size_t)bh*S + R) << 6) + dc0 + f*4);
    const float p = pd[bh*S + R];
    float a0 = p*x.x, a1 = p*x.y, a2 = p*x.z, a3 = p*x.w;
    for (int j = 0; j < kstep; ++j) {
      const float4 y = *(const float4*)(upart + ((((size_t)bh*15 + j)*128 + r) << 6) + dc0 + f*4);
      a0 += y.x; a1 += y.y; a2 += y.z; a3 += y.w;
    }
    *(float4*)&u[r][f*4] = make_float4(a0, a1, a2, a3);
  }
  for (int v4 = t; v4 < 1024; v4 += 256) {
    const int j = v4 >> 4, f = v4 & 15;
    *(float4*)&kst[j][f*4] =
      *(const float4*)(MinvT + ((((size_t)bh*32 + kstep*2)*64 + j) << 6) + f*4);
  }
  __syncthreads();
  // phase 1: A_lo = Minv @ u_lo (this d-chunk); keep in LDS + write global
  {
    const int r = t & 63, dq = (t >> 6) * 4;
    float a0=0.f, a1=0.f, a2=0.f, a3=0.f;
    for (int j = 0; j < 64; ++j) {
      const float w = kst[j][r];
      a0 += w*u[j][dq];   a1 += w*u[j][dq+1];
      a2 += w*u[j][dq+2]; a3 += w*u[j][dq+3];
    }
    alo[r][dq] = a0; alo[r][dq+1] = a1; alo[r][dq+2] = a2; alo[r][dq+3] = a3;
    *(float4*)(Abuf + (((size_t)bh*S + base + r) << 6) + dc0 + dq) =
        make_float4(a0, a1, a2, a3);
  }
  __syncthreads();
  for (int v4 = t; v4 < 1024; v4 += 256) {   // stage K rows [base, base+64)
    const int j = v4 >> 4, f = v4 & 15;
    *(float4*)&kst[j][f*4] = *(const float4*)(Kb + (((size_t)bh*S + base + j) << 6) + f*4);
  }
  __syncthreads();
  // phase 2a: pbuf[r][j] = exp(q_{base+64+r} . k_j) * zi  (dots computed once)
  {
    const int rp = t >> 2, c4 = t & 3;
    const int R = base + 64 + rp;
    float q[64];
    const float* qp = Q + (((size_t)bh*S + R) << 6);
#pragma unroll
    for (int f = 0; f < 16; ++f) {
      const float4 x = *(const float4*)(qp + f*4);
      q[f*4]=x.x; q[f*4+1]=x.y; q[f*4+2]=x.z; q[f*4+3]=x.w;
    }
    const float zi = zinv[bh*S + R];
    for (int j = c4; j < 64; j += 4) {
      float s = 0.f;
#pragma unroll
      for (int i4 = 0; i4 < 16; ++i4) {
        const float4 kv = *(const float4*)&kst[j][i4*4];
        s += q[i4*4]*kv.x + q[i4*4+1]*kv.y + q[i4*4+2]*kv.z + q[i4*4+3]*kv.w;
      }
      pbuf[rp][j] = __expf(s) * zi;
    }
  }
  __syncthreads();
  // phase 2b: u_hi += P @ A_lo (this d-chunk, A_lo from LDS)
  {
    const int r = t & 63, dq = (t >> 6) * 4;
    float a0=0.f, a1=0.f, a2=0.f, a3=0.f;
    for (int j = 0; j < 64; ++j) {
      const float p = pbuf[r][j];
      a0 += p*alo[j][dq];   a1 += p*alo[j][dq+1];
      a2 += p*alo[j][dq+2]; a3 += p*alo[j][dq+3];
    }
    u[64+r][dq] += a0; u[64+r][dq+1] += a1;
    u[64+r][dq+2] += a2; u[64+r][dq+3] += a3;
  }
  __syncthreads();
  for (int v4 = t; v4 < 1024; v4 += 256) {   // stage MinvT(2k+1)
    const int j = v4 >> 4, f = v4 & 15;
    *(float4*)&kst[j][f*4] =
      *(const float4*)(MinvT + ((((size_t)bh*32 + kstep*2 + 1)*64 + j) << 6) + f*4);
  }
  __syncthreads();
  // phase 3: A_hi = Minv @ u_hi
  {
    const int r = t & 63, dq = (t >> 6) * 4;
    float a0=0.f, a1=0.f, a2=0.f, a3=0.f;
    for (int j = 0; j < 64; ++j) {
      const float w = kst[j][r];
      a0 += w*u[64+j][dq];   a1 += w*u[64+j][dq+1];
      a2 += w*u[64+j][dq+2]; a3 += w*u[64+j][dq+3];
    }
    *(float4*)(Abuf + (((size_t)bh*S + base + 64 + r) << 6) + dc0 + dq) =
        make_float4(a0, a1, a2, a3);
  }
}

} // namespace

extern "C" void kernel_launch(void* const* d_in, const int* in_sizes, int n_in,
                              void* d_out, int out_size, void* d_ws, size_t ws_size,
                              hipStream_t stream) {
  const float* hs   = (const float*)d_in[0];
  const float* Wqkv = (const float*)d_in[1];
  const float* bqkv = (const float*)d_in[2];
  const float* Wd   = (const float*)d_in[3];
  const float* bd   = (const float*)d_in[4];
  float* out = (float*)d_out;
  float* W   = (float*)d_ws;
  if (ws_size < WS_FLOATS * sizeof(float)) return;  // insufficient scratch

  float* qkv   = W + OFF_QKV;
  float* partZ = W + OFF_PART;   // lives between rope and k4_minv
  float* MinvT = W + OFF_MINV;
  float* Abuf  = W + OFF_A;
  float* Qb    = W + OFF_Q;
  float* Kbuf  = W + OFF_K;
  float* Vb    = W + OFF_V;
  float* zi    = W + OFF_ZI;
  float* pdg   = W + OFF_PD;
  float* up    = W + OFF_UP;

  gemm_nt<0><<<dim3(24, 32), 256, 0, stream>>>(hs, Wqkv, bqkv, qkv, B*S, 3*HID, HID);
  k2_rope<<<dim3(BH * S / 256), 256, 0, stream>>>(qkv, Qb, Kbuf, Vb);
  k3_stats<<<dim3(8, 32, BH), 256, 0, stream>>>(Qb, Kbuf, partZ, pdg);
  k3_reduce<<<dim3(BH * S / 256), 256, 0, stream>>>(partZ, zi, pdg);
  k4_minv<<<dim3(S / 64, BH), 64, 0, stream>>>(Qb, Kbuf, zi, MinvT);
  for (int k = 0; k < NSTEP; ++k) {
    if (k > 0)
      k5_acc<<<dim3(k, BH), 256, 0, stream>>>(Qb, Kbuf, Abuf, zi, up, k);
    k5_fin<<<dim3(4, BH), 256, 0, stream>>>(Qb, Kbuf, Vb, pdg, zi, up, MinvT, Abuf, k);
  }
  gemm_nt<1><<<dim3(8, 32), 256, 0, stream>>>(Abuf, Wd, bd, out, B*S, HID, HID);
}

// Round 3
// 1684.736 us; speedup vs baseline: 1.9900x; 1.3155x over previous
//
#include <hip/hip_runtime.h>
#include <math.h>

namespace {

constexpr int B  = 2, S = 2048, NH = 16, HD = 64, HID = 1024;
constexpr int BH = B * NH;          // 32
constexpr int NSTEP = 16;           // 128-row scan blocks

// ws layout in floats. qkv region (12.58M floats) is reused for partZ/MinvT + A.
constexpr size_t OFF_QKV  = 0;
constexpr size_t OFF_PART = 0;                 // [BH][16][16][128] = 1,048,576 (Z partials)
constexpr size_t OFF_MINV = 0;                 // [BH][32][64][64] = 4,194,304
constexpr size_t OFF_A    = 4194304;           // [BH][S][HD]      = 4,194,304
constexpr size_t OFF_Q    = 12582912;          // [BH][S][HD]
constexpr size_t OFF_K    = 16777216;
constexpr size_t OFF_V    = 20971520;
constexpr size_t OFF_ZI   = 25231360;          // [BH*S]
constexpr size_t OFF_PD   = 25296896;          // [BH*S]
constexpr size_t OFF_UP   = 25362432;          // [BH][15][128][64]
constexpr size_t WS_FLOATS = 29294592;         // ~117 MB

// ---------------------------------------------------------------------------
// NT GEMM: C[M][N] = A[M][K] @ B[N][K]^T + bias.  GATHER=1 gathers A rows from
// the [BH][S][HD] attention-output layout (k index = h*64+d).
// ---------------------------------------------------------------------------
template<int GATHER>
__global__ __launch_bounds__(256) void gemm_nt(
    const float* __restrict__ Am, const float* __restrict__ Bm,
    const float* __restrict__ bias, float* __restrict__ C,
    int M, int N, int K) {
  __shared__ float as[16][128];
  __shared__ float bs[16][128];
  const int t  = threadIdx.x;
  const int m0 = blockIdx.y * 128, n0 = blockIdx.x * 128;
  const int tm = (t & 15) * 8, tn = (t >> 4) * 8;
  float acc[8][8];
#pragma unroll
  for (int i = 0; i < 8; ++i)
#pragma unroll
    for (int j = 0; j < 8; ++j) acc[i][j] = 0.f;

  for (int kb = 0; kb < K; kb += 16) {
#pragma unroll
    for (int v = 0; v < 2; ++v) {
      const int idx = t + v * 256;           // 0..511 float4 slots
      const int row = idx >> 2, kq = idx & 3;
      const float* srcA;
      if (GATHER) {
        const int m = m0 + row;
        const int b = m >> 11, ss = m & (S - 1);
        const int kk = kb + kq * 4;
        const int h = kk >> 6, d = kk & 63;
        srcA = Am + (((size_t)(b * NH + h) * S + ss) << 6) + d;
      } else {
        srcA = Am + (size_t)(m0 + row) * K + kb + kq * 4;
      }
      const float4 f = *(const float4*)srcA;
      as[kq*4+0][row] = f.x; as[kq*4+1][row] = f.y;
      as[kq*4+2][row] = f.z; as[kq*4+3][row] = f.w;
      const float4 g = *(const float4*)(Bm + (size_t)(n0 + row) * K + kb + kq * 4);
      bs[kq*4+0][row] = g.x; bs[kq*4+1][row] = g.y;
      bs[kq*4+2][row] = g.z; bs[kq*4+3][row] = g.w;
    }
    __syncthreads();
#pragma unroll
    for (int kk = 0; kk < 16; ++kk) {
      const float4 a0 = *(const float4*)&as[kk][tm];
      const float4 a1 = *(const float4*)&as[kk][tm + 4];
      const float4 b0 = *(const float4*)&bs[kk][tn];
      const float4 b1 = *(const float4*)&bs[kk][tn + 4];
      const float av[8] = {a0.x, a0.y, a0.z, a0.w, a1.x, a1.y, a1.z, a1.w};
      const float bv[8] = {b0.x, b0.y, b0.z, b0.w, b1.x, b1.y, b1.z, b1.w};
#pragma unroll
      for (int i = 0; i < 8; ++i)
#pragma unroll
        for (int j = 0; j < 8; ++j) acc[i][j] += av[i] * bv[j];
    }
    __syncthreads();
  }
#pragma unroll
  for (int i = 0; i < 8; ++i) {
    float* dst = C + (size_t)(m0 + tm + i) * N + n0 + tn;
#pragma unroll
    for (int j = 0; j < 8; j += 4) {
      float4 o;
      o.x = acc[i][j+0] + bias[n0+tn+j+0];
      o.y = acc[i][j+1] + bias[n0+tn+j+1];
      o.z = acc[i][j+2] + bias[n0+tn+j+2];
      o.w = acc[i][j+3] + bias[n0+tn+j+3];
      *(float4*)(dst + j) = o;
    }
  }
}

// ---------------------------------------------------------------------------
// RoPE + transpose [b][s][3][h][d] -> Q/K/V [bh][s][d].  Q pre-scaled by 1/8.
// ---------------------------------------------------------------------------
__global__ __launch_bounds__(256) void k2_rope(
    const float* __restrict__ qkv, float* __restrict__ Q,
    float* __restrict__ Kb, float* __restrict__ V) {
  const int g  = blockIdx.x * 256 + threadIdx.x;   // (bh, s)
  const int s  = g & (S - 1);
  const int bh = g >> 11;
  const int b  = bh >> 4, h = bh & 15;
  const float* base = qkv + ((size_t)b * S + s) * 3072 + h * 64;
  float q[64], k[64], v[64];
#pragma unroll
  for (int f = 0; f < 16; ++f) {
    const float4 x = *(const float4*)(base + f * 4);
    q[f*4+0]=x.x; q[f*4+1]=x.y; q[f*4+2]=x.z; q[f*4+3]=x.w;
    const float4 y = *(const float4*)(base + 1024 + f * 4);
    k[f*4+0]=y.x; k[f*4+1]=y.y; k[f*4+2]=y.z; k[f*4+3]=y.w;
    const float4 z = *(const float4*)(base + 2048 + f * 4);
    v[f*4+0]=z.x; v[f*4+1]=z.y; v[f*4+2]=z.z; v[f*4+3]=z.w;
  }
  // 10000^{j/8} = 10^{j/2}, correctly-rounded fp32 (matches numpy fp32 table)
  const float PW[8] = {1.0f, 3.1622776601683795f, 10.0f, 31.622776601683793f,
                       100.0f, 316.22776601683796f, 1000.0f, 3162.2776601683795f};
  float qr[16], kr[16];
#pragma unroll
  for (int d = 0; d < 16; ++d) {
    const int j = d & 7;
    const float invf = 1.0f / PW[j];
    const float fr = (float)s * invf;
    float sn, c;
    sincosf(fr, &sn, &c);
    const float rq = (d < 8) ? -q[d + 8] : q[d - 8];
    const float rk = (d < 8) ? -k[d + 8] : k[d - 8];
    qr[d] = q[d] * c + rq * sn;
    kr[d] = k[d] * c + rk * sn;
  }
#pragma unroll
  for (int d = 0; d < 16; ++d) { q[d] = qr[d]; k[d] = kr[d]; }
#pragma unroll
  for (int d = 0; d < 64; ++d) q[d] *= 0.125f;   // fold softmax scale into Q
  float* qd = Q  + (((size_t)bh * S + s) << 6);
  float* kd = Kb + (((size_t)bh * S + s) << 6);
  float* vd = V  + (((size_t)bh * S + s) << 6);
#pragma unroll
  for (int f = 0; f < 16; ++f) {
    *(float4*)(qd + f*4) = make_float4(q[f*4], q[f*4+1], q[f*4+2], q[f*4+3]);
    *(float4*)(kd + f*4) = make_float4(k[f*4], k[f*4+1], k[f*4+2], k[f*4+3]);
    *(float4*)(vd + f*4) = make_float4(v[f*4], v[f*4+1], v[f*4+2], v[f*4+3]);
  }
}

// ---------------------------------------------------------------------------
// Register-blocked score pass: per 128x128 causal block, E=exp(QK^T) row-sums
// -> partZ[bh][rb][cb][128]; raw diag score -> sdg. 8x8 microtiles.
// ---------------------------------------------------------------------------
__global__ __launch_bounds__(256) void k3_scores(
    const float* __restrict__ Q, const float* __restrict__ Kb,
    float* __restrict__ partZ, float* __restrict__ sdg) {
  const int cb = blockIdx.x, rb = blockIdx.y, bh = blockIdx.z;
  if (cb > rb) return;
  __shared__ float qs[64][132];    // Q^T tile [kk][row]
  __shared__ float ks[64][132];    // K^T tile [kk][col]
  __shared__ float red[128][17];
  const int t = threadIdx.x;
  const int tm = (t & 15) * 8, tn = (t >> 4) * 8;
  for (int v4 = t; v4 < 2048; v4 += 256) {
    const int r = v4 >> 4, f = v4 & 15;
    const float4 x = *(const float4*)(Q + (((size_t)bh*S + rb*128 + r) << 6) + f*4);
    qs[f*4+0][r]=x.x; qs[f*4+1][r]=x.y; qs[f*4+2][r]=x.z; qs[f*4+3][r]=x.w;
    const float4 y = *(const float4*)(Kb + (((size_t)bh*S + cb*128 + r) << 6) + f*4);
    ks[f*4+0][r]=y.x; ks[f*4+1][r]=y.y; ks[f*4+2][r]=y.z; ks[f*4+3][r]=y.w;
  }
  __syncthreads();
  float acc[8][8];
#pragma unroll
  for (int i = 0; i < 8; ++i)
#pragma unroll
    for (int j = 0; j < 8; ++j) acc[i][j] = 0.f;
#pragma unroll 4
  for (int kk = 0; kk < 64; ++kk) {
    const float4 a0 = *(const float4*)&qs[kk][tm];
    const float4 a1 = *(const float4*)&qs[kk][tm + 4];
    const float4 b0 = *(const float4*)&ks[kk][tn];
    const float4 b1 = *(const float4*)&ks[kk][tn + 4];
    const float av[8] = {a0.x, a0.y, a0.z, a0.w, a1.x, a1.y, a1.z, a1.w};
    const float bv[8] = {b0.x, b0.y, b0.z, b0.w, b1.x, b1.y, b1.z, b1.w};
#pragma unroll
    for (int i = 0; i < 8; ++i)
#pragma unroll
      for (int j = 0; j < 8; ++j) acc[i][j] += av[i] * bv[j];
  }
  // mask + exp + per-thread row sums; capture raw diag score
  const int rbase = rb * 128 + tm, cbase = cb * 128 + tn;
  float rs[8];
#pragma unroll
  for (int i = 0; i < 8; ++i) {
    rs[i] = 0.f;
    const int rG = rbase + i;
#pragma unroll
    for (int j = 0; j < 8; ++j) {
      const int cG = cbase + j;
      if (cG <= rG) {
        rs[i] += __expf(acc[i][j]);
        if (cG == rG) sdg[(size_t)bh * S + rG] = acc[i][j];
      }
    }
  }
  const int tnq = t >> 4;
#pragma unroll
  for (int i = 0; i < 8; ++i) red[tm + i][tnq] = rs[i];
  __syncthreads();
  if (t < 128) {
    float z = 0.f;
#pragma unroll
    for (int c = 0; c < 16; ++c) z += red[t][c];
    partZ[(((size_t)bh*16 + rb)*16 + cb)*128 + t] = z;
  }
}

// ---------------------------------------------------------------------------
// Stats pass 2: Z = sum of partials over cb<=rb -> zinv; pd = exp(sd)*zinv.
// ---------------------------------------------------------------------------
__global__ __launch_bounds__(256) void k3_reduce(
    const float* __restrict__ partZ, float* __restrict__ zinv,
    float* __restrict__ pdg) {
  const int R = blockIdx.x * 256 + threadIdx.x;   // 0..BH*S-1
  const int bh = R >> 11, r = R & 2047;
  const int rb = r >> 7, row = r & 127;
  float Z = 0.f;
  for (int c = 0; c <= rb; ++c)
    Z += partZ[(((size_t)bh*16 + rb)*16 + c)*128 + row];
  const float zi = 1.f / Z;
  zinv[R] = zi;
  pdg[R] = __expf(pdg[R]) * zi;
}

// ---------------------------------------------------------------------------
// Per-64-block unit-lower-triangular inverse of (I - N), N = strict-lower P.
// Output TRANSPOSED: MinvT[bh][ib][j][r] = Minv[r][j].
// ---------------------------------------------------------------------------
__global__ __launch_bounds__(64) void k4_minv(
    const float* __restrict__ Q, const float* __restrict__ Kb,
    const float* __restrict__ zinv, float* __restrict__ MinvT) {
  const int bh = blockIdx.y, ib = blockIdx.x;
  const int r0 = ib * 64;
  __shared__ float qs[64][64];
  __shared__ float Nb[64][64];
  __shared__ float X[64][64];
  const int c = threadIdx.x;
  float kc[64];
#pragma unroll
  for (int f = 0; f < 16; ++f) {
    const float4 x = *(const float4*)(Kb + (((size_t)bh * S + r0 + c) << 6) + f * 4);
    kc[f*4+0]=x.x; kc[f*4+1]=x.y; kc[f*4+2]=x.z; kc[f*4+3]=x.w;
  }
  for (int v4 = c; v4 < 1024; v4 += 64) {
    const int r = v4 >> 4, f = v4 & 15;
    *(float4*)&qs[r][f*4] = *(const float4*)(Q + (((size_t)bh * S + r0 + r) << 6) + f * 4);
  }
  __syncthreads();
  for (int r = 0; r < 64; ++r) {
    float sdot = 0.f;
#pragma unroll
    for (int i4 = 0; i4 < 16; ++i4) {
      const float4 qv = *(const float4*)&qs[r][i4*4];
      sdot += qv.x*kc[i4*4] + qv.y*kc[i4*4+1] + qv.z*kc[i4*4+2] + qv.w*kc[i4*4+3];
    }
    Nb[r][c] = (c < r) ? __expf(sdot) * zinv[bh * S + r0 + r] : 0.f;
  }
  __syncthreads();
  for (int r = 0; r < 64; ++r) X[r][c] = (r == c) ? 1.f : 0.f;
  __syncthreads();
  for (int r = 1; r < 64; ++r) {         // forward substitution, X = (I-N)^-1
    float a = 0.f;
    for (int j = 0; j < r; ++j) a += Nb[r][j] * X[j][c];
    X[r][c] += a;
    __syncthreads();
  }
  float* dst = MinvT + (((size_t)bh * 32 + ib) * 64 + c) * 64;
  for (int r4 = 0; r4 < 64; r4 += 4) {
    float4 o; o.x = X[r4][c]; o.y = X[r4+1][c]; o.z = X[r4+2][c]; o.w = X[r4+3][c];
    *(float4*)(dst + r4) = o;
  }
}

// ---------------------------------------------------------------------------
// Scan step k off-diagonal accumulate (register-blocked, two 64-col halves):
// upart[bh][j] = P[k-rows, j-block] @ A_j.  8x4 microtiles both phases.
// ---------------------------------------------------------------------------
__global__ __launch_bounds__(256) void k5_acc(
    const float* __restrict__ Q, const float* __restrict__ Kb,
    const float* __restrict__ Abuf, const float* __restrict__ zinv,
    float* __restrict__ upart, int kstep) {
  const int bh = blockIdx.y, j = blockIdx.x;
  __shared__ float qs[64][132];    // Q^T [kk][r], rows base..base+127
  __shared__ float pt[64][132];    // P^T half [c][r]
  __shared__ float buf[64][68];    // K^T half [kk][c], then A half [c][d]
  const int t = threadIdx.x;
  const int tm = (t & 15) * 8, tn4 = (t >> 4) * 4;
  const int base = kstep * 128;
  for (int v4 = t; v4 < 2048; v4 += 256) {
    const int r = v4 >> 4, f = v4 & 15;
    const float4 x = *(const float4*)(Q + (((size_t)bh*S + base + r) << 6) + f*4);
    qs[f*4+0][r]=x.x; qs[f*4+1][r]=x.y; qs[f*4+2][r]=x.z; qs[f*4+3][r]=x.w;
  }
  float ziv[8];
#pragma unroll
  for (int i = 0; i < 8; ++i) ziv[i] = zinv[bh*S + base + tm + i];
  float out[8][4];
#pragma unroll
  for (int i = 0; i < 8; ++i)
#pragma unroll
    for (int jj = 0; jj < 4; ++jj) out[i][jj] = 0.f;

  for (int h = 0; h < 2; ++h) {
    __syncthreads();     // covers qs staging (h=0) / pt+buf reuse (h=1)
    for (int v4 = t; v4 < 1024; v4 += 256) {      // K^T half
      const int c = v4 >> 4, f = v4 & 15;
      const float4 y = *(const float4*)(Kb + (((size_t)bh*S + j*128 + h*64 + c) << 6) + f*4);
      buf[f*4+0][c]=y.x; buf[f*4+1][c]=y.y; buf[f*4+2][c]=y.z; buf[f*4+3][c]=y.w;
    }
    __syncthreads();
    float qk[8][4];
#pragma unroll
    for (int i = 0; i < 8; ++i)
#pragma unroll
      for (int jj = 0; jj < 4; ++jj) qk[i][jj] = 0.f;
#pragma unroll 4
    for (int kk = 0; kk < 64; ++kk) {
      const float4 a0 = *(const float4*)&qs[kk][tm];
      const float4 a1 = *(const float4*)&qs[kk][tm + 4];
      const float4 b  = *(const float4*)&buf[kk][tn4];
      const float av[8] = {a0.x, a0.y, a0.z, a0.w, a1.x, a1.y, a1.z, a1.w};
      const float bv[4] = {b.x, b.y, b.z, b.w};
#pragma unroll
      for (int i = 0; i < 8; ++i)
#pragma unroll
        for (int jj = 0; jj < 4; ++jj) qk[i][jj] += av[i] * bv[jj];
    }
#pragma unroll
    for (int i = 0; i < 8; ++i)
#pragma unroll
      for (int jj = 0; jj < 4; ++jj)
        pt[tn4 + jj][tm + i] = __expf(qk[i][jj]) * ziv[i];
    __syncthreads();
    for (int v4 = t; v4 < 1024; v4 += 256) {      // A half (row-major)
      const int c = v4 >> 4, f = v4 & 15;
      *(float4*)&buf[c][f*4] =
        *(const float4*)(Abuf + (((size_t)bh*S + j*128 + h*64 + c) << 6) + f*4);
    }
    __syncthreads();
#pragma unroll 4
    for (int c = 0; c < 64; ++c) {
      const float4 p0 = *(const float4*)&pt[c][tm];
      const float4 p1 = *(const float4*)&pt[c][tm + 4];
      const float4 a  = *(const float4*)&buf[c][tn4];
      const float pv[8] = {p0.x, p0.y, p0.z, p0.w, p1.x, p1.y, p1.z, p1.w};
      const float avv[4] = {a.x, a.y, a.z, a.w};
#pragma unroll
      for (int i = 0; i < 8; ++i)
#pragma unroll
        for (int jj = 0; jj < 4; ++jj) out[i][jj] += pv[i] * avv[jj];
    }
  }
#pragma unroll
  for (int i = 0; i < 8; ++i)
    *(float4*)(upart + ((((size_t)bh*15 + j)*128 + tm + i) << 6) + tn4) =
        make_float4(out[i][0], out[i][1], out[i][2], out[i][3]);
}

// ---------------------------------------------------------------------------
// Scan step k finalize, parallel over 16-d chunks (grid 4 x BH):
//   u = pd*v + sum(upart);  A_lo = Minv@u_lo (kept in LDS);
//   u_hi += P(hi,lo)@A_lo;  A_hi = Minv@u_hi.
// ---------------------------------------------------------------------------
__global__ __launch_bounds__(256) void k5_fin(
    const float* __restrict__ Q, const float* __restrict__ Kb,
    const float* __restrict__ V, const float* __restrict__ pd,
    const float* __restrict__ zinv, const float* __restrict__ upart,
    const float* __restrict__ MinvT, float* __restrict__ Abuf, int kstep) {
  const int dc0 = blockIdx.x * 16;
  const int bh  = blockIdx.y;
  const int t = threadIdx.x;
  const int base = kstep * 128;
  __shared__ float u[128][16];
  __shared__ float alo[64][17];
  __shared__ float kst[64][68];     // MinvT / K staging (sequential reuse)
  __shared__ float pbuf[64][65];

  // phase 0: u = pd*v + sum partials (this d-chunk); stage MinvT(2k)
  for (int v4 = t; v4 < 512; v4 += 256) {
    const int r = v4 >> 2, f = v4 & 3;
    const int R = base + r;
    const float4 x = *(const float4*)(V + (((size_t)bh*S + R) << 6) + dc0 + f*4);
    const float p = pd[bh*S + R];
    float a0 = p*x.x, a1 = p*x.y, a2 = p*x.z, a3 = p*x.w;
    for (int j = 0; j < kstep; ++j) {
      const float4 y = *(const float4*)(upart + ((((size_t)bh*15 + j)*128 + r) << 6) + dc0 + f*4);
      a0 += y.x; a1 += y.y; a2 += y.z; a3 += y.w;
    }
    *(float4*)&u[r][f*4] = make_float4(a0, a1, a2, a3);
  }
  for (int v4 = t; v4 < 1024; v4 += 256) {
    const int j = v4 >> 4, f = v4 & 15;
    *(float4*)&kst[j][f*4] =
      *(const float4*)(MinvT + ((((size_t)bh*32 + kstep*2)*64 + j) << 6) + f*4);
  }
  __syncthreads();
  // phase 1: A_lo = Minv @ u_lo (this d-chunk); keep in LDS + write global
  {
    const int r = t & 63, dq = (t >> 6) * 4;
    float a0=0.f, a1=0.f, a2=0.f, a3=0.f;
    for (int j = 0; j < 64; ++j) {
      const float w = kst[j][r];
      a0 += w*u[j][dq];   a1 += w*u[j][dq+1];
      a2 += w*u[j][dq+2]; a3 += w*u[j][dq+3];
    }
    alo[r][dq] = a0; alo[r][dq+1] = a1; alo[r][dq+2] = a2; alo[r][dq+3] = a3;
    *(float4*)(Abuf + (((size_t)bh*S + base + r) << 6) + dc0 + dq) =
        make_float4(a0, a1, a2, a3);
  }
  __syncthreads();
  for (int v4 = t; v4 < 1024; v4 += 256) {   // stage K rows [base, base+64)
    const int j = v4 >> 4, f = v4 & 15;
    *(float4*)&kst[j][f*4] = *(const float4*)(Kb + (((size_t)bh*S + base + j) << 6) + f*4);
  }
  __syncthreads();
  // phase 2a: pbuf[r][j] = exp(q_{base+64+r} . k_j) * zi  (dots computed once)
  {
    const int rp = t >> 2, c4 = t & 3;
    const int R = base + 64 + rp;
    float q[64];
    const float* qp = Q + (((size_t)bh*S + R) << 6);
#pragma unroll
    for (int f = 0; f < 16; ++f) {
      const float4 x = *(const float4*)(qp + f*4);
      q[f*4]=x.x; q[f*4+1]=x.y; q[f*4+2]=x.z; q[f*4+3]=x.w;
    }
    const float zi = zinv[bh*S + R];
    for (int j = c4; j < 64; j += 4) {
      float s = 0.f;
#pragma unroll
      for (int i4 = 0; i4 < 16; ++i4) {
        const float4 kv = *(const float4*)&kst[j][i4*4];
        s += q[i4*4]*kv.x + q[i4*4+1]*kv.y + q[i4*4+2]*kv.z + q[i4*4+3]*kv.w;
      }
      pbuf[rp][j] = __expf(s) * zi;
    }
  }
  __syncthreads();
  // phase 2b: u_hi += P @ A_lo (this d-chunk, A_lo from LDS)
  {
    const int r = t & 63, dq = (t >> 6) * 4;
    float a0=0.f, a1=0.f, a2=0.f, a3=0.f;
    for (int j = 0; j < 64; ++j) {
      const float p = pbuf[r][j];
      a0 += p*alo[j][dq];   a1 += p*alo[j][dq+1];
      a2 += p*alo[j][dq+2]; a3 += p*alo[j][dq+3];
    }
    u[64+r][dq] += a0; u[64+r][dq+1] += a1;
    u[64+r][dq+2] += a2; u[64+r][dq+3] += a3;
  }
  __syncthreads();
  for (int v4 = t; v4 < 1024; v4 += 256) {   // stage MinvT(2k+1)
    const int j = v4 >> 4, f = v4 & 15;
    *(float4*)&kst[j][f*4] =
      *(const float4*)(MinvT + ((((size_t)bh*32 + kstep*2 + 1)*64 + j) << 6) + f*4);
  }
  __syncthreads();
  // phase 3: A_hi = Minv @ u_hi
  {
    const int r = t & 63, dq = (t >> 6) * 4;
    float a0=0.f, a1=0.f, a2=0.f, a3=0.f;
    for (int j = 0; j < 64; ++j) {
      const float w = kst[j][r];
      a0 += w*u[64+j][dq];   a1 += w*u[64+j][dq+1];
      a2 += w*u[64+j][dq+2]; a3 += w*u[64+j][dq+3];
    }
    *(float4*)(Abuf + (((size_t)bh*S + base + 64 + r) << 6) + dc0 + dq) =
        make_float4(a0, a1, a2, a3);
  }
}

} // namespace

extern "C" void kernel_launch(void* const* d_in, const int* in_sizes, int n_in,
                              void* d_out, int out_size, void* d_ws, size_t ws_size,
                              hipStream_t stream) {
  const float* hs   = (const float*)d_in[0];
  const float* Wqkv = (const float*)d_in[1];
  const float* bqkv = (const float*)d_in[2];
  const float* Wd   = (const float*)d_in[3];
  const float* bd   = (const float*)d_in[4];
  float* out = (float*)d_out;
  float* W   = (float*)d_ws;
  if (ws_size < WS_FLOATS * sizeof(float)) return;  // insufficient scratch

  float* qkv   = W + OFF_QKV;
  float* partZ = W + OFF_PART;   // lives between rope and k4_minv
  float* MinvT = W + OFF_MINV;
  float* Abuf  = W + OFF_A;
  float* Qb    = W + OFF_Q;
  float* Kbuf  = W + OFF_K;
  float* Vb    = W + OFF_V;
  float* zi    = W + OFF_ZI;
  float* pdg   = W + OFF_PD;
  float* up    = W + OFF_UP;

  gemm_nt<0><<<dim3(24, 32), 256, 0, stream>>>(hs, Wqkv, bqkv, qkv, B*S, 3*HID, HID);
  k2_rope<<<dim3(BH * S / 256), 256, 0, stream>>>(qkv, Qb, Kbuf, Vb);
  k3_scores<<<dim3(16, 16, BH), 256, 0, stream>>>(Qb, Kbuf, partZ, pdg);
  k3_reduce<<<dim3(BH * S / 256), 256, 0, stream>>>(partZ, zi, pdg);
  k4_minv<<<dim3(S / 64, BH), 64, 0, stream>>>(Qb, Kbuf, zi, MinvT);
  for (int k = 0; k < NSTEP; ++k) {
    if (k > 0)
      k5_acc<<<dim3(k, BH), 256, 0, stream>>>(Qb, Kbuf, Abuf, zi, up, k);
    k5_fin<<<dim3(4, BH), 256, 0, stream>>>(Qb, Kbuf, Vb, pdg, zi, up, MinvT, Abuf, k);
  }
  gemm_nt<1><<<dim3(8, 32), 256, 0, stream>>>(Abuf, Wd, bd, out, B*S, HID, HID);
}

// Round 4
// 1422.617 us; speedup vs baseline: 2.3567x; 1.1843x over previous
//
#include <hip/hip_runtime.h>
#include <math.h>

namespace {

constexpr int B  = 2, S = 2048, NH = 16, HD = 64, HID = 1024;
constexpr int BH = B * NH;          // 32
constexpr int NSTEP = 16;           // 128-row scan blocks

// ws layout in floats. qkv region (12.58M floats) is reused for partZ/MinvT + A.
constexpr size_t OFF_QKV  = 0;
constexpr size_t OFF_PART = 0;                 // [BH][16][16][128] = 1,048,576 (Z partials)
constexpr size_t OFF_MINV = 0;                 // [BH][32][64][64] = 4,194,304
constexpr size_t OFF_A    = 4194304;           // [BH][S][HD]      = 4,194,304
constexpr size_t OFF_Q    = 12582912;          // [BH][S][HD]
constexpr size_t OFF_K    = 16777216;
constexpr size_t OFF_V    = 20971520;
constexpr size_t OFF_ZI   = 25231360;          // [BH*S]
constexpr size_t OFF_PD   = 25296896;          // [BH*S]
constexpr size_t OFF_UP   = 25362432;          // [BH][15][128][64]
constexpr size_t WS_FLOATS = 29294592;         // ~117 MB

typedef __attribute__((ext_vector_type(8))) short bf16x8;
typedef __attribute__((ext_vector_type(4))) float f32x4;

__device__ inline unsigned short bf_rne(float x) {
  const unsigned u = __float_as_uint(x);
  return (unsigned short)((u + 0x7FFFu + ((u >> 16) & 1u)) >> 16);
}

// ---------------------------------------------------------------------------
// Split fp32 -> (hi, lo) bf16 arrays.  n4 = element_count / 4.
// ---------------------------------------------------------------------------
__global__ __launch_bounds__(256) void split2(
    const float* __restrict__ in, short* __restrict__ hi,
    short* __restrict__ lo, int n4) {
  for (int g = blockIdx.x * 256 + threadIdx.x; g < n4; g += gridDim.x * 256) {
    const float4 x = *(const float4*)(in + (size_t)g * 4);
    short4 h, l;
    h.x = bf_rne(x.x); h.y = bf_rne(x.y); h.z = bf_rne(x.z); h.w = bf_rne(x.w);
    l.x = bf_rne(x.x - __uint_as_float((unsigned)(unsigned short)h.x << 16));
    l.y = bf_rne(x.y - __uint_as_float((unsigned)(unsigned short)h.y << 16));
    l.z = bf_rne(x.z - __uint_as_float((unsigned)(unsigned short)h.z << 16));
    l.w = bf_rne(x.w - __uint_as_float((unsigned)(unsigned short)h.w << 16));
    *(short4*)(hi + (size_t)g * 4) = h;
    *(short4*)(lo + (size_t)g * 4) = l;
  }
}

// ---------------------------------------------------------------------------
// Gather attn output [bh][s][d] -> [m=(b,s)][k=(h,d)] and split to hi/lo bf16.
// ---------------------------------------------------------------------------
__global__ __launch_bounds__(256) void split_gather(
    const float* __restrict__ Abuf, short* __restrict__ hi,
    short* __restrict__ lo) {
  const int n4 = B * S * HID / 4;
  for (int g = blockIdx.x * 256 + threadIdx.x; g < n4; g += gridDim.x * 256) {
    const int m = g >> 8, q = g & 255;
    const int k0 = q * 4;
    const int b = m >> 11, s = m & (S - 1);
    const int h = k0 >> 6, d = k0 & 63;
    const float4 x = *(const float4*)(Abuf + (((size_t)(b * NH + h) * S + s) << 6) + d);
    short4 hh, ll;
    hh.x = bf_rne(x.x); hh.y = bf_rne(x.y); hh.z = bf_rne(x.z); hh.w = bf_rne(x.w);
    ll.x = bf_rne(x.x - __uint_as_float((unsigned)(unsigned short)hh.x << 16));
    ll.y = bf_rne(x.y - __uint_as_float((unsigned)(unsigned short)hh.y << 16));
    ll.z = bf_rne(x.z - __uint_as_float((unsigned)(unsigned short)hh.z << 16));
    ll.w = bf_rne(x.w - __uint_as_float((unsigned)(unsigned short)hh.w << 16));
    *(short4*)(hi + (size_t)m * HID + k0) = hh;
    *(short4*)(lo + (size_t)m * HID + k0) = ll;
  }
}

// ---------------------------------------------------------------------------
// Split-bf16 MFMA NT GEMM: C[M][N] = A[M][K] @ B[N][K]^T + bias, fp32 via
// 3 bf16 chains (hi*hi + lo*hi + hi*lo).  128x128 tile, 4 waves x 64x64,
// v_mfma_f32_16x16x32_bf16.  LDS rows padded to 40 shorts (80B stride:
// 8 distinct bank-groups per 8 rows -> 2-way aliasing, free).
// ---------------------------------------------------------------------------
__global__ __launch_bounds__(256) void gemm_bf3(
    const short* __restrict__ Ahi, const short* __restrict__ Alo,
    const short* __restrict__ Bhi, const short* __restrict__ Blo,
    const float* __restrict__ bias, float* __restrict__ C,
    int M, int N, int K) {
  __shared__ short ash[128][40], als[128][40], bsh[128][40], bls[128][40];
  const int t = threadIdx.x;
  const int m0 = blockIdx.y * 128, n0 = blockIdx.x * 128;
  const int w = t >> 6, l = t & 63;
  const int wm = (w >> 1) * 64, wn = (w & 1) * 64;
  const int lr = l & 15, lk = (l >> 4) * 8;
  f32x4 acc[4][4];
#pragma unroll
  for (int i = 0; i < 4; ++i)
#pragma unroll
    for (int j = 0; j < 4; ++j) acc[i][j] = (f32x4)0.f;

  for (int kb = 0; kb < K; kb += 32) {
    __syncthreads();
#pragma unroll
    for (int i = 0; i < 2; ++i) {
      const int idx = t + i * 256;
      const int row = idx >> 2, c8 = (idx & 3) * 8;
      *(uint4*)&ash[row][c8] = *(const uint4*)(Ahi + (size_t)(m0 + row) * K + kb + c8);
      *(uint4*)&als[row][c8] = *(const uint4*)(Alo + (size_t)(m0 + row) * K + kb + c8);
      *(uint4*)&bsh[row][c8] = *(const uint4*)(Bhi + (size_t)(n0 + row) * K + kb + c8);
      *(uint4*)&bls[row][c8] = *(const uint4*)(Blo + (size_t)(n0 + row) * K + kb + c8);
    }
    __syncthreads();
    bf16x8 ah[4], al[4], bh[4], bl[4];
#pragma unroll
    for (int mi = 0; mi < 4; ++mi) {
      ah[mi] = *(const bf16x8*)&ash[wm + mi * 16 + lr][lk];
      al[mi] = *(const bf16x8*)&als[wm + mi * 16 + lr][lk];
    }
#pragma unroll
    for (int ni = 0; ni < 4; ++ni) {
      bh[ni] = *(const bf16x8*)&bsh[wn + ni * 16 + lr][lk];
      bl[ni] = *(const bf16x8*)&bls[wn + ni * 16 + lr][lk];
    }
#pragma unroll
    for (int mi = 0; mi < 4; ++mi)
#pragma unroll
      for (int ni = 0; ni < 4; ++ni) {
        acc[mi][ni] = __builtin_amdgcn_mfma_f32_16x16x32_bf16(
            ah[mi], bh[ni], acc[mi][ni], 0, 0, 0);
        acc[mi][ni] = __builtin_amdgcn_mfma_f32_16x16x32_bf16(
            al[mi], bh[ni], acc[mi][ni], 0, 0, 0);
        acc[mi][ni] = __builtin_amdgcn_mfma_f32_16x16x32_bf16(
            ah[mi], bl[ni], acc[mi][ni], 0, 0, 0);
      }
  }
  // epilogue: D row = (l>>4)*4 + reg, col = lane&15  [m89-verified]
  const int rq = (l >> 4) * 4;
#pragma unroll
  for (int ni = 0; ni < 4; ++ni) {
    const int col = n0 + wn + ni * 16 + lr;
    const float bv = bias[col];
#pragma unroll
    for (int mi = 0; mi < 4; ++mi)
#pragma unroll
      for (int r = 0; r < 4; ++r) {
        const int row = m0 + wm + mi * 16 + rq + r;
        C[(size_t)row * N + col] = acc[mi][ni][r] + bv;
      }
  }
}

// ---------------------------------------------------------------------------
// RoPE + transpose [b][s][3][h][d] -> Q/K/V [bh][s][d].  Q pre-scaled by 1/8.
// ---------------------------------------------------------------------------
__global__ __launch_bounds__(256) void k2_rope(
    const float* __restrict__ qkv, float* __restrict__ Q,
    float* __restrict__ Kb, float* __restrict__ V) {
  const int g  = blockIdx.x * 256 + threadIdx.x;   // (bh, s)
  const int s  = g & (S - 1);
  const int bh = g >> 11;
  const int b  = bh >> 4, h = bh & 15;
  const float* base = qkv + ((size_t)b * S + s) * 3072 + h * 64;
  float q[64], k[64], v[64];
#pragma unroll
  for (int f = 0; f < 16; ++f) {
    const float4 x = *(const float4*)(base + f * 4);
    q[f*4+0]=x.x; q[f*4+1]=x.y; q[f*4+2]=x.z; q[f*4+3]=x.w;
    const float4 y = *(const float4*)(base + 1024 + f * 4);
    k[f*4+0]=y.x; k[f*4+1]=y.y; k[f*4+2]=y.z; k[f*4+3]=y.w;
    const float4 z = *(const float4*)(base + 2048 + f * 4);
    v[f*4+0]=z.x; v[f*4+1]=z.y; v[f*4+2]=z.z; v[f*4+3]=z.w;
  }
  // 10000^{j/8} = 10^{j/2}, correctly-rounded fp32 (matches numpy fp32 table)
  const float PW[8] = {1.0f, 3.1622776601683795f, 10.0f, 31.622776601683793f,
                       100.0f, 316.22776601683796f, 1000.0f, 3162.2776601683795f};
  float qr[16], kr[16];
#pragma unroll
  for (int d = 0; d < 16; ++d) {
    const int j = d & 7;
    const float invf = 1.0f / PW[j];
    const float fr = (float)s * invf;
    float sn, c;
    sincosf(fr, &sn, &c);
    const float rq = (d < 8) ? -q[d + 8] : q[d - 8];
    const float rk = (d < 8) ? -k[d + 8] : k[d - 8];
    qr[d] = q[d] * c + rq * sn;
    kr[d] = k[d] * c + rk * sn;
  }
#pragma unroll
  for (int d = 0; d < 16; ++d) { q[d] = qr[d]; k[d] = kr[d]; }
#pragma unroll
  for (int d = 0; d < 64; ++d) q[d] *= 0.125f;   // fold softmax scale into Q
  float* qd = Q  + (((size_t)bh * S + s) << 6);
  float* kd = Kb + (((size_t)bh * S + s) << 6);
  float* vd = V  + (((size_t)bh * S + s) << 6);
#pragma unroll
  for (int f = 0; f < 16; ++f) {
    *(float4*)(qd + f*4) = make_float4(q[f*4], q[f*4+1], q[f*4+2], q[f*4+3]);
    *(float4*)(kd + f*4) = make_float4(k[f*4], k[f*4+1], k[f*4+2], k[f*4+3]);
    *(float4*)(vd + f*4) = make_float4(v[f*4], v[f*4+1], v[f*4+2], v[f*4+3]);
  }
}

// ---------------------------------------------------------------------------
// Register-blocked score pass: per 128x128 causal block, E=exp(QK^T) row-sums
// -> partZ[bh][rb][cb][128]; raw diag score -> sdg. 8x8 microtiles.
// ---------------------------------------------------------------------------
__global__ __launch_bounds__(256) void k3_scores(
    const float* __restrict__ Q, const float* __restrict__ Kb,
    float* __restrict__ partZ, float* __restrict__ sdg) {
  const int cb = blockIdx.x, rb = blockIdx.y, bh = blockIdx.z;
  if (cb > rb) return;
  __shared__ float qs[64][132];    // Q^T tile [kk][row]
  __shared__ float ks[64][132];    // K^T tile [kk][col]
  __shared__ float red[128][17];
  const int t = threadIdx.x;
  const int tm = (t & 15) * 8, tn = (t >> 4) * 8;
  for (int v4 = t; v4 < 2048; v4 += 256) {
    const int r = v4 >> 4, f = v4 & 15;
    const float4 x = *(const float4*)(Q + (((size_t)bh*S + rb*128 + r) << 6) + f*4);
    qs[f*4+0][r]=x.x; qs[f*4+1][r]=x.y; qs[f*4+2][r]=x.z; qs[f*4+3][r]=x.w;
    const float4 y = *(const float4*)(Kb + (((size_t)bh*S + cb*128 + r) << 6) + f*4);
    ks[f*4+0][r]=y.x; ks[f*4+1][r]=y.y; ks[f*4+2][r]=y.z; ks[f*4+3][r]=y.w;
  }
  __syncthreads();
  float acc[8][8];
#pragma unroll
  for (int i = 0; i < 8; ++i)
#pragma unroll
    for (int j = 0; j < 8; ++j) acc[i][j] = 0.f;
#pragma unroll 4
  for (int kk = 0; kk < 64; ++kk) {
    const float4 a0 = *(const float4*)&qs[kk][tm];
    const float4 a1 = *(const float4*)&qs[kk][tm + 4];
    const float4 b0 = *(const float4*)&ks[kk][tn];
    const float4 b1 = *(const float4*)&ks[kk][tn + 4];
    const float av[8] = {a0.x, a0.y, a0.z, a0.w, a1.x, a1.y, a1.z, a1.w};
    const float bv[8] = {b0.x, b0.y, b0.z, b0.w, b1.x, b1.y, b1.z, b1.w};
#pragma unroll
    for (int i = 0; i < 8; ++i)
#pragma unroll
      for (int j = 0; j < 8; ++j) acc[i][j] += av[i] * bv[j];
  }
  // mask + exp + per-thread row sums; capture raw diag score
  const int rbase = rb * 128 + tm, cbase = cb * 128 + tn;
  float rs[8];
#pragma unroll
  for (int i = 0; i < 8; ++i) {
    rs[i] = 0.f;
    const int rG = rbase + i;
#pragma unroll
    for (int j = 0; j < 8; ++j) {
      const int cG = cbase + j;
      if (cG <= rG) {
        rs[i] += __expf(acc[i][j]);
        if (cG == rG) sdg[(size_t)bh * S + rG] = acc[i][j];
      }
    }
  }
  const int tnq = t >> 4;
#pragma unroll
  for (int i = 0; i < 8; ++i) red[tm + i][tnq] = rs[i];
  __syncthreads();
  if (t < 128) {
    float z = 0.f;
#pragma unroll
    for (int c = 0; c < 16; ++c) z += red[t][c];
    partZ[(((size_t)bh*16 + rb)*16 + cb)*128 + t] = z;
  }
}

// ---------------------------------------------------------------------------
// Stats pass 2: Z = sum of partials over cb<=rb -> zinv; pd = exp(sd)*zinv.
// ---------------------------------------------------------------------------
__global__ __launch_bounds__(256) void k3_reduce(
    const float* __restrict__ partZ, float* __restrict__ zinv,
    float* __restrict__ pdg) {
  const int R = blockIdx.x * 256 + threadIdx.x;   // 0..BH*S-1
  const int bh = R >> 11, r = R & 2047;
  const int rb = r >> 7, row = r & 127;
  float Z = 0.f;
  for (int c = 0; c <= rb; ++c)
    Z += partZ[(((size_t)bh*16 + rb)*16 + c)*128 + row];
  const float zi = 1.f / Z;
  zinv[R] = zi;
  pdg[R] = __expf(pdg[R]) * zi;
}

// ---------------------------------------------------------------------------
// Per-64-block unit-lower-triangular inverse of (I - N), N = strict-lower P.
// Output TRANSPOSED: MinvT[bh][ib][j][r] = Minv[r][j].
// ---------------------------------------------------------------------------
__global__ __launch_bounds__(64) void k4_minv(
    const float* __restrict__ Q, const float* __restrict__ Kb,
    const float* __restrict__ zinv, float* __restrict__ MinvT) {
  const int bh = blockIdx.y, ib = blockIdx.x;
  const int r0 = ib * 64;
  __shared__ float qs[64][64];
  __shared__ float Nb[64][64];
  __shared__ float X[64][64];
  const int c = threadIdx.x;
  float kc[64];
#pragma unroll
  for (int f = 0; f < 16; ++f) {
    const float4 x = *(const float4*)(Kb + (((size_t)bh * S + r0 + c) << 6) + f * 4);
    kc[f*4+0]=x.x; kc[f*4+1]=x.y; kc[f*4+2]=x.z; kc[f*4+3]=x.w;
  }
  for (int v4 = c; v4 < 1024; v4 += 64) {
    const int r = v4 >> 4, f = v4 & 15;
    *(float4*)&qs[r][f*4] = *(const float4*)(Q + (((size_t)bh * S + r0 + r) << 6) + f * 4);
  }
  __syncthreads();
  for (int r = 0; r < 64; ++r) {
    float sdot = 0.f;
#pragma unroll
    for (int i4 = 0; i4 < 16; ++i4) {
      const float4 qv = *(const float4*)&qs[r][i4*4];
      sdot += qv.x*kc[i4*4] + qv.y*kc[i4*4+1] + qv.z*kc[i4*4+2] + qv.w*kc[i4*4+3];
    }
    Nb[r][c] = (c < r) ? __expf(sdot) * zinv[bh * S + r0 + r] : 0.f;
  }
  __syncthreads();
  for (int r = 0; r < 64; ++r) X[r][c] = (r == c) ? 1.f : 0.f;
  __syncthreads();
  for (int r = 1; r < 64; ++r) {         // forward substitution, X = (I-N)^-1
    float a = 0.f;
    for (int j = 0; j < r; ++j) a += Nb[r][j] * X[j][c];
    X[r][c] += a;
    __syncthreads();
  }
  float* dst = MinvT + (((size_t)bh * 32 + ib) * 64 + c) * 64;
  for (int r4 = 0; r4 < 64; r4 += 4) {
    float4 o; o.x = X[r4][c]; o.y = X[r4+1][c]; o.z = X[r4+2][c]; o.w = X[r4+3][c];
    *(float4*)(dst + r4) = o;
  }
}

// ---------------------------------------------------------------------------
// Scan step k off-diagonal accumulate (register-blocked, two 64-col halves):
// upart[bh][j] = P[k-rows, j-block] @ A_j.  8x4 microtiles both phases.
// ---------------------------------------------------------------------------
__global__ __launch_bounds__(256) void k5_acc(
    const float* __restrict__ Q, const float* __restrict__ Kb,
    const float* __restrict__ Abuf, const float* __restrict__ zinv,
    float* __restrict__ upart, int kstep) {
  const int bh = blockIdx.y, j = blockIdx.x;
  __shared__ float qs[64][132];    // Q^T [kk][r], rows base..base+127
  __shared__ float pt[64][132];    // P^T half [c][r]
  __shared__ float buf[64][68];    // K^T half [kk][c], then A half [c][d]
  const int t = threadIdx.x;
  const int tm = (t & 15) * 8, tn4 = (t >> 4) * 4;
  const int base = kstep * 128;
  for (int v4 = t; v4 < 2048; v4 += 256) {
    const int r = v4 >> 4, f = v4 & 15;
    const float4 x = *(const float4*)(Q + (((size_t)bh*S + base + r) << 6) + f*4);
    qs[f*4+0][r]=x.x; qs[f*4+1][r]=x.y; qs[f*4+2][r]=x.z; qs[f*4+3][r]=x.w;
  }
  float ziv[8];
#pragma unroll
  for (int i = 0; i < 8; ++i) ziv[i] = zinv[bh*S + base + tm + i];
  float out[8][4];
#pragma unroll
  for (int i = 0; i < 8; ++i)
#pragma unroll
    for (int jj = 0; jj < 4; ++jj) out[i][jj] = 0.f;

  for (int h = 0; h < 2; ++h) {
    __syncthreads();     // covers qs staging (h=0) / pt+buf reuse (h=1)
    for (int v4 = t; v4 < 1024; v4 += 256) {      // K^T half
      const int c = v4 >> 4, f = v4 & 15;
      const float4 y = *(const float4*)(Kb + (((size_t)bh*S + j*128 + h*64 + c) << 6) + f*4);
      buf[f*4+0][c]=y.x; buf[f*4+1][c]=y.y; buf[f*4+2][c]=y.z; buf[f*4+3][c]=y.w;
    }
    __syncthreads();
    float qk[8][4];
#pragma unroll
    for (int i = 0; i < 8; ++i)
#pragma unroll
      for (int jj = 0; jj < 4; ++jj) qk[i][jj] = 0.f;
#pragma unroll 4
    for (int kk = 0; kk < 64; ++kk) {
      const float4 a0 = *(const float4*)&qs[kk][tm];
      const float4 a1 = *(const float4*)&qs[kk][tm + 4];
      const float4 b  = *(const float4*)&buf[kk][tn4];
      const float av[8] = {a0.x, a0.y, a0.z, a0.w, a1.x, a1.y, a1.z, a1.w};
      const float bv[4] = {b.x, b.y, b.z, b.w};
#pragma unroll
      for (int i = 0; i < 8; ++i)
#pragma unroll
        for (int jj = 0; jj < 4; ++jj) qk[i][jj] += av[i] * bv[jj];
    }
#pragma unroll
    for (int i = 0; i < 8; ++i)
#pragma unroll
      for (int jj = 0; jj < 4; ++jj)
        pt[tn4 + jj][tm + i] = __expf(qk[i][jj]) * ziv[i];
    __syncthreads();
    for (int v4 = t; v4 < 1024; v4 += 256) {      // A half (row-major)
      const int c = v4 >> 4, f = v4 & 15;
      *(float4*)&buf[c][f*4] =
        *(const float4*)(Abuf + (((size_t)bh*S + j*128 + h*64 + c) << 6) + f*4);
    }
    __syncthreads();
#pragma unroll 4
    for (int c = 0; c < 64; ++c) {
      const float4 p0 = *(const float4*)&pt[c][tm];
      const float4 p1 = *(const float4*)&pt[c][tm + 4];
      const float4 a  = *(const float4*)&buf[c][tn4];
      const float pv[8] = {p0.x, p0.y, p0.z, p0.w, p1.x, p1.y, p1.z, p1.w};
      const float avv[4] = {a.x, a.y, a.z, a.w};
#pragma unroll
      for (int i = 0; i < 8; ++i)
#pragma unroll
        for (int jj = 0; jj < 4; ++jj) out[i][jj] += pv[i] * avv[jj];
    }
  }
#pragma unroll
  for (int i = 0; i < 8; ++i)
    *(float4*)(upart + ((((size_t)bh*15 + j)*128 + tm + i) << 6) + tn4) =
        make_float4(out[i][0], out[i][1], out[i][2], out[i][3]);
}

// ---------------------------------------------------------------------------
// Scan step k finalize, parallel over 16-d chunks (grid 4 x BH):
//   u = pd*v + sum(upart);  A_lo = Minv@u_lo (kept in LDS);
//   u_hi += P(hi,lo)@A_lo;  A_hi = Minv@u_hi.
// ---------------------------------------------------------------------------
__global__ __launch_bounds__(256) void k5_fin(
    const float* __restrict__ Q, const float* __restrict__ Kb,
    const float* __restrict__ V, const float* __restrict__ pd,
    const float* __restrict__ zinv, const float* __restrict__ upart,
    const float* __restrict__ MinvT, float* __restrict__ Abuf, int kstep) {
  const int dc0 = blockIdx.x * 16;
  const int bh  = blockIdx.y;
  const int t = threadIdx.x;
  const int base = kstep * 128;
  __shared__ float u[128][16];
  __shared__ float alo[64][17];
  __shared__ float kst[64][68];     // MinvT / K staging (sequential reuse)
  __shared__ float pbuf[64][65];

  // phase 0: u = pd*v + sum partials (this d-chunk); stage MinvT(2k)
  for (int v4 = t; v4 < 512; v4 += 256) {
    const int r = v4 >> 2, f = v4 & 3;
    const int R = base + r;
    const float4 x = *(const float4*)(V + (((size_t)bh*S + R) << 6) + dc0 + f*4);
    const float p = pd[bh*S + R];
    float a0 = p*x.x, a1 = p*x.y, a2 = p*x.z, a3 = p*x.w;
    for (int j = 0; j < kstep; ++j) {
      const float4 y = *(const float4*)(upart + ((((size_t)bh*15 + j)*128 + r) << 6) + dc0 + f*4);
      a0 += y.x; a1 += y.y; a2 += y.z; a3 += y.w;
    }
    *(float4*)&u[r][f*4] = make_float4(a0, a1, a2, a3);
  }
  for (int v4 = t; v4 < 1024; v4 += 256) {
    const int j = v4 >> 4, f = v4 & 15;
    *(float4*)&kst[j][f*4] =
      *(const float4*)(MinvT + ((((size_t)bh*32 + kstep*2)*64 + j) << 6) + f*4);
  }
  __syncthreads();
  // phase 1: A_lo = Minv @ u_lo (this d-chunk); keep in LDS + write global
  {
    const int r = t & 63, dq = (t >> 6) * 4;
    float a0=0.f, a1=0.f, a2=0.f, a3=0.f;
    for (int j = 0; j < 64; ++j) {
      const float w = kst[j][r];
      a0 += w*u[j][dq];   a1 += w*u[j][dq+1];
      a2 += w*u[j][dq+2]; a3 += w*u[j][dq+3];
    }
    alo[r][dq] = a0; alo[r][dq+1] = a1; alo[r][dq+2] = a2; alo[r][dq+3] = a3;
    *(float4*)(Abuf + (((size_t)bh*S + base + r) << 6) + dc0 + dq) =
        make_float4(a0, a1, a2, a3);
  }
  __syncthreads();
  for (int v4 = t; v4 < 1024; v4 += 256) {   // stage K rows [base, base+64)
    const int j = v4 >> 4, f = v4 & 15;
    *(float4*)&kst[j][f*4] = *(const float4*)(Kb + (((size_t)bh*S + base + j) << 6) + f*4);
  }
  __syncthreads();
  // phase 2a: pbuf[r][j] = exp(q_{base+64+r} . k_j) * zi  (dots computed once)
  {
    const int rp = t >> 2, c4 = t & 3;
    const int R = base + 64 + rp;
    float q[64];
    const float* qp = Q + (((size_t)bh*S + R) << 6);
#pragma unroll
    for (int f = 0; f < 16; ++f) {
      const float4 x = *(const float4*)(qp + f*4);
      q[f*4]=x.x; q[f*4+1]=x.y; q[f*4+2]=x.z; q[f*4+3]=x.w;
    }
    const float zi = zinv[bh*S + R];
    for (int j = c4; j < 64; j += 4) {
      float s = 0.f;
#pragma unroll
      for (int i4 = 0; i4 < 16; ++i4) {
        const float4 kv = *(const float4*)&kst[j][i4*4];
        s += q[i4*4]*kv.x + q[i4*4+1]*kv.y + q[i4*4+2]*kv.z + q[i4*4+3]*kv.w;
      }
      pbuf[rp][j] = __expf(s) * zi;
    }
  }
  __syncthreads();
  // phase 2b: u_hi += P @ A_lo (this d-chunk, A_lo from LDS)
  {
    const int r = t & 63, dq = (t >> 6) * 4;
    float a0=0.f, a1=0.f, a2=0.f, a3=0.f;
    for (int j = 0; j < 64; ++j) {
      const float p = pbuf[r][j];
      a0 += p*alo[j][dq];   a1 += p*alo[j][dq+1];
      a2 += p*alo[j][dq+2]; a3 += p*alo[j][dq+3];
    }
    u[64+r][dq] += a0; u[64+r][dq+1] += a1;
    u[64+r][dq+2] += a2; u[64+r][dq+3] += a3;
  }
  __syncthreads();
  for (int v4 = t; v4 < 1024; v4 += 256) {   // stage MinvT(2k+1)
    const int j = v4 >> 4, f = v4 & 15;
    *(float4*)&kst[j][f*4] =
      *(const float4*)(MinvT + ((((size_t)bh*32 + kstep*2 + 1)*64 + j) << 6) + f*4);
  }
  __syncthreads();
  // phase 3: A_hi = Minv @ u_hi
  {
    const int r = t & 63, dq = (t >> 6) * 4;
    float a0=0.f, a1=0.f, a2=0.f, a3=0.f;
    for (int j = 0; j < 64; ++j) {
      const float w = kst[j][r];
      a0 += w*u[64+j][dq];   a1 += w*u[64+j][dq+1];
      a2 += w*u[64+j][dq+2]; a3 += w*u[64+j][dq+3];
    }
    *(float4*)(Abuf + (((size_t)bh*S + base + 64 + r) << 6) + dc0 + dq) =
        make_float4(a0, a1, a2, a3);
  }
}

} // namespace

extern "C" void kernel_launch(void* const* d_in, const int* in_sizes, int n_in,
                              void* d_out, int out_size, void* d_ws, size_t ws_size,
                              hipStream_t stream) {
  const float* hs   = (const float*)d_in[0];
  const float* Wqkv = (const float*)d_in[1];
  const float* bqkv = (const float*)d_in[2];
  const float* Wd   = (const float*)d_in[3];
  const float* bd   = (const float*)d_in[4];
  float* out = (float*)d_out;
  float* W   = (float*)d_ws;
  if (ws_size < WS_FLOATS * sizeof(float)) return;  // insufficient scratch

  float* qkv   = W + OFF_QKV;
  float* partZ = W + OFF_PART;   // lives between rope and k4_minv
  float* MinvT = W + OFF_MINV;
  float* Abuf  = W + OFF_A;
  float* Qb    = W + OFF_Q;
  float* Kbuf  = W + OFF_K;
  float* Vb    = W + OFF_V;
  float* zi    = W + OFF_ZI;
  float* pdg   = W + OFF_PD;
  float* up    = W + OFF_UP;

  // bf16 split scratch, overlapping regions that are dead at time of use:
  //  - pre-QKV: Q region (bytes 50331648..67108864) holds Ahi/Alo;
  //             K region (67108864..) holds Whi/Wlo.  k2_rope overwrites later.
  //  - post-scan: same regions hold A2hi/A2lo and Wdhi/Wdlo (Q/K dead).
  char* wsb = (char*)d_ws;
  short* Ahi  = (short*)(wsb + 50331648);
  short* Alo  = Ahi + 4194304;                 // 4096x1024
  short* Whi  = (short*)(wsb + 67108864);
  short* Wlo  = Whi + 3145728;                 // 3072x1024
  short* A2hi = (short*)(wsb + 50331648);
  short* A2lo = A2hi + 4194304;
  short* Wdhi = (short*)(wsb + 67108864);
  short* Wdlo = Wdhi + 1048576;                // 1024x1024

  split2<<<dim3(2048), 256, 0, stream>>>(hs, Ahi, Alo, B*S*HID/4);
  split2<<<dim3(2048), 256, 0, stream>>>(Wqkv, Whi, Wlo, 3*HID*HID/4);
  gemm_bf3<<<dim3(24, 32), 256, 0, stream>>>(Ahi, Alo, Whi, Wlo, bqkv, qkv,
                                             B*S, 3*HID, HID);
  k2_rope<<<dim3(BH * S / 256), 256, 0, stream>>>(qkv, Qb, Kbuf, Vb);
  k3_scores<<<dim3(16, 16, BH), 256, 0, stream>>>(Qb, Kbuf, partZ, pdg);
  k3_reduce<<<dim3(BH * S / 256), 256, 0, stream>>>(partZ, zi, pdg);
  k4_minv<<<dim3(S / 64, BH), 64, 0, stream>>>(Qb, Kbuf, zi, MinvT);
  for (int k = 0; k < NSTEP; ++k) {
    if (k > 0)
      k5_acc<<<dim3(k, BH), 256, 0, stream>>>(Qb, Kbuf, Abuf, zi, up, k);
    k5_fin<<<dim3(4, BH), 256, 0, stream>>>(Qb, Kbuf, Vb, pdg, zi, up, MinvT, Abuf, k);
  }
  split_gather<<<dim3(2048), 256, 0, stream>>>(Abuf, A2hi, A2lo);
  split2<<<dim3(2048), 256, 0, stream>>>(Wd, Wdhi, Wdlo, HID*HID/4);
  gemm_bf3<<<dim3(8, 32), 256, 0, stream>>>(A2hi, A2lo, Wdhi, Wdlo, bd, out,
                                            B*S, HID, HID);
}

// Round 5
// 1342.629 us; speedup vs baseline: 2.4971x; 1.0596x over previous
//
#include <hip/hip_runtime.h>
#include <math.h>

namespace {

constexpr int B  = 2, S = 2048, NH = 16, HD = 64, HID = 1024;
constexpr int BH = B * NH;          // 32
constexpr int NSTEP = 16;           // 128-row scan blocks

// ws layout in floats.
constexpr size_t OFF_QKV  = 0;
constexpr size_t OFF_PART = 0;                 // [BH][16][16][128] Z partials
constexpr size_t OFF_MINV = 0;                 // [BH][32][64][64]
constexpr size_t OFF_A    = 4194304;           // [BH][S][HD]
constexpr size_t OFF_Q    = 12582912;          // Qhi/Qlo bf16 pairs (8MB+8MB)
constexpr size_t OFF_K    = 16777216;          // Khi/Klo bf16 pairs
constexpr size_t OFF_V    = 20971520;          // fp32 V
constexpr size_t OFF_ZI   = 25231360;          // [BH*S]
constexpr size_t OFF_PD   = 25296896;          // [BH*S]
constexpr size_t OFF_UP   = 25362432;          // [BH][15][128][64]
constexpr size_t WS_FLOATS = 29294592;         // ~117 MB

typedef __attribute__((ext_vector_type(8))) short bf16x8;
typedef __attribute__((ext_vector_type(4))) float f32x4;

__device__ inline unsigned short bf_rne(float x) {
  const unsigned u = __float_as_uint(x);
  return (unsigned short)((u + 0x7FFFu + ((u >> 16) & 1u)) >> 16);
}
__device__ inline float bf2f(short h) {
  return __uint_as_float((unsigned)(unsigned short)h << 16);
}
// load 4 fp32 reconstructed from hi/lo bf16 arrays at element offset off
__device__ inline float4 ld_hl4(const short* __restrict__ hi,
                                const short* __restrict__ lo, size_t off) {
  const short4 h = *(const short4*)(hi + off);
  const short4 l = *(const short4*)(lo + off);
  return make_float4(bf2f(h.x) + bf2f(l.x), bf2f(h.y) + bf2f(l.y),
                     bf2f(h.z) + bf2f(l.z), bf2f(h.w) + bf2f(l.w));
}

// ---------------------------------------------------------------------------
// Split fp32 -> (hi, lo) bf16 arrays.  n4 = element_count / 4.
// ---------------------------------------------------------------------------
__global__ __launch_bounds__(256) void split2(
    const float* __restrict__ in, short* __restrict__ hi,
    short* __restrict__ lo, int n4) {
  for (int g = blockIdx.x * 256 + threadIdx.x; g < n4; g += gridDim.x * 256) {
    const float4 x = *(const float4*)(in + (size_t)g * 4);
    short4 h, l;
    h.x = bf_rne(x.x); h.y = bf_rne(x.y); h.z = bf_rne(x.z); h.w = bf_rne(x.w);
    l.x = bf_rne(x.x - bf2f(h.x));
    l.y = bf_rne(x.y - bf2f(h.y));
    l.z = bf_rne(x.z - bf2f(h.z));
    l.w = bf_rne(x.w - bf2f(h.w));
    *(short4*)(hi + (size_t)g * 4) = h;
    *(short4*)(lo + (size_t)g * 4) = l;
  }
}

// ---------------------------------------------------------------------------
// Gather attn output [bh][s][d] -> [m=(b,s)][k=(h,d)] and split to hi/lo bf16.
// ---------------------------------------------------------------------------
__global__ __launch_bounds__(256) void split_gather(
    const float* __restrict__ Abuf, short* __restrict__ hi,
    short* __restrict__ lo) {
  const int n4 = B * S * HID / 4;
  for (int g = blockIdx.x * 256 + threadIdx.x; g < n4; g += gridDim.x * 256) {
    const int m = g >> 8, q = g & 255;
    const int k0 = q * 4;
    const int b = m >> 11, s = m & (S - 1);
    const int h = k0 >> 6, d = k0 & 63;
    const float4 x = *(const float4*)(Abuf + (((size_t)(b * NH + h) * S + s) << 6) + d);
    short4 hh, ll;
    hh.x = bf_rne(x.x); hh.y = bf_rne(x.y); hh.z = bf_rne(x.z); hh.w = bf_rne(x.w);
    ll.x = bf_rne(x.x - bf2f(hh.x));
    ll.y = bf_rne(x.y - bf2f(hh.y));
    ll.z = bf_rne(x.z - bf2f(hh.z));
    ll.w = bf_rne(x.w - bf2f(hh.w));
    *(short4*)(hi + (size_t)m * HID + k0) = hh;
    *(short4*)(lo + (size_t)m * HID + k0) = ll;
  }
}

// ---------------------------------------------------------------------------
// Split-bf16 MFMA NT GEMM: C = A @ B^T + bias (fp32 via 3 bf16 chains).
// ---------------------------------------------------------------------------
__global__ __launch_bounds__(256) void gemm_bf3(
    const short* __restrict__ Ahi, const short* __restrict__ Alo,
    const short* __restrict__ Bhi, const short* __restrict__ Blo,
    const float* __restrict__ bias, float* __restrict__ C,
    int M, int N, int K) {
  __shared__ short ash[128][40], als[128][40], bsh[128][40], bls[128][40];
  const int t = threadIdx.x;
  const int m0 = blockIdx.y * 128, n0 = blockIdx.x * 128;
  const int w = t >> 6, l = t & 63;
  const int wm = (w >> 1) * 64, wn = (w & 1) * 64;
  const int lr = l & 15, lk = (l >> 4) * 8;
  f32x4 acc[4][4];
#pragma unroll
  for (int i = 0; i < 4; ++i)
#pragma unroll
    for (int j = 0; j < 4; ++j) acc[i][j] = (f32x4)0.f;

  for (int kb = 0; kb < K; kb += 32) {
    __syncthreads();
#pragma unroll
    for (int i = 0; i < 2; ++i) {
      const int idx = t + i * 256;
      const int row = idx >> 2, c8 = (idx & 3) * 8;
      *(uint4*)&ash[row][c8] = *(const uint4*)(Ahi + (size_t)(m0 + row) * K + kb + c8);
      *(uint4*)&als[row][c8] = *(const uint4*)(Alo + (size_t)(m0 + row) * K + kb + c8);
      *(uint4*)&bsh[row][c8] = *(const uint4*)(Bhi + (size_t)(n0 + row) * K + kb + c8);
      *(uint4*)&bls[row][c8] = *(const uint4*)(Blo + (size_t)(n0 + row) * K + kb + c8);
    }
    __syncthreads();
    bf16x8 ah[4], al[4], bh[4], bl[4];
#pragma unroll
    for (int mi = 0; mi < 4; ++mi) {
      ah[mi] = *(const bf16x8*)&ash[wm + mi * 16 + lr][lk];
      al[mi] = *(const bf16x8*)&als[wm + mi * 16 + lr][lk];
    }
#pragma unroll
    for (int ni = 0; ni < 4; ++ni) {
      bh[ni] = *(const bf16x8*)&bsh[wn + ni * 16 + lr][lk];
      bl[ni] = *(const bf16x8*)&bls[wn + ni * 16 + lr][lk];
    }
#pragma unroll
    for (int mi = 0; mi < 4; ++mi)
#pragma unroll
      for (int ni = 0; ni < 4; ++ni) {
        acc[mi][ni] = __builtin_amdgcn_mfma_f32_16x16x32_bf16(
            ah[mi], bh[ni], acc[mi][ni], 0, 0, 0);
        acc[mi][ni] = __builtin_amdgcn_mfma_f32_16x16x32_bf16(
            al[mi], bh[ni], acc[mi][ni], 0, 0, 0);
        acc[mi][ni] = __builtin_amdgcn_mfma_f32_16x16x32_bf16(
            ah[mi], bl[ni], acc[mi][ni], 0, 0, 0);
      }
  }
  const int rq = (l >> 4) * 4;
#pragma unroll
  for (int ni = 0; ni < 4; ++ni) {
    const int col = n0 + wn + ni * 16 + lr;
    const float bv = bias[col];
#pragma unroll
    for (int mi = 0; mi < 4; ++mi)
#pragma unroll
      for (int r = 0; r < 4; ++r) {
        const int row = m0 + wm + mi * 16 + rq + r;
        C[(size_t)row * N + col] = acc[mi][ni][r] + bv;
      }
  }
}

// ---------------------------------------------------------------------------
// RoPE + transpose -> Qhi/Qlo, Khi/Klo (bf16 split, [bh][s][d]) + fp32 V.
// Q pre-scaled by 1/8.
// ---------------------------------------------------------------------------
__global__ __launch_bounds__(256) void k2_rope(
    const float* __restrict__ qkv, short* __restrict__ Qhi,
    short* __restrict__ Qlo, short* __restrict__ Khi,
    short* __restrict__ Klo, float* __restrict__ V) {
  const int g  = blockIdx.x * 256 + threadIdx.x;   // (bh, s)
  const int s  = g & (S - 1);
  const int bh = g >> 11;
  const int b  = bh >> 4, h = bh & 15;
  const float* base = qkv + ((size_t)b * S + s) * 3072 + h * 64;
  float q[64], k[64], v[64];
#pragma unroll
  for (int f = 0; f < 16; ++f) {
    const float4 x = *(const float4*)(base + f * 4);
    q[f*4+0]=x.x; q[f*4+1]=x.y; q[f*4+2]=x.z; q[f*4+3]=x.w;
    const float4 y = *(const float4*)(base + 1024 + f * 4);
    k[f*4+0]=y.x; k[f*4+1]=y.y; k[f*4+2]=y.z; k[f*4+3]=y.w;
    const float4 z = *(const float4*)(base + 2048 + f * 4);
    v[f*4+0]=z.x; v[f*4+1]=z.y; v[f*4+2]=z.z; v[f*4+3]=z.w;
  }
  const float PW[8] = {1.0f, 3.1622776601683795f, 10.0f, 31.622776601683793f,
                       100.0f, 316.22776601683796f, 1000.0f, 3162.2776601683795f};
  float qr[16], kr[16];
#pragma unroll
  for (int d = 0; d < 16; ++d) {
    const int j = d & 7;
    const float invf = 1.0f / PW[j];
    const float fr = (float)s * invf;
    float sn, c;
    sincosf(fr, &sn, &c);
    const float rq = (d < 8) ? -q[d + 8] : q[d - 8];
    const float rk = (d < 8) ? -k[d + 8] : k[d - 8];
    qr[d] = q[d] * c + rq * sn;
    kr[d] = k[d] * c + rk * sn;
  }
#pragma unroll
  for (int d = 0; d < 16; ++d) { q[d] = qr[d]; k[d] = kr[d]; }
#pragma unroll
  for (int d = 0; d < 64; ++d) q[d] *= 0.125f;   // fold softmax scale into Q
  const size_t o = ((size_t)bh * S + s) << 6;
  float* vd = V + o;
#pragma unroll
  for (int f = 0; f < 16; ++f) {
    short4 qh, ql, kh, kl;
    const float* qq = q + f * 4;
    const float* kk = k + f * 4;
    qh.x = bf_rne(qq[0]); qh.y = bf_rne(qq[1]); qh.z = bf_rne(qq[2]); qh.w = bf_rne(qq[3]);
    ql.x = bf_rne(qq[0]-bf2f(qh.x)); ql.y = bf_rne(qq[1]-bf2f(qh.y));
    ql.z = bf_rne(qq[2]-bf2f(qh.z)); ql.w = bf_rne(qq[3]-bf2f(qh.w));
    kh.x = bf_rne(kk[0]); kh.y = bf_rne(kk[1]); kh.z = bf_rne(kk[2]); kh.w = bf_rne(kk[3]);
    kl.x = bf_rne(kk[0]-bf2f(kh.x)); kl.y = bf_rne(kk[1]-bf2f(kh.y));
    kl.z = bf_rne(kk[2]-bf2f(kh.z)); kl.w = bf_rne(kk[3]-bf2f(kh.w));
    *(short4*)(Qhi + o + f*4) = qh;
    *(short4*)(Qlo + o + f*4) = ql;
    *(short4*)(Khi + o + f*4) = kh;
    *(short4*)(Klo + o + f*4) = kl;
    *(float4*)(vd + f*4) = make_float4(v[f*4], v[f*4+1], v[f*4+2], v[f*4+3]);
  }
}

// ---------------------------------------------------------------------------
// MFMA score pass: per 128x128 causal block, rowsum(exp(QK^T)) -> partZ,
// raw diag score -> sdg.  Split-bf16, 4 waves x 64x64 quadrants.
// LDS rows padded to 72 shorts (144B stride -> 2-way bank alias, free).
// ---------------------------------------------------------------------------
__global__ __launch_bounds__(256) void k3_scores(
    const short* __restrict__ Qhi, const short* __restrict__ Qlo,
    const short* __restrict__ Khi, const short* __restrict__ Klo,
    float* __restrict__ partZ, float* __restrict__ sdg) {
  const int cb = blockIdx.x, rb = blockIdx.y, bh = blockIdx.z;
  if (cb > rb) return;
  __shared__ short qh[128][72], ql[128][72], kh[128][72], kl[128][72];
  __shared__ float red[128][2];
  const int t = threadIdx.x;
  const int w = t >> 6, l = t & 63;
  const int wm = (w >> 1) * 64, wn = (w & 1) * 64;
  const int lr = l & 15, lg = l >> 4;
  for (int v = t; v < 1024; v += 256) {
    const int r = v >> 3, c8 = (v & 7) * 8;
    const size_t gq = (((size_t)bh * S + rb * 128 + r) << 6) + c8;
    const size_t gk = (((size_t)bh * S + cb * 128 + r) << 6) + c8;
    *(uint4*)&qh[r][c8] = *(const uint4*)(Qhi + gq);
    *(uint4*)&ql[r][c8] = *(const uint4*)(Qlo + gq);
    *(uint4*)&kh[r][c8] = *(const uint4*)(Khi + gk);
    *(uint4*)&kl[r][c8] = *(const uint4*)(Klo + gk);
  }
  __syncthreads();
  f32x4 acc[4][4];
#pragma unroll
  for (int i = 0; i < 4; ++i)
#pragma unroll
    for (int j = 0; j < 4; ++j) acc[i][j] = (f32x4)0.f;
#pragma unroll
  for (int ks = 0; ks < 2; ++ks) {
    const int lk = ks * 32 + lg * 8;
    bf16x8 ah[4], al[4], bhf[4], blf[4];
#pragma unroll
    for (int mi = 0; mi < 4; ++mi) {
      ah[mi] = *(const bf16x8*)&qh[wm + mi * 16 + lr][lk];
      al[mi] = *(const bf16x8*)&ql[wm + mi * 16 + lr][lk];
    }
#pragma unroll
    for (int ni = 0; ni < 4; ++ni) {
      bhf[ni] = *(const bf16x8*)&kh[wn + ni * 16 + lr][lk];
      blf[ni] = *(const bf16x8*)&kl[wn + ni * 16 + lr][lk];
    }
#pragma unroll
    for (int mi = 0; mi < 4; ++mi)
#pragma unroll
      for (int ni = 0; ni < 4; ++ni) {
        acc[mi][ni] = __builtin_amdgcn_mfma_f32_16x16x32_bf16(
            ah[mi], bhf[ni], acc[mi][ni], 0, 0, 0);
        acc[mi][ni] = __builtin_amdgcn_mfma_f32_16x16x32_bf16(
            al[mi], bhf[ni], acc[mi][ni], 0, 0, 0);
        acc[mi][ni] = __builtin_amdgcn_mfma_f32_16x16x32_bf16(
            ah[mi], blf[ni], acc[mi][ni], 0, 0, 0);
      }
  }
  // epilogue: mask + exp + row sums (rows: (l>>4)*4 + r, cols: lane&15)
  const int rq = lg * 4;
  const int rowbase = rb * 128 + wm, colbase = cb * 128 + wn;
  float rp[4][4];
#pragma unroll
  for (int mi = 0; mi < 4; ++mi)
#pragma unroll
    for (int r = 0; r < 4; ++r) rp[mi][r] = 0.f;
#pragma unroll
  for (int mi = 0; mi < 4; ++mi)
#pragma unroll
    for (int ni = 0; ni < 4; ++ni)
#pragma unroll
      for (int r = 0; r < 4; ++r) {
        const int rG = rowbase + mi * 16 + rq + r;
        const int cG = colbase + ni * 16 + lr;
        if (cG <= rG) rp[mi][r] += __expf(acc[mi][ni][r]);
        if (cG == rG) sdg[(size_t)bh * S + rG] = acc[mi][ni][r];
      }
#pragma unroll
  for (int off = 1; off < 16; off <<= 1)
#pragma unroll
    for (int mi = 0; mi < 4; ++mi)
#pragma unroll
      for (int r = 0; r < 4; ++r)
        rp[mi][r] += __shfl_xor(rp[mi][r], off, 64);
  if (lr == 0)
#pragma unroll
    for (int mi = 0; mi < 4; ++mi)
#pragma unroll
      for (int r = 0; r < 4; ++r)
        red[wm + mi * 16 + rq + r][w & 1] = rp[mi][r];
  __syncthreads();
  if (t < 128)
    partZ[(((size_t)bh * 16 + rb) * 16 + cb) * 128 + t] = red[t][0] + red[t][1];
}

// ---------------------------------------------------------------------------
// Stats pass 2: Z = sum of partials over cb<=rb -> zinv; pd = exp(sd)*zinv.
// ---------------------------------------------------------------------------
__global__ __launch_bounds__(256) void k3_reduce(
    const float* __restrict__ partZ, float* __restrict__ zinv,
    float* __restrict__ pdg) {
  const int R = blockIdx.x * 256 + threadIdx.x;   // 0..BH*S-1
  const int bh = R >> 11, r = R & 2047;
  const int rb = r >> 7, row = r & 127;
  float Z = 0.f;
  for (int c = 0; c <= rb; ++c)
    Z += partZ[(((size_t)bh*16 + rb)*16 + c)*128 + row];
  const float zi = 1.f / Z;
  zinv[R] = zi;
  pdg[R] = __expf(pdg[R]) * zi;
}

// ---------------------------------------------------------------------------
// Per-64-block unit-lower-triangular inverse of (I - N), N = strict-lower P.
// Output TRANSPOSED: MinvT[bh][ib][j][r] = Minv[r][j].
// ---------------------------------------------------------------------------
__global__ __launch_bounds__(64) void k4_minv(
    const short* __restrict__ Qhi, const short* __restrict__ Qlo,
    const short* __restrict__ Khi, const short* __restrict__ Klo,
    const float* __restrict__ zinv, float* __restrict__ MinvT) {
  const int bh = blockIdx.y, ib = blockIdx.x;
  const int r0 = ib * 64;
  __shared__ float qs[64][64];
  __shared__ float Nb[64][64];
  __shared__ float X[64][64];
  const int c = threadIdx.x;
  float kc[64];
#pragma unroll
  for (int f = 0; f < 16; ++f) {
    const float4 x = ld_hl4(Khi, Klo, (((size_t)bh * S + r0 + c) << 6) + f * 4);
    kc[f*4+0]=x.x; kc[f*4+1]=x.y; kc[f*4+2]=x.z; kc[f*4+3]=x.w;
  }
  for (int v4 = c; v4 < 1024; v4 += 64) {
    const int r = v4 >> 4, f = v4 & 15;
    *(float4*)&qs[r][f*4] = ld_hl4(Qhi, Qlo, (((size_t)bh * S + r0 + r) << 6) + f * 4);
  }
  __syncthreads();
  for (int r = 0; r < 64; ++r) {
    float sdot = 0.f;
#pragma unroll
    for (int i4 = 0; i4 < 16; ++i4) {
      const float4 qv = *(const float4*)&qs[r][i4*4];
      sdot += qv.x*kc[i4*4] + qv.y*kc[i4*4+1] + qv.z*kc[i4*4+2] + qv.w*kc[i4*4+3];
    }
    Nb[r][c] = (c < r) ? __expf(sdot) * zinv[bh * S + r0 + r] : 0.f;
  }
  __syncthreads();
  for (int r = 0; r < 64; ++r) X[r][c] = (r == c) ? 1.f : 0.f;
  __syncthreads();
  for (int r = 1; r < 64; ++r) {         // forward substitution, X = (I-N)^-1
    float a = 0.f;
    for (int j = 0; j < r; ++j) a += Nb[r][j] * X[j][c];
    X[r][c] += a;
    __syncthreads();
  }
  float* dst = MinvT + (((size_t)bh * 32 + ib) * 64 + c) * 64;
  for (int r4 = 0; r4 < 64; r4 += 4) {
    float4 o; o.x = X[r4][c]; o.y = X[r4+1][c]; o.z = X[r4+2][c]; o.w = X[r4+3][c];
    *(float4*)(dst + r4) = o;
  }
}

// ---------------------------------------------------------------------------
// Scan step k off-diagonal accumulate (register-blocked, two 64-col halves):
// upart[bh][j] = P[k-rows, j-block] @ A_j.  8x4 microtiles both phases.
// ---------------------------------------------------------------------------
__global__ __launch_bounds__(256) void k5_acc(
    const short* __restrict__ Qhi, const short* __restrict__ Qlo,
    const short* __restrict__ Khi, const short* __restrict__ Klo,
    const float* __restrict__ Abuf, const float* __restrict__ zinv,
    float* __restrict__ upart, int kstep) {
  const int bh = blockIdx.y, j = blockIdx.x;
  __shared__ float qs[64][132];    // Q^T [kk][r], rows base..base+127
  __shared__ float pt[64][132];    // P^T half [c][r]
  __shared__ float buf[64][68];    // K^T half [kk][c], then A half [c][d]
  const int t = threadIdx.x;
  const int tm = (t & 15) * 8, tn4 = (t >> 4) * 4;
  const int base = kstep * 128;
  for (int v4 = t; v4 < 2048; v4 += 256) {
    const int r = v4 >> 4, f = v4 & 15;
    const float4 x = ld_hl4(Qhi, Qlo, (((size_t)bh*S + base + r) << 6) + f*4);
    qs[f*4+0][r]=x.x; qs[f*4+1][r]=x.y; qs[f*4+2][r]=x.z; qs[f*4+3][r]=x.w;
  }
  float ziv[8];
#pragma unroll
  for (int i = 0; i < 8; ++i) ziv[i] = zinv[bh*S + base + tm + i];
  float out[8][4];
#pragma unroll
  for (int i = 0; i < 8; ++i)
#pragma unroll
    for (int jj = 0; jj < 4; ++jj) out[i][jj] = 0.f;

  for (int h = 0; h < 2; ++h) {
    __syncthreads();     // covers qs staging (h=0) / pt+buf reuse (h=1)
    for (int v4 = t; v4 < 1024; v4 += 256) {      // K^T half
      const int c = v4 >> 4, f = v4 & 15;
      const float4 y = ld_hl4(Khi, Klo, (((size_t)bh*S + j*128 + h*64 + c) << 6) + f*4);
      buf[f*4+0][c]=y.x; buf[f*4+1][c]=y.y; buf[f*4+2][c]=y.z; buf[f*4+3][c]=y.w;
    }
    __syncthreads();
    float qk[8][4];
#pragma unroll
    for (int i = 0; i < 8; ++i)
#pragma unroll
      for (int jj = 0; jj < 4; ++jj) qk[i][jj] = 0.f;
#pragma unroll 4
    for (int kk = 0; kk < 64; ++kk) {
      const float4 a0 = *(const float4*)&qs[kk][tm];
      const float4 a1 = *(const float4*)&qs[kk][tm + 4];
      const float4 b  = *(const float4*)&buf[kk][tn4];
      const float av[8] = {a0.x, a0.y, a0.z, a0.w, a1.x, a1.y, a1.z, a1.w};
      const float bv[4] = {b.x, b.y, b.z, b.w};
#pragma unroll
      for (int i = 0; i < 8; ++i)
#pragma unroll
        for (int jj = 0; jj < 4; ++jj) qk[i][jj] += av[i] * bv[jj];
    }
#pragma unroll
    for (int i = 0; i < 8; ++i)
#pragma unroll
      for (int jj = 0; jj < 4; ++jj)
        pt[tn4 + jj][tm + i] = __expf(qk[i][jj]) * ziv[i];
    __syncthreads();
    for (int v4 = t; v4 < 1024; v4 += 256) {      // A half (row-major)
      const int c = v4 >> 4, f = v4 & 15;
      *(float4*)&buf[c][f*4] =
        *(const float4*)(Abuf + (((size_t)bh*S + j*128 + h*64 + c) << 6) + f*4);
    }
    __syncthreads();
#pragma unroll 4
    for (int c = 0; c < 64; ++c) {
      const float4 p0 = *(const float4*)&pt[c][tm];
      const float4 p1 = *(const float4*)&pt[c][tm + 4];
      const float4 a  = *(const float4*)&buf[c][tn4];
      const float pv[8] = {p0.x, p0.y, p0.z, p0.w, p1.x, p1.y, p1.z, p1.w};
      const float avv[4] = {a.x, a.y, a.z, a.w};
#pragma unroll
      for (int i = 0; i < 8; ++i)
#pragma unroll
        for (int jj = 0; jj < 4; ++jj) out[i][jj] += pv[i] * avv[jj];
    }
  }
#pragma unroll
  for (int i = 0; i < 8; ++i)
    *(float4*)(upart + ((((size_t)bh*15 + j)*128 + tm + i) << 6) + tn4) =
        make_float4(out[i][0], out[i][1], out[i][2], out[i][3]);
}

// ---------------------------------------------------------------------------
// Scan step k finalize, parallel over 16-d chunks (grid 4 x BH):
//   u = pd*v + sum(upart);  A_lo = Minv@u_lo (kept in LDS);
//   u_hi += P(hi,lo)@A_lo;  A_hi = Minv@u_hi.
// ---------------------------------------------------------------------------
__global__ __launch_bounds__(256) void k5_fin(
    const short* __restrict__ Qhi, const short* __restrict__ Qlo,
    const short* __restrict__ Khi, const short* __restrict__ Klo,
    const float* __restrict__ V, const float* __restrict__ pd,
    const float* __restrict__ zinv, const float* __restrict__ upart,
    const float* __restrict__ MinvT, float* __restrict__ Abuf, int kstep) {
  const int dc0 = blockIdx.x * 16;
  const int bh  = blockIdx.y;
  const int t = threadIdx.x;
  const int base = kstep * 128;
  __shared__ float u[128][16];
  __shared__ float alo[64][17];
  __shared__ float kst[64][68];     // MinvT / K staging (sequential reuse)
  __shared__ float pbuf[64][65];

  // phase 0: u = pd*v + sum partials (this d-chunk); stage MinvT(2k)
  for (int v4 = t; v4 < 512; v4 += 256) {
    const int r = v4 >> 2, f = v4 & 3;
    const int R = base + r;
    const float4 x = *(const float4*)(V + (((size_t)bh*S + R) << 6) + dc0 + f*4);
    const float p = pd[bh*S + R];
    float a0 = p*x.x, a1 = p*x.y, a2 = p*x.z, a3 = p*x.w;
    for (int j = 0; j < kstep; ++j) {
      const float4 y = *(const float4*)(upart + ((((size_t)bh*15 + j)*128 + r) << 6) + dc0 + f*4);
      a0 += y.x; a1 += y.y; a2 += y.z; a3 += y.w;
    }
    *(float4*)&u[r][f*4] = make_float4(a0, a1, a2, a3);
  }
  for (int v4 = t; v4 < 1024; v4 += 256) {
    const int j = v4 >> 4, f = v4 & 15;
    *(float4*)&kst[j][f*4] =
      *(const float4*)(MinvT + ((((size_t)bh*32 + kstep*2)*64 + j) << 6) + f*4);
  }
  __syncthreads();
  // phase 1: A_lo = Minv @ u_lo (this d-chunk); keep in LDS + write global
  {
    const int r = t & 63, dq = (t >> 6) * 4;
    float a0=0.f, a1=0.f, a2=0.f, a3=0.f;
    for (int j = 0; j < 64; ++j) {
      const float w = kst[j][r];
      a0 += w*u[j][dq];   a1 += w*u[j][dq+1];
      a2 += w*u[j][dq+2]; a3 += w*u[j][dq+3];
    }
    alo[r][dq] = a0; alo[r][dq+1] = a1; alo[r][dq+2] = a2; alo[r][dq+3] = a3;
    *(float4*)(Abuf + (((size_t)bh*S + base + r) << 6) + dc0 + dq) =
        make_float4(a0, a1, a2, a3);
  }
  __syncthreads();
  for (int v4 = t; v4 < 1024; v4 += 256) {   // stage K rows [base, base+64)
    const int j = v4 >> 4, f = v4 & 15;
    *(float4*)&kst[j][f*4] = ld_hl4(Khi, Klo, (((size_t)bh*S + base + j) << 6) + f*4);
  }
  __syncthreads();
  // phase 2a: pbuf[r][j] = exp(q_{base+64+r} . k_j) * zi  (dots computed once)
  {
    const int rp = t >> 2, c4 = t & 3;
    const int R = base + 64 + rp;
    float q[64];
#pragma unroll
    for (int f = 0; f < 16; ++f) {
      const float4 x = ld_hl4(Qhi, Qlo, (((size_t)bh*S + R) << 6) + f*4);
      q[f*4]=x.x; q[f*4+1]=x.y; q[f*4+2]=x.z; q[f*4+3]=x.w;
    }
    const float zi = zinv[bh*S + R];
    for (int j = c4; j < 64; j += 4) {
      float s = 0.f;
#pragma unroll
      for (int i4 = 0; i4 < 16; ++i4) {
        const float4 kv = *(const float4*)&kst[j][i4*4];
        s += q[i4*4]*kv.x + q[i4*4+1]*kv.y + q[i4*4+2]*kv.z + q[i4*4+3]*kv.w;
      }
      pbuf[rp][j] = __expf(s) * zi;
    }
  }
  __syncthreads();
  // phase 2b: u_hi += P @ A_lo (this d-chunk, A_lo from LDS)
  {
    const int r = t & 63, dq = (t >> 6) * 4;
    float a0=0.f, a1=0.f, a2=0.f, a3=0.f;
    for (int j = 0; j < 64; ++j) {
      const float p = pbuf[r][j];
      a0 += p*alo[j][dq];   a1 += p*alo[j][dq+1];
      a2 += p*alo[j][dq+2]; a3 += p*alo[j][dq+3];
    }
    u[64+r][dq] += a0; u[64+r][dq+1] += a1;
    u[64+r][dq+2] += a2; u[64+r][dq+3] += a3;
  }
  __syncthreads();
  for (int v4 = t; v4 < 1024; v4 += 256) {   // stage MinvT(2k+1)
    const int j = v4 >> 4, f = v4 & 15;
    *(float4*)&kst[j][f*4] =
      *(const float4*)(MinvT + ((((size_t)bh*32 + kstep*2 + 1)*64 + j) << 6) + f*4);
  }
  __syncthreads();
  // phase 3: A_hi = Minv @ u_hi
  {
    const int r = t & 63, dq = (t >> 6) * 4;
    float a0=0.f, a1=0.f, a2=0.f, a3=0.f;
    for (int j = 0; j < 64; ++j) {
      const float w = kst[j][r];
      a0 += w*u[64+j][dq];   a1 += w*u[64+j][dq+1];
      a2 += w*u[64+j][dq+2]; a3 += w*u[64+j][dq+3];
    }
    *(float4*)(Abuf + (((size_t)bh*S + base + 64 + r) << 6) + dc0 + dq) =
        make_float4(a0, a1, a2, a3);
  }
}

} // namespace

extern "C" void kernel_launch(void* const* d_in, const int* in_sizes, int n_in,
                              void* d_out, int out_size, void* d_ws, size_t ws_size,
                              hipStream_t stream) {
  const float* hs   = (const float*)d_in[0];
  const float* Wqkv = (const float*)d_in[1];
  const float* bqkv = (const float*)d_in[2];
  const float* Wd   = (const float*)d_in[3];
  const float* bd   = (const float*)d_in[4];
  float* out = (float*)d_out;
  float* W   = (float*)d_ws;
  if (ws_size < WS_FLOATS * sizeof(float)) return;  // insufficient scratch

  float* qkv   = W + OFF_QKV;
  float* partZ = W + OFF_PART;
  float* MinvT = W + OFF_MINV;
  float* Abuf  = W + OFF_A;
  short* Qhi   = (short*)(W + OFF_Q);
  short* Qlo   = Qhi + 4194304;
  short* Khi   = (short*)(W + OFF_K);
  short* Klo   = Khi + 4194304;
  float* Vb    = W + OFF_V;
  float* zi    = W + OFF_ZI;
  float* pdg   = W + OFF_PD;
  float* up    = W + OFF_UP;

  // bf16 split scratch in regions dead at time of use (Q/K regions pre-rope,
  // same regions post-scan).
  char* wsb = (char*)d_ws;
  short* Ahi  = (short*)(wsb + 50331648);
  short* Alo  = Ahi + 4194304;                 // 4096x1024
  short* Whi  = (short*)(wsb + 67108864);
  short* Wlo  = Whi + 3145728;                 // 3072x1024
  short* A2hi = (short*)(wsb + 50331648);
  short* A2lo = A2hi + 4194304;
  short* Wdhi = (short*)(wsb + 67108864);
  short* Wdlo = Wdhi + 1048576;                // 1024x1024

  split2<<<dim3(2048), 256, 0, stream>>>(hs, Ahi, Alo, B*S*HID/4);
  split2<<<dim3(2048), 256, 0, stream>>>(Wqkv, Whi, Wlo, 3*HID*HID/4);
  gemm_bf3<<<dim3(24, 32), 256, 0, stream>>>(Ahi, Alo, Whi, Wlo, bqkv, qkv,
                                             B*S, 3*HID, HID);
  k2_rope<<<dim3(BH * S / 256), 256, 0, stream>>>(qkv, Qhi, Qlo, Khi, Klo, Vb);
  k3_scores<<<dim3(16, 16, BH), 256, 0, stream>>>(Qhi, Qlo, Khi, Klo, partZ, pdg);
  k3_reduce<<<dim3(BH * S / 256), 256, 0, stream>>>(partZ, zi, pdg);
  k4_minv<<<dim3(S / 64, BH), 64, 0, stream>>>(Qhi, Qlo, Khi, Klo, zi, MinvT);
  for (int k = 0; k < NSTEP; ++k) {
    if (k > 0)
      k5_acc<<<dim3(k, BH), 256, 0, stream>>>(Qhi, Qlo, Khi, Klo, Abuf, zi, up, k);
    k5_fin<<<dim3(4, BH), 256, 0, stream>>>(Qhi, Qlo, Khi, Klo, Vb, pdg, zi, up,
                                            MinvT, Abuf, k);
  }
  split_gather<<<dim3(2048), 256, 0, stream>>>(Abuf, A2hi, A2lo);
  split2<<<dim3(2048), 256, 0, stream>>>(Wd, Wdhi, Wdlo, HID*HID/4);
  gemm_bf3<<<dim3(8, 32), 256, 0, stream>>>(A2hi, A2lo, Wdhi, Wdlo, bd, out,
                                            B*S, HID, HID);
}

// Round 6
// 1237.296 us; speedup vs baseline: 2.7097x; 1.0851x over previous
//
#include <hip/hip_runtime.h>
#include <math.h>

namespace {

constexpr int B  = 2, S = 2048, NH = 16, HD = 64, HID = 1024;
constexpr int BH = B * NH;          // 32
constexpr int NSTEP = 16;           // 128-row scan blocks

// ws layout in floats.
constexpr size_t OFF_QKV  = 0;
constexpr size_t OFF_PART = 0;                 // [BH][16][16][128] Z partials
constexpr size_t OFF_MINV = 0;                 // [BH][32][64][64]
constexpr size_t OFF_A    = 4194304;           // [BH][S][HD]
constexpr size_t OFF_Q    = 12582912;          // Qhi/Qlo bf16 pairs (8MB+8MB)
constexpr size_t OFF_K    = 16777216;          // Khi/Klo bf16 pairs
constexpr size_t OFF_V    = 20971520;          // fp32 V
constexpr size_t OFF_ZI   = 25231360;          // [BH*S]
constexpr size_t OFF_PD   = 25296896;          // [BH*S]
constexpr size_t OFF_UP   = 25362432;          // [BH][15][128][64]
constexpr size_t WS_FLOATS = 29294592;         // ~117 MB

typedef __attribute__((ext_vector_type(8))) short bf16x8;
typedef __attribute__((ext_vector_type(4))) float f32x4;

__device__ inline unsigned short bf_rne(float x) {
  const unsigned u = __float_as_uint(x);
  return (unsigned short)((u + 0x7FFFu + ((u >> 16) & 1u)) >> 16);
}
__device__ inline float bf2f(short h) {
  return __uint_as_float((unsigned)(unsigned short)h << 16);
}
// load 4 fp32 reconstructed from hi/lo bf16 arrays at element offset off
__device__ inline float4 ld_hl4(const short* __restrict__ hi,
                                const short* __restrict__ lo, size_t off) {
  const short4 h = *(const short4*)(hi + off);
  const short4 l = *(const short4*)(lo + off);
  return make_float4(bf2f(h.x) + bf2f(l.x), bf2f(h.y) + bf2f(l.y),
                     bf2f(h.z) + bf2f(l.z), bf2f(h.w) + bf2f(l.w));
}

// ---------------------------------------------------------------------------
// Split fp32 -> (hi, lo) bf16 arrays.  n4 = element_count / 4.
// ---------------------------------------------------------------------------
__global__ __launch_bounds__(256) void split2(
    const float* __restrict__ in, short* __restrict__ hi,
    short* __restrict__ lo, int n4) {
  for (int g = blockIdx.x * 256 + threadIdx.x; g < n4; g += gridDim.x * 256) {
    const float4 x = *(const float4*)(in + (size_t)g * 4);
    short4 h, l;
    h.x = bf_rne(x.x); h.y = bf_rne(x.y); h.z = bf_rne(x.z); h.w = bf_rne(x.w);
    l.x = bf_rne(x.x - bf2f(h.x));
    l.y = bf_rne(x.y - bf2f(h.y));
    l.z = bf_rne(x.z - bf2f(h.z));
    l.w = bf_rne(x.w - bf2f(h.w));
    *(short4*)(hi + (size_t)g * 4) = h;
    *(short4*)(lo + (size_t)g * 4) = l;
  }
}

// ---------------------------------------------------------------------------
// Gather attn output [bh][s][d] -> [m=(b,s)][k=(h,d)] and split to hi/lo bf16.
// ---------------------------------------------------------------------------
__global__ __launch_bounds__(256) void split_gather(
    const float* __restrict__ Abuf, short* __restrict__ hi,
    short* __restrict__ lo) {
  const int n4 = B * S * HID / 4;
  for (int g = blockIdx.x * 256 + threadIdx.x; g < n4; g += gridDim.x * 256) {
    const int m = g >> 8, q = g & 255;
    const int k0 = q * 4;
    const int b = m >> 11, s = m & (S - 1);
    const int h = k0 >> 6, d = k0 & 63;
    const float4 x = *(const float4*)(Abuf + (((size_t)(b * NH + h) * S + s) << 6) + d);
    short4 hh, ll;
    hh.x = bf_rne(x.x); hh.y = bf_rne(x.y); hh.z = bf_rne(x.z); hh.w = bf_rne(x.w);
    ll.x = bf_rne(x.x - bf2f(hh.x));
    ll.y = bf_rne(x.y - bf2f(hh.y));
    ll.z = bf_rne(x.z - bf2f(hh.z));
    ll.w = bf_rne(x.w - bf2f(hh.w));
    *(short4*)(hi + (size_t)m * HID + k0) = hh;
    *(short4*)(lo + (size_t)m * HID + k0) = ll;
  }
}

// ---------------------------------------------------------------------------
// Split-bf16 MFMA NT GEMM: C = A @ B^T + bias (fp32 via 3 bf16 chains).
// ---------------------------------------------------------------------------
__global__ __launch_bounds__(256) void gemm_bf3(
    const short* __restrict__ Ahi, const short* __restrict__ Alo,
    const short* __restrict__ Bhi, const short* __restrict__ Blo,
    const float* __restrict__ bias, float* __restrict__ C,
    int M, int N, int K) {
  __shared__ short ash[128][40], als[128][40], bsh[128][40], bls[128][40];
  const int t = threadIdx.x;
  const int m0 = blockIdx.y * 128, n0 = blockIdx.x * 128;
  const int w = t >> 6, l = t & 63;
  const int wm = (w >> 1) * 64, wn = (w & 1) * 64;
  const int lr = l & 15, lk = (l >> 4) * 8;
  f32x4 acc[4][4];
#pragma unroll
  for (int i = 0; i < 4; ++i)
#pragma unroll
    for (int j = 0; j < 4; ++j) acc[i][j] = (f32x4)0.f;

  for (int kb = 0; kb < K; kb += 32) {
    __syncthreads();
#pragma unroll
    for (int i = 0; i < 2; ++i) {
      const int idx = t + i * 256;
      const int row = idx >> 2, c8 = (idx & 3) * 8;
      *(uint4*)&ash[row][c8] = *(const uint4*)(Ahi + (size_t)(m0 + row) * K + kb + c8);
      *(uint4*)&als[row][c8] = *(const uint4*)(Alo + (size_t)(m0 + row) * K + kb + c8);
      *(uint4*)&bsh[row][c8] = *(const uint4*)(Bhi + (size_t)(n0 + row) * K + kb + c8);
      *(uint4*)&bls[row][c8] = *(const uint4*)(Blo + (size_t)(n0 + row) * K + kb + c8);
    }
    __syncthreads();
    bf16x8 ah[4], al[4], bh[4], bl[4];
#pragma unroll
    for (int mi = 0; mi < 4; ++mi) {
      ah[mi] = *(const bf16x8*)&ash[wm + mi * 16 + lr][lk];
      al[mi] = *(const bf16x8*)&als[wm + mi * 16 + lr][lk];
    }
#pragma unroll
    for (int ni = 0; ni < 4; ++ni) {
      bh[ni] = *(const bf16x8*)&bsh[wn + ni * 16 + lr][lk];
      bl[ni] = *(const bf16x8*)&bls[wn + ni * 16 + lr][lk];
    }
#pragma unroll
    for (int mi = 0; mi < 4; ++mi)
#pragma unroll
      for (int ni = 0; ni < 4; ++ni) {
        acc[mi][ni] = __builtin_amdgcn_mfma_f32_16x16x32_bf16(
            ah[mi], bh[ni], acc[mi][ni], 0, 0, 0);
        acc[mi][ni] = __builtin_amdgcn_mfma_f32_16x16x32_bf16(
            al[mi], bh[ni], acc[mi][ni], 0, 0, 0);
        acc[mi][ni] = __builtin_amdgcn_mfma_f32_16x16x32_bf16(
            ah[mi], bl[ni], acc[mi][ni], 0, 0, 0);
      }
  }
  const int rq = (l >> 4) * 4;
#pragma unroll
  for (int ni = 0; ni < 4; ++ni) {
    const int col = n0 + wn + ni * 16 + lr;
    const float bv = bias[col];
#pragma unroll
    for (int mi = 0; mi < 4; ++mi)
#pragma unroll
      for (int r = 0; r < 4; ++r) {
        const int row = m0 + wm + mi * 16 + rq + r;
        C[(size_t)row * N + col] = acc[mi][ni][r] + bv;
      }
  }
}

// ---------------------------------------------------------------------------
// RoPE + transpose -> Qhi/Qlo, Khi/Klo (bf16 split, [bh][s][d]) + fp32 V.
// Q pre-scaled by 1/8.
// ---------------------------------------------------------------------------
__global__ __launch_bounds__(256) void k2_rope(
    const float* __restrict__ qkv, short* __restrict__ Qhi,
    short* __restrict__ Qlo, short* __restrict__ Khi,
    short* __restrict__ Klo, float* __restrict__ V) {
  const int g  = blockIdx.x * 256 + threadIdx.x;   // (bh, s)
  const int s  = g & (S - 1);
  const int bh = g >> 11;
  const int b  = bh >> 4, h = bh & 15;
  const float* base = qkv + ((size_t)b * S + s) * 3072 + h * 64;
  float q[64], k[64], v[64];
#pragma unroll
  for (int f = 0; f < 16; ++f) {
    const float4 x = *(const float4*)(base + f * 4);
    q[f*4+0]=x.x; q[f*4+1]=x.y; q[f*4+2]=x.z; q[f*4+3]=x.w;
    const float4 y = *(const float4*)(base + 1024 + f * 4);
    k[f*4+0]=y.x; k[f*4+1]=y.y; k[f*4+2]=y.z; k[f*4+3]=y.w;
    const float4 z = *(const float4*)(base + 2048 + f * 4);
    v[f*4+0]=z.x; v[f*4+1]=z.y; v[f*4+2]=z.z; v[f*4+3]=z.w;
  }
  const float PW[8] = {1.0f, 3.1622776601683795f, 10.0f, 31.622776601683793f,
                       100.0f, 316.22776601683796f, 1000.0f, 3162.2776601683795f};
  float qr[16], kr[16];
#pragma unroll
  for (int d = 0; d < 16; ++d) {
    const int j = d & 7;
    const float invf = 1.0f / PW[j];
    const float fr = (float)s * invf;
    float sn, c;
    sincosf(fr, &sn, &c);
    const float rq = (d < 8) ? -q[d + 8] : q[d - 8];
    const float rk = (d < 8) ? -k[d + 8] : k[d - 8];
    qr[d] = q[d] * c + rq * sn;
    kr[d] = k[d] * c + rk * sn;
  }
#pragma unroll
  for (int d = 0; d < 16; ++d) { q[d] = qr[d]; k[d] = kr[d]; }
#pragma unroll
  for (int d = 0; d < 64; ++d) q[d] *= 0.125f;   // fold softmax scale into Q
  const size_t o = ((size_t)bh * S + s) << 6;
  float* vd = V + o;
#pragma unroll
  for (int f = 0; f < 16; ++f) {
    short4 qh, ql, kh, kl;
    const float* qq = q + f * 4;
    const float* kk = k + f * 4;
    qh.x = bf_rne(qq[0]); qh.y = bf_rne(qq[1]); qh.z = bf_rne(qq[2]); qh.w = bf_rne(qq[3]);
    ql.x = bf_rne(qq[0]-bf2f(qh.x)); ql.y = bf_rne(qq[1]-bf2f(qh.y));
    ql.z = bf_rne(qq[2]-bf2f(qh.z)); ql.w = bf_rne(qq[3]-bf2f(qh.w));
    kh.x = bf_rne(kk[0]); kh.y = bf_rne(kk[1]); kh.z = bf_rne(kk[2]); kh.w = bf_rne(kk[3]);
    kl.x = bf_rne(kk[0]-bf2f(kh.x)); kl.y = bf_rne(kk[1]-bf2f(kh.y));
    kl.z = bf_rne(kk[2]-bf2f(kh.z)); kl.w = bf_rne(kk[3]-bf2f(kh.w));
    *(short4*)(Qhi + o + f*4) = qh;
    *(short4*)(Qlo + o + f*4) = ql;
    *(short4*)(Khi + o + f*4) = kh;
    *(short4*)(Klo + o + f*4) = kl;
    *(float4*)(vd + f*4) = make_float4(v[f*4], v[f*4+1], v[f*4+2], v[f*4+3]);
  }
}

// ---------------------------------------------------------------------------
// MFMA score pass: per 128x128 causal block, rowsum(exp(QK^T)) -> partZ,
// raw diag score -> sdg.  Split-bf16, 4 waves x 64x64 quadrants.
// LDS rows padded to 72 shorts (144B stride -> 2-way bank alias, free).
// ---------------------------------------------------------------------------
__global__ __launch_bounds__(256) void k3_scores(
    const short* __restrict__ Qhi, const short* __restrict__ Qlo,
    const short* __restrict__ Khi, const short* __restrict__ Klo,
    float* __restrict__ partZ, float* __restrict__ sdg) {
  const int cb = blockIdx.x, rb = blockIdx.y, bh = blockIdx.z;
  if (cb > rb) return;
  __shared__ short qh[128][72], ql[128][72], kh[128][72], kl[128][72];
  __shared__ float red[128][2];
  const int t = threadIdx.x;
  const int w = t >> 6, l = t & 63;
  const int wm = (w >> 1) * 64, wn = (w & 1) * 64;
  const int lr = l & 15, lg = l >> 4;
  for (int v = t; v < 1024; v += 256) {
    const int r = v >> 3, c8 = (v & 7) * 8;
    const size_t gq = (((size_t)bh * S + rb * 128 + r) << 6) + c8;
    const size_t gk = (((size_t)bh * S + cb * 128 + r) << 6) + c8;
    *(uint4*)&qh[r][c8] = *(const uint4*)(Qhi + gq);
    *(uint4*)&ql[r][c8] = *(const uint4*)(Qlo + gq);
    *(uint4*)&kh[r][c8] = *(const uint4*)(Khi + gk);
    *(uint4*)&kl[r][c8] = *(const uint4*)(Klo + gk);
  }
  __syncthreads();
  f32x4 acc[4][4];
#pragma unroll
  for (int i = 0; i < 4; ++i)
#pragma unroll
    for (int j = 0; j < 4; ++j) acc[i][j] = (f32x4)0.f;
#pragma unroll
  for (int ks = 0; ks < 2; ++ks) {
    const int lk = ks * 32 + lg * 8;
    bf16x8 ah[4], al[4], bhf[4], blf[4];
#pragma unroll
    for (int mi = 0; mi < 4; ++mi) {
      ah[mi] = *(const bf16x8*)&qh[wm + mi * 16 + lr][lk];
      al[mi] = *(const bf16x8*)&ql[wm + mi * 16 + lr][lk];
    }
#pragma unroll
    for (int ni = 0; ni < 4; ++ni) {
      bhf[ni] = *(const bf16x8*)&kh[wn + ni * 16 + lr][lk];
      blf[ni] = *(const bf16x8*)&kl[wn + ni * 16 + lr][lk];
    }
#pragma unroll
    for (int mi = 0; mi < 4; ++mi)
#pragma unroll
      for (int ni = 0; ni < 4; ++ni) {
        acc[mi][ni] = __builtin_amdgcn_mfma_f32_16x16x32_bf16(
            ah[mi], bhf[ni], acc[mi][ni], 0, 0, 0);
        acc[mi][ni] = __builtin_amdgcn_mfma_f32_16x16x32_bf16(
            al[mi], bhf[ni], acc[mi][ni], 0, 0, 0);
        acc[mi][ni] = __builtin_amdgcn_mfma_f32_16x16x32_bf16(
            ah[mi], blf[ni], acc[mi][ni], 0, 0, 0);
      }
  }
  // epilogue: mask + exp + row sums (rows: (l>>4)*4 + r, cols: lane&15)
  const int rq = lg * 4;
  const int rowbase = rb * 128 + wm, colbase = cb * 128 + wn;
  float rp[4][4];
#pragma unroll
  for (int mi = 0; mi < 4; ++mi)
#pragma unroll
    for (int r = 0; r < 4; ++r) rp[mi][r] = 0.f;
#pragma unroll
  for (int mi = 0; mi < 4; ++mi)
#pragma unroll
    for (int ni = 0; ni < 4; ++ni)
#pragma unroll
      for (int r = 0; r < 4; ++r) {
        const int rG = rowbase + mi * 16 + rq + r;
        const int cG = colbase + ni * 16 + lr;
        if (cG <= rG) rp[mi][r] += __expf(acc[mi][ni][r]);
        if (cG == rG) sdg[(size_t)bh * S + rG] = acc[mi][ni][r];
      }
#pragma unroll
  for (int off = 1; off < 16; off <<= 1)
#pragma unroll
    for (int mi = 0; mi < 4; ++mi)
#pragma unroll
      for (int r = 0; r < 4; ++r)
        rp[mi][r] += __shfl_xor(rp[mi][r], off, 64);
  if (lr == 0)
#pragma unroll
    for (int mi = 0; mi < 4; ++mi)
#pragma unroll
      for (int r = 0; r < 4; ++r)
        red[wm + mi * 16 + rq + r][w & 1] = rp[mi][r];
  __syncthreads();
  if (t < 128)
    partZ[(((size_t)bh * 16 + rb) * 16 + cb) * 128 + t] = red[t][0] + red[t][1];
}

// ---------------------------------------------------------------------------
// Stats pass 2: Z = sum of partials over cb<=rb -> zinv; pd = exp(sd)*zinv.
// ---------------------------------------------------------------------------
__global__ __launch_bounds__(256) void k3_reduce(
    const float* __restrict__ partZ, float* __restrict__ zinv,
    float* __restrict__ pdg) {
  const int R = blockIdx.x * 256 + threadIdx.x;   // 0..BH*S-1
  const int bh = R >> 11, r = R & 2047;
  const int rb = r >> 7, row = r & 127;
  float Z = 0.f;
  for (int c = 0; c <= rb; ++c)
    Z += partZ[(((size_t)bh*16 + rb)*16 + c)*128 + row];
  const float zi = 1.f / Z;
  zinv[R] = zi;
  pdg[R] = __expf(pdg[R]) * zi;
}

// ---------------------------------------------------------------------------
// Per-64-block unit-lower-triangular inverse of (I - N), 256 threads.
// Phase A: scores via split-bf16 MFMA (global frags) -> Nb = exp*zi (strict lower).
// Phase B: X = I.  Phase C: panel-blocked forward substitution — column c of X
// is lane-private; inter-panel contribution is a parallel 256-thread matmul,
// within-panel 15-round solve on wave 0 only.
// Output TRANSPOSED: MinvT[bh][ib][c][r] = X[r][c].
// ---------------------------------------------------------------------------
__global__ __launch_bounds__(256) void k4_minv(
    const short* __restrict__ Qhi, const short* __restrict__ Qlo,
    const short* __restrict__ Khi, const short* __restrict__ Klo,
    const float* __restrict__ zinv, float* __restrict__ MinvT) {
  const int bh = blockIdx.y, ib = blockIdx.x;
  const int r0 = ib * 64;
  __shared__ float Nb[64][68];
  __shared__ float X[64][68];
  const int t = threadIdx.x;
  const int w = t >> 6, l = t & 63;     // wave w owns score rows 16w..16w+15
  const int lr = l & 15, lg = l >> 4;

  // Phase A: scores rows [16w,16w+16) x cols [0,64), K=64, MFMA from global
  f32x4 acc[4];
#pragma unroll
  for (int i = 0; i < 4; ++i) acc[i] = (f32x4)0.f;
  const size_t qbase = (((size_t)bh * S + r0 + 16 * w + lr) << 6);
  const size_t kbase = ((size_t)bh * S + r0) << 6;
#pragma unroll
  for (int ks = 0; ks < 2; ++ks) {
    const int k0 = ks * 32 + lg * 8;
    const bf16x8 ah = *(const bf16x8*)(Qhi + qbase + k0);
    const bf16x8 al = *(const bf16x8*)(Qlo + qbase + k0);
#pragma unroll
    for (int ni = 0; ni < 4; ++ni) {
      const size_t kb = kbase + (((size_t)(16 * ni + lr)) << 6) + k0;
      const bf16x8 bhf = *(const bf16x8*)(Khi + kb);
      const bf16x8 blf = *(const bf16x8*)(Klo + kb);
      acc[ni] = __builtin_amdgcn_mfma_f32_16x16x32_bf16(ah, bhf, acc[ni], 0, 0, 0);
      acc[ni] = __builtin_amdgcn_mfma_f32_16x16x32_bf16(al, bhf, acc[ni], 0, 0, 0);
      acc[ni] = __builtin_amdgcn_mfma_f32_16x16x32_bf16(ah, blf, acc[ni], 0, 0, 0);
    }
  }
  // epilogue -> Nb (strict lower exp*zi, else 0)
  {
    const int rloc0 = 16 * w + lg * 4;
    float ziv[4];
#pragma unroll
    for (int i = 0; i < 4; ++i) ziv[i] = zinv[(size_t)bh * S + r0 + rloc0 + i];
#pragma unroll
    for (int ni = 0; ni < 4; ++ni) {
      const int c = 16 * ni + lr;
#pragma unroll
      for (int i = 0; i < 4; ++i) {
        const int r = rloc0 + i;
        Nb[r][c] = (c < r) ? __expf(acc[ni][i]) * ziv[i] : 0.f;
      }
    }
  }
  // Phase B: X = I  (thread (c,g) inits rows 16g..16g+15 of column c)
  {
    const int c = t & 63, g = t >> 6;
#pragma unroll
    for (int i = 0; i < 16; ++i) {
      const int r = 16 * g + i;
      X[r][c] = (r == c) ? 1.f : 0.f;
    }
  }
  __syncthreads();

  // Phase C: panel-blocked forward substitution, X = (I - N)^-1
  const int c = t & 63, g = t >> 6;
  // solve panel 0 (wave 0 only; column c lane-private, no barrier inside)
  if (w == 0) {
    for (int rr = 1; rr < 16; ++rr) {
      float a = 0.f;
      for (int j = 0; j < rr; ++j) a += Nb[rr][j] * X[j][l];
      X[rr][l] += a;
    }
  }
  __syncthreads();
#pragma unroll
  for (int I = 1; I < 4; ++I) {
    // matmul: rows 16I+4g..+3 accumulate over j < 16I (all 256 threads)
    {
      const int rb4 = 16 * I + 4 * g;
      float s0 = 0.f, s1 = 0.f, s2 = 0.f, s3 = 0.f;
      for (int j = 0; j < 16 * I; j += 4) {
        const float4 n0 = *(const float4*)&Nb[rb4 + 0][j];
        const float4 n1 = *(const float4*)&Nb[rb4 + 1][j];
        const float4 n2 = *(const float4*)&Nb[rb4 + 2][j];
        const float4 n3 = *(const float4*)&Nb[rb4 + 3][j];
        const float x0 = X[j + 0][c], x1 = X[j + 1][c];
        const float x2 = X[j + 2][c], x3 = X[j + 3][c];
        s0 += n0.x * x0 + n0.y * x1 + n0.z * x2 + n0.w * x3;
        s1 += n1.x * x0 + n1.y * x1 + n1.z * x2 + n1.w * x3;
        s2 += n2.x * x0 + n2.y * x1 + n2.z * x2 + n2.w * x3;
        s3 += n3.x * x0 + n3.y * x1 + n3.z * x2 + n3.w * x3;
      }
      X[rb4 + 0][c] += s0; X[rb4 + 1][c] += s1;
      X[rb4 + 2][c] += s2; X[rb4 + 3][c] += s3;
    }
    __syncthreads();
    // within-panel solve (wave 0 only)
    if (w == 0) {
      const int rb = 16 * I;
      for (int rr = 1; rr < 16; ++rr) {
        const int r = rb + rr;
        float a = 0.f;
        for (int j = rb; j < r; ++j) a += Nb[r][j] * X[j][l];
        X[r][l] += a;
      }
    }
    __syncthreads();
  }

  // Phase D: write MinvT[bh][ib][c][r] = X[r][c]
  float* dst = MinvT + (((size_t)bh * 32 + ib) * 64 + c) * 64;
#pragma unroll
  for (int rq = 0; rq < 4; ++rq) {
    const int r = 16 * g + rq * 4;
    float4 o;
    o.x = X[r + 0][c]; o.y = X[r + 1][c]; o.z = X[r + 2][c]; o.w = X[r + 3][c];
    *(float4*)(dst + r) = o;
  }
}

// ---------------------------------------------------------------------------
// Scan step k off-diagonal accumulate (register-blocked, two 64-col halves):
// upart[bh][j] = P[k-rows, j-block] @ A_j.  8x4 microtiles both phases.
// ---------------------------------------------------------------------------
__global__ __launch_bounds__(256) void k5_acc(
    const short* __restrict__ Qhi, const short* __restrict__ Qlo,
    const short* __restrict__ Khi, const short* __restrict__ Klo,
    const float* __restrict__ Abuf, const float* __restrict__ zinv,
    float* __restrict__ upart, int kstep) {
  const int bh = blockIdx.y, j = blockIdx.x;
  __shared__ float qs[64][132];    // Q^T [kk][r], rows base..base+127
  __shared__ float pt[64][132];    // P^T half [c][r]
  __shared__ float buf[64][68];    // K^T half [kk][c], then A half [c][d]
  const int t = threadIdx.x;
  const int tm = (t & 15) * 8, tn4 = (t >> 4) * 4;
  const int base = kstep * 128;
  for (int v4 = t; v4 < 2048; v4 += 256) {
    const int r = v4 >> 4, f = v4 & 15;
    const float4 x = ld_hl4(Qhi, Qlo, (((size_t)bh*S + base + r) << 6) + f*4);
    qs[f*4+0][r]=x.x; qs[f*4+1][r]=x.y; qs[f*4+2][r]=x.z; qs[f*4+3][r]=x.w;
  }
  float ziv[8];
#pragma unroll
  for (int i = 0; i < 8; ++i) ziv[i] = zinv[bh*S + base + tm + i];
  float out[8][4];
#pragma unroll
  for (int i = 0; i < 8; ++i)
#pragma unroll
    for (int jj = 0; jj < 4; ++jj) out[i][jj] = 0.f;

  for (int h = 0; h < 2; ++h) {
    __syncthreads();     // covers qs staging (h=0) / pt+buf reuse (h=1)
    for (int v4 = t; v4 < 1024; v4 += 256) {      // K^T half
      const int c = v4 >> 4, f = v4 & 15;
      const float4 y = ld_hl4(Khi, Klo, (((size_t)bh*S + j*128 + h*64 + c) << 6) + f*4);
      buf[f*4+0][c]=y.x; buf[f*4+1][c]=y.y; buf[f*4+2][c]=y.z; buf[f*4+3][c]=y.w;
    }
    __syncthreads();
    float qk[8][4];
#pragma unroll
    for (int i = 0; i < 8; ++i)
#pragma unroll
      for (int jj = 0; jj < 4; ++jj) qk[i][jj] = 0.f;
#pragma unroll 4
    for (int kk = 0; kk < 64; ++kk) {
      const float4 a0 = *(const float4*)&qs[kk][tm];
      const float4 a1 = *(const float4*)&qs[kk][tm + 4];
      const float4 b  = *(const float4*)&buf[kk][tn4];
      const float av[8] = {a0.x, a0.y, a0.z, a0.w, a1.x, a1.y, a1.z, a1.w};
      const float bv[4] = {b.x, b.y, b.z, b.w};
#pragma unroll
      for (int i = 0; i < 8; ++i)
#pragma unroll
        for (int jj = 0; jj < 4; ++jj) qk[i][jj] += av[i] * bv[jj];
    }
#pragma unroll
    for (int i = 0; i < 8; ++i)
#pragma unroll
      for (int jj = 0; jj < 4; ++jj)
        pt[tn4 + jj][tm + i] = __expf(qk[i][jj]) * ziv[i];
    __syncthreads();
    for (int v4 = t; v4 < 1024; v4 += 256) {      // A half (row-major)
      const int c = v4 >> 4, f = v4 & 15;
      *(float4*)&buf[c][f*4] =
        *(const float4*)(Abuf + (((size_t)bh*S + j*128 + h*64 + c) << 6) + f*4);
    }
    __syncthreads();
#pragma unroll 4
    for (int c = 0; c < 64; ++c) {
      const float4 p0 = *(const float4*)&pt[c][tm];
      const float4 p1 = *(const float4*)&pt[c][tm + 4];
      const float4 a  = *(const float4*)&buf[c][tn4];
      const float pv[8] = {p0.x, p0.y, p0.z, p0.w, p1.x, p1.y, p1.z, p1.w};
      const float avv[4] = {a.x, a.y, a.z, a.w};
#pragma unroll
      for (int i = 0; i < 8; ++i)
#pragma unroll
        for (int jj = 0; jj < 4; ++jj) out[i][jj] += pv[i] * avv[jj];
    }
  }
#pragma unroll
  for (int i = 0; i < 8; ++i)
    *(float4*)(upart + ((((size_t)bh*15 + j)*128 + tm + i) << 6) + tn4) =
        make_float4(out[i][0], out[i][1], out[i][2], out[i][3]);
}

// ---------------------------------------------------------------------------
// Scan step k finalize, parallel over 16-d chunks (grid 4 x BH):
//   u = pd*v + sum(upart);  A_lo = Minv@u_lo (kept in LDS);
//   u_hi += P(hi,lo)@A_lo;  A_hi = Minv@u_hi.
// ---------------------------------------------------------------------------
__global__ __launch_bounds__(256) void k5_fin(
    const short* __restrict__ Qhi, const short* __restrict__ Qlo,
    const short* __restrict__ Khi, const short* __restrict__ Klo,
    const float* __restrict__ V, const float* __restrict__ pd,
    const float* __restrict__ zinv, const float* __restrict__ upart,
    const float* __restrict__ MinvT, float* __restrict__ Abuf, int kstep) {
  const int dc0 = blockIdx.x * 16;
  const int bh  = blockIdx.y;
  const int t = threadIdx.x;
  const int base = kstep * 128;
  __shared__ float u[128][16];
  __shared__ float alo[64][17];
  __shared__ float kst[64][68];     // MinvT / K staging (sequential reuse)
  __shared__ float pbuf[64][65];

  // phase 0: u = pd*v + sum partials (this d-chunk); stage MinvT(2k)
  for (int v4 = t; v4 < 512; v4 += 256) {
    const int r = v4 >> 2, f = v4 & 3;
    const int R = base + r;
    const float4 x = *(const float4*)(V + (((size_t)bh*S + R) << 6) + dc0 + f*4);
    const float p = pd[bh*S + R];
    float a0 = p*x.x, a1 = p*x.y, a2 = p*x.z, a3 = p*x.w;
    for (int j = 0; j < kstep; ++j) {
      const float4 y = *(const float4*)(upart + ((((size_t)bh*15 + j)*128 + r) << 6) + dc0 + f*4);
      a0 += y.x; a1 += y.y; a2 += y.z; a3 += y.w;
    }
    *(float4*)&u[r][f*4] = make_float4(a0, a1, a2, a3);
  }
  for (int v4 = t; v4 < 1024; v4 += 256) {
    const int j = v4 >> 4, f = v4 & 15;
    *(float4*)&kst[j][f*4] =
      *(const float4*)(MinvT + ((((size_t)bh*32 + kstep*2)*64 + j) << 6) + f*4);
  }
  __syncthreads();
  // phase 1: A_lo = Minv @ u_lo (this d-chunk); keep in LDS + write global
  {
    const int r = t & 63, dq = (t >> 6) * 4;
    float a0=0.f, a1=0.f, a2=0.f, a3=0.f;
    for (int j = 0; j < 64; ++j) {
      const float w = kst[j][r];
      a0 += w*u[j][dq];   a1 += w*u[j][dq+1];
      a2 += w*u[j][dq+2]; a3 += w*u[j][dq+3];
    }
    alo[r][dq] = a0; alo[r][dq+1] = a1; alo[r][dq+2] = a2; alo[r][dq+3] = a3;
    *(float4*)(Abuf + (((size_t)bh*S + base + r) << 6) + dc0 + dq) =
        make_float4(a0, a1, a2, a3);
  }
  __syncthreads();
  for (int v4 = t; v4 < 1024; v4 += 256) {   // stage K rows [base, base+64)
    const int j = v4 >> 4, f = v4 & 15;
    *(float4*)&kst[j][f*4] = ld_hl4(Khi, Klo, (((size_t)bh*S + base + j) << 6) + f*4);
  }
  __syncthreads();
  // phase 2a: pbuf[r][j] = exp(q_{base+64+r} . k_j) * zi  (dots computed once)
  {
    const int rp = t >> 2, c4 = t & 3;
    const int R = base + 64 + rp;
    float q[64];
#pragma unroll
    for (int f = 0; f < 16; ++f) {
      const float4 x = ld_hl4(Qhi, Qlo, (((size_t)bh*S + R) << 6) + f*4);
      q[f*4]=x.x; q[f*4+1]=x.y; q[f*4+2]=x.z; q[f*4+3]=x.w;
    }
    const float zi = zinv[bh*S + R];
    for (int j = c4; j < 64; j += 4) {
      float s = 0.f;
#pragma unroll
      for (int i4 = 0; i4 < 16; ++i4) {
        const float4 kv = *(const float4*)&kst[j][i4*4];
        s += q[i4*4]*kv.x + q[i4*4+1]*kv.y + q[i4*4+2]*kv.z + q[i4*4+3]*kv.w;
      }
      pbuf[rp][j] = __expf(s) * zi;
    }
  }
  __syncthreads();
  // phase 2b: u_hi += P @ A_lo (this d-chunk, A_lo from LDS)
  {
    const int r = t & 63, dq = (t >> 6) * 4;
    float a0=0.f, a1=0.f, a2=0.f, a3=0.f;
    for (int j = 0; j < 64; ++j) {
      const float p = pbuf[r][j];
      a0 += p*alo[j][dq];   a1 += p*alo[j][dq+1];
      a2 += p*alo[j][dq+2]; a3 += p*alo[j][dq+3];
    }
    u[64+r][dq] += a0; u[64+r][dq+1] += a1;
    u[64+r][dq+2] += a2; u[64+r][dq+3] += a3;
  }
  __syncthreads();
  for (int v4 = t; v4 < 1024; v4 += 256) {   // stage MinvT(2k+1)
    const int j = v4 >> 4, f = v4 & 15;
    *(float4*)&kst[j][f*4] =
      *(const float4*)(MinvT + ((((size_t)bh*32 + kstep*2 + 1)*64 + j) << 6) + f*4);
  }
  __syncthreads();
  // phase 3: A_hi = Minv @ u_hi
  {
    const int r = t & 63, dq = (t >> 6) * 4;
    float a0=0.f, a1=0.f, a2=0.f, a3=0.f;
    for (int j = 0; j < 64; ++j) {
      const float w = kst[j][r];
      a0 += w*u[64+j][dq];   a1 += w*u[64+j][dq+1];
      a2 += w*u[64+j][dq+2]; a3 += w*u[64+j][dq+3];
    }
    *(float4*)(Abuf + (((size_t)bh*S + base + 64 + r) << 6) + dc0 + dq) =
        make_float4(a0, a1, a2, a3);
  }
}

} // namespace

extern "C" void kernel_launch(void* const* d_in, const int* in_sizes, int n_in,
                              void* d_out, int out_size, void* d_ws, size_t ws_size,
                              hipStream_t stream) {
  const float* hs   = (const float*)d_in[0];
  const float* Wqkv = (const float*)d_in[1];
  const float* bqkv = (const float*)d_in[2];
  const float* Wd   = (const float*)d_in[3];
  const float* bd   = (const float*)d_in[4];
  float* out = (float*)d_out;
  float* W   = (float*)d_ws;
  if (ws_size < WS_FLOATS * sizeof(float)) return;  // insufficient scratch

  float* qkv   = W + OFF_QKV;
  float* partZ = W + OFF_PART;
  float* MinvT = W + OFF_MINV;
  float* Abuf  = W + OFF_A;
  short* Qhi   = (short*)(W + OFF_Q);
  short* Qlo   = Qhi + 4194304;
  short* Khi   = (short*)(W + OFF_K);
  short* Klo   = Khi + 4194304;
  float* Vb    = W + OFF_V;
  float* zi    = W + OFF_ZI;
  float* pdg   = W + OFF_PD;
  float* up    = W + OFF_UP;

  // bf16 split scratch in regions dead at time of use (Q/K regions pre-rope,
  // same regions post-scan).
  char* wsb = (char*)d_ws;
  short* Ahi  = (short*)(wsb + 50331648);
  short* Alo  = Ahi + 4194304;                 // 4096x1024
  short* Whi  = (short*)(wsb + 67108864);
  short* Wlo  = Whi + 3145728;                 // 3072x1024
  short* A2hi = (short*)(wsb + 50331648);
  short* A2lo = A2hi + 4194304;
  short* Wdhi = (short*)(wsb + 67108864);
  short* Wdlo = Wdhi + 1048576;                // 1024x1024

  split2<<<dim3(2048), 256, 0, stream>>>(hs, Ahi, Alo, B*S*HID/4);
  split2<<<dim3(2048), 256, 0, stream>>>(Wqkv, Whi, Wlo, 3*HID*HID/4);
  gemm_bf3<<<dim3(24, 32), 256, 0, stream>>>(Ahi, Alo, Whi, Wlo, bqkv, qkv,
                                             B*S, 3*HID, HID);
  k2_rope<<<dim3(BH * S / 256), 256, 0, stream>>>(qkv, Qhi, Qlo, Khi, Klo, Vb);
  k3_scores<<<dim3(16, 16, BH), 256, 0, stream>>>(Qhi, Qlo, Khi, Klo, partZ, pdg);
  k3_reduce<<<dim3(BH * S / 256), 256, 0, stream>>>(partZ, zi, pdg);
  k4_minv<<<dim3(S / 64, BH), 256, 0, stream>>>(Qhi, Qlo, Khi, Klo, zi, MinvT);
  for (int k = 0; k < NSTEP; ++k) {
    if (k > 0)
      k5_acc<<<dim3(k, BH), 256, 0, stream>>>(Qhi, Qlo, Khi, Klo, Abuf, zi, up, k);
    k5_fin<<<dim3(4, BH), 256, 0, stream>>>(Qhi, Qlo, Khi, Klo, Vb, pdg, zi, up,
                                            MinvT, Abuf, k);
  }
  split_gather<<<dim3(2048), 256, 0, stream>>>(Abuf, A2hi, A2lo);
  split2<<<dim3(2048), 256, 0, stream>>>(Wd, Wdhi, Wdlo, HID*HID/4);
  gemm_bf3<<<dim3(8, 32), 256, 0, stream>>>(A2hi, A2lo, Wdhi, Wdlo, bd, out,
                                            B*S, HID, HID);
}

// Round 7
// 923.419 us; speedup vs baseline: 3.6307x; 1.3399x over previous
//
#include <hip/hip_runtime.h>
#include <math.h>

namespace {

constexpr int B  = 2, S = 2048, NH = 16, HD = 64, HID = 1024;
constexpr int BH = B * NH;          // 32
constexpr int NSTEP = 16;           // 128-row scan blocks

// ws layout in floats.
constexpr size_t OFF_QKV  = 0;
constexpr size_t OFF_PART = 0;                 // [BH][16][16][128] Z partials
constexpr size_t OFF_MINV = 0;                 // [BH][32][64][64]
constexpr size_t OFF_A    = 4194304;           // [BH][S][HD]
constexpr size_t OFF_Q    = 12582912;          // Qhi/Qlo bf16 pairs (8MB+8MB)
constexpr size_t OFF_K    = 16777216;          // Khi/Klo bf16 pairs
constexpr size_t OFF_V    = 20971520;          // fp32 V
constexpr size_t OFF_ZI   = 25231360;          // [BH*S]
constexpr size_t OFF_PD   = 25296896;          // [BH*S]
constexpr size_t OFF_UP   = 25362432;          // [BH][15][128][64]
constexpr size_t WS_FLOATS = 29294592;         // ~117 MB

typedef __attribute__((ext_vector_type(8))) short bf16x8;
typedef __attribute__((ext_vector_type(4))) float f32x4;

__device__ inline unsigned short bf_rne(float x) {
  const unsigned u = __float_as_uint(x);
  return (unsigned short)((u + 0x7FFFu + ((u >> 16) & 1u)) >> 16);
}
__device__ inline float bf2f(short h) {
  return __uint_as_float((unsigned)(unsigned short)h << 16);
}
// load 4 fp32 reconstructed from hi/lo bf16 arrays at element offset off
__device__ inline float4 ld_hl4(const short* __restrict__ hi,
                                const short* __restrict__ lo, size_t off) {
  const short4 h = *(const short4*)(hi + off);
  const short4 l = *(const short4*)(lo + off);
  return make_float4(bf2f(h.x) + bf2f(l.x), bf2f(h.y) + bf2f(l.y),
                     bf2f(h.z) + bf2f(l.z), bf2f(h.w) + bf2f(l.w));
}
// split 8 fp32 (two float4) into hi/lo bf16x8 fragments
__device__ inline void split8(const float4 a, const float4 b,
                              bf16x8& hi, bf16x8& lo) {
  float v[8] = {a.x, a.y, a.z, a.w, b.x, b.y, b.z, b.w};
#pragma unroll
  for (int i = 0; i < 8; ++i) {
    const unsigned short h = bf_rne(v[i]);
    hi[i] = (short)h;
    lo[i] = (short)bf_rne(v[i] - bf2f((short)h));
  }
}

// ---------------------------------------------------------------------------
// Split fp32 -> (hi, lo) bf16 arrays.  n4 = element_count / 4.
// ---------------------------------------------------------------------------
__global__ __launch_bounds__(256) void split2(
    const float* __restrict__ in, short* __restrict__ hi,
    short* __restrict__ lo, int n4) {
  for (int g = blockIdx.x * 256 + threadIdx.x; g < n4; g += gridDim.x * 256) {
    const float4 x = *(const float4*)(in + (size_t)g * 4);
    short4 h, l;
    h.x = bf_rne(x.x); h.y = bf_rne(x.y); h.z = bf_rne(x.z); h.w = bf_rne(x.w);
    l.x = bf_rne(x.x - bf2f(h.x));
    l.y = bf_rne(x.y - bf2f(h.y));
    l.z = bf_rne(x.z - bf2f(h.z));
    l.w = bf_rne(x.w - bf2f(h.w));
    *(short4*)(hi + (size_t)g * 4) = h;
    *(short4*)(lo + (size_t)g * 4) = l;
  }
}

// ---------------------------------------------------------------------------
// Gather attn output [bh][s][d] -> [m=(b,s)][k=(h,d)] and split to hi/lo bf16.
// ---------------------------------------------------------------------------
__global__ __launch_bounds__(256) void split_gather(
    const float* __restrict__ Abuf, short* __restrict__ hi,
    short* __restrict__ lo) {
  const int n4 = B * S * HID / 4;
  for (int g = blockIdx.x * 256 + threadIdx.x; g < n4; g += gridDim.x * 256) {
    const int m = g >> 8, q = g & 255;
    const int k0 = q * 4;
    const int b = m >> 11, s = m & (S - 1);
    const int h = k0 >> 6, d = k0 & 63;
    const float4 x = *(const float4*)(Abuf + (((size_t)(b * NH + h) * S + s) << 6) + d);
    short4 hh, ll;
    hh.x = bf_rne(x.x); hh.y = bf_rne(x.y); hh.z = bf_rne(x.z); hh.w = bf_rne(x.w);
    ll.x = bf_rne(x.x - bf2f(hh.x));
    ll.y = bf_rne(x.y - bf2f(hh.y));
    ll.z = bf_rne(x.z - bf2f(hh.z));
    ll.w = bf_rne(x.w - bf2f(hh.w));
    *(short4*)(hi + (size_t)m * HID + k0) = hh;
    *(short4*)(lo + (size_t)m * HID + k0) = ll;
  }
}

// ---------------------------------------------------------------------------
// Split-bf16 MFMA NT GEMM: C = A @ B^T + bias (fp32 via 3 bf16 chains).
// ---------------------------------------------------------------------------
__global__ __launch_bounds__(256) void gemm_bf3(
    const short* __restrict__ Ahi, const short* __restrict__ Alo,
    const short* __restrict__ Bhi, const short* __restrict__ Blo,
    const float* __restrict__ bias, float* __restrict__ C,
    int M, int N, int K) {
  __shared__ short ash[128][40], als[128][40], bsh[128][40], bls[128][40];
  const int t = threadIdx.x;
  const int m0 = blockIdx.y * 128, n0 = blockIdx.x * 128;
  const int w = t >> 6, l = t & 63;
  const int wm = (w >> 1) * 64, wn = (w & 1) * 64;
  const int lr = l & 15, lk = (l >> 4) * 8;
  f32x4 acc[4][4];
#pragma unroll
  for (int i = 0; i < 4; ++i)
#pragma unroll
    for (int j = 0; j < 4; ++j) acc[i][j] = (f32x4)0.f;

  for (int kb = 0; kb < K; kb += 32) {
    __syncthreads();
#pragma unroll
    for (int i = 0; i < 2; ++i) {
      const int idx = t + i * 256;
      const int row = idx >> 2, c8 = (idx & 3) * 8;
      *(uint4*)&ash[row][c8] = *(const uint4*)(Ahi + (size_t)(m0 + row) * K + kb + c8);
      *(uint4*)&als[row][c8] = *(const uint4*)(Alo + (size_t)(m0 + row) * K + kb + c8);
      *(uint4*)&bsh[row][c8] = *(const uint4*)(Bhi + (size_t)(n0 + row) * K + kb + c8);
      *(uint4*)&bls[row][c8] = *(const uint4*)(Blo + (size_t)(n0 + row) * K + kb + c8);
    }
    __syncthreads();
    bf16x8 ah[4], al[4], bh[4], bl[4];
#pragma unroll
    for (int mi = 0; mi < 4; ++mi) {
      ah[mi] = *(const bf16x8*)&ash[wm + mi * 16 + lr][lk];
      al[mi] = *(const bf16x8*)&als[wm + mi * 16 + lr][lk];
    }
#pragma unroll
    for (int ni = 0; ni < 4; ++ni) {
      bh[ni] = *(const bf16x8*)&bsh[wn + ni * 16 + lr][lk];
      bl[ni] = *(const bf16x8*)&bls[wn + ni * 16 + lr][lk];
    }
#pragma unroll
    for (int mi = 0; mi < 4; ++mi)
#pragma unroll
      for (int ni = 0; ni < 4; ++ni) {
        acc[mi][ni] = __builtin_amdgcn_mfma_f32_16x16x32_bf16(
            ah[mi], bh[ni], acc[mi][ni], 0, 0, 0);
        acc[mi][ni] = __builtin_amdgcn_mfma_f32_16x16x32_bf16(
            al[mi], bh[ni], acc[mi][ni], 0, 0, 0);
        acc[mi][ni] = __builtin_amdgcn_mfma_f32_16x16x32_bf16(
            ah[mi], bl[ni], acc[mi][ni], 0, 0, 0);
      }
  }
  const int rq = (l >> 4) * 4;
#pragma unroll
  for (int ni = 0; ni < 4; ++ni) {
    const int col = n0 + wn + ni * 16 + lr;
    const float bv = bias[col];
#pragma unroll
    for (int mi = 0; mi < 4; ++mi)
#pragma unroll
      for (int r = 0; r < 4; ++r) {
        const int row = m0 + wm + mi * 16 + rq + r;
        C[(size_t)row * N + col] = acc[mi][ni][r] + bv;
      }
  }
}

// ---------------------------------------------------------------------------
// RoPE + transpose -> Qhi/Qlo, Khi/Klo (bf16 split, [bh][s][d]) + fp32 V.
// Q pre-scaled by 1/8.
// ---------------------------------------------------------------------------
__global__ __launch_bounds__(256) void k2_rope(
    const float* __restrict__ qkv, short* __restrict__ Qhi,
    short* __restrict__ Qlo, short* __restrict__ Khi,
    short* __restrict__ Klo, float* __restrict__ V) {
  const int g  = blockIdx.x * 256 + threadIdx.x;   // (bh, s)
  const int s  = g & (S - 1);
  const int bh = g >> 11;
  const int b  = bh >> 4, h = bh & 15;
  const float* base = qkv + ((size_t)b * S + s) * 3072 + h * 64;
  float q[64], k[64], v[64];
#pragma unroll
  for (int f = 0; f < 16; ++f) {
    const float4 x = *(const float4*)(base + f * 4);
    q[f*4+0]=x.x; q[f*4+1]=x.y; q[f*4+2]=x.z; q[f*4+3]=x.w;
    const float4 y = *(const float4*)(base + 1024 + f * 4);
    k[f*4+0]=y.x; k[f*4+1]=y.y; k[f*4+2]=y.z; k[f*4+3]=y.w;
    const float4 z = *(const float4*)(base + 2048 + f * 4);
    v[f*4+0]=z.x; v[f*4+1]=z.y; v[f*4+2]=z.z; v[f*4+3]=z.w;
  }
  const float PW[8] = {1.0f, 3.1622776601683795f, 10.0f, 31.622776601683793f,
                       100.0f, 316.22776601683796f, 1000.0f, 3162.2776601683795f};
  float qr[16], kr[16];
#pragma unroll
  for (int d = 0; d < 16; ++d) {
    const int j = d & 7;
    const float invf = 1.0f / PW[j];
    const float fr = (float)s * invf;
    float sn, c;
    sincosf(fr, &sn, &c);
    const float rq = (d < 8) ? -q[d + 8] : q[d - 8];
    const float rk = (d < 8) ? -k[d + 8] : k[d - 8];
    qr[d] = q[d] * c + rq * sn;
    kr[d] = k[d] * c + rk * sn;
  }
#pragma unroll
  for (int d = 0; d < 16; ++d) { q[d] = qr[d]; k[d] = kr[d]; }
#pragma unroll
  for (int d = 0; d < 64; ++d) q[d] *= 0.125f;   // fold softmax scale into Q
  const size_t o = ((size_t)bh * S + s) << 6;
  float* vd = V + o;
#pragma unroll
  for (int f = 0; f < 16; ++f) {
    short4 qh, ql, kh, kl;
    const float* qq = q + f * 4;
    const float* kk = k + f * 4;
    qh.x = bf_rne(qq[0]); qh.y = bf_rne(qq[1]); qh.z = bf_rne(qq[2]); qh.w = bf_rne(qq[3]);
    ql.x = bf_rne(qq[0]-bf2f(qh.x)); ql.y = bf_rne(qq[1]-bf2f(qh.y));
    ql.z = bf_rne(qq[2]-bf2f(qh.z)); ql.w = bf_rne(qq[3]-bf2f(qh.w));
    kh.x = bf_rne(kk[0]); kh.y = bf_rne(kk[1]); kh.z = bf_rne(kk[2]); kh.w = bf_rne(kk[3]);
    kl.x = bf_rne(kk[0]-bf2f(kh.x)); kl.y = bf_rne(kk[1]-bf2f(kh.y));
    kl.z = bf_rne(kk[2]-bf2f(kh.z)); kl.w = bf_rne(kk[3]-bf2f(kh.w));
    *(short4*)(Qhi + o + f*4) = qh;
    *(short4*)(Qlo + o + f*4) = ql;
    *(short4*)(Khi + o + f*4) = kh;
    *(short4*)(Klo + o + f*4) = kl;
    *(float4*)(vd + f*4) = make_float4(v[f*4], v[f*4+1], v[f*4+2], v[f*4+3]);
  }
}

// ---------------------------------------------------------------------------
// MFMA score pass: per 128x128 causal block, rowsum(exp(QK^T)) -> partZ,
// raw diag score -> sdg.  Split-bf16, 4 waves x 64x64 quadrants.
// ---------------------------------------------------------------------------
__global__ __launch_bounds__(256) void k3_scores(
    const short* __restrict__ Qhi, const short* __restrict__ Qlo,
    const short* __restrict__ Khi, const short* __restrict__ Klo,
    float* __restrict__ partZ, float* __restrict__ sdg) {
  const int cb = blockIdx.x, rb = blockIdx.y, bh = blockIdx.z;
  if (cb > rb) return;
  __shared__ short qh[128][72], ql[128][72], kh[128][72], kl[128][72];
  __shared__ float red[128][2];
  const int t = threadIdx.x;
  const int w = t >> 6, l = t & 63;
  const int wm = (w >> 1) * 64, wn = (w & 1) * 64;
  const int lr = l & 15, lg = l >> 4;
  for (int v = t; v < 1024; v += 256) {
    const int r = v >> 3, c8 = (v & 7) * 8;
    const size_t gq = (((size_t)bh * S + rb * 128 + r) << 6) + c8;
    const size_t gk = (((size_t)bh * S + cb * 128 + r) << 6) + c8;
    *(uint4*)&qh[r][c8] = *(const uint4*)(Qhi + gq);
    *(uint4*)&ql[r][c8] = *(const uint4*)(Qlo + gq);
    *(uint4*)&kh[r][c8] = *(const uint4*)(Khi + gk);
    *(uint4*)&kl[r][c8] = *(const uint4*)(Klo + gk);
  }
  __syncthreads();
  f32x4 acc[4][4];
#pragma unroll
  for (int i = 0; i < 4; ++i)
#pragma unroll
    for (int j = 0; j < 4; ++j) acc[i][j] = (f32x4)0.f;
#pragma unroll
  for (int ks = 0; ks < 2; ++ks) {
    const int lk = ks * 32 + lg * 8;
    bf16x8 ah[4], al[4], bhf[4], blf[4];
#pragma unroll
    for (int mi = 0; mi < 4; ++mi) {
      ah[mi] = *(const bf16x8*)&qh[wm + mi * 16 + lr][lk];
      al[mi] = *(const bf16x8*)&ql[wm + mi * 16 + lr][lk];
    }
#pragma unroll
    for (int ni = 0; ni < 4; ++ni) {
      bhf[ni] = *(const bf16x8*)&kh[wn + ni * 16 + lr][lk];
      blf[ni] = *(const bf16x8*)&kl[wn + ni * 16 + lr][lk];
    }
#pragma unroll
    for (int mi = 0; mi < 4; ++mi)
#pragma unroll
      for (int ni = 0; ni < 4; ++ni) {
        acc[mi][ni] = __builtin_amdgcn_mfma_f32_16x16x32_bf16(
            ah[mi], bhf[ni], acc[mi][ni], 0, 0, 0);
        acc[mi][ni] = __builtin_amdgcn_mfma_f32_16x16x32_bf16(
            al[mi], bhf[ni], acc[mi][ni], 0, 0, 0);
        acc[mi][ni] = __builtin_amdgcn_mfma_f32_16x16x32_bf16(
            ah[mi], blf[ni], acc[mi][ni], 0, 0, 0);
      }
  }
  // epilogue: mask + exp + row sums (rows: (l>>4)*4 + r, cols: lane&15)
  const int rq = lg * 4;
  const int rowbase = rb * 128 + wm, colbase = cb * 128 + wn;
  float rp[4][4];
#pragma unroll
  for (int mi = 0; mi < 4; ++mi)
#pragma unroll
    for (int r = 0; r < 4; ++r) rp[mi][r] = 0.f;
#pragma unroll
  for (int mi = 0; mi < 4; ++mi)
#pragma unroll
    for (int ni = 0; ni < 4; ++ni)
#pragma unroll
      for (int r = 0; r < 4; ++r) {
        const int rG = rowbase + mi * 16 + rq + r;
        const int cG = colbase + ni * 16 + lr;
        if (cG <= rG) rp[mi][r] += __expf(acc[mi][ni][r]);
        if (cG == rG) sdg[(size_t)bh * S + rG] = acc[mi][ni][r];
      }
#pragma unroll
  for (int off = 1; off < 16; off <<= 1)
#pragma unroll
    for (int mi = 0; mi < 4; ++mi)
#pragma unroll
      for (int r = 0; r < 4; ++r)
        rp[mi][r] += __shfl_xor(rp[mi][r], off, 64);
  if (lr == 0)
#pragma unroll
    for (int mi = 0; mi < 4; ++mi)
#pragma unroll
      for (int r = 0; r < 4; ++r)
        red[wm + mi * 16 + rq + r][w & 1] = rp[mi][r];
  __syncthreads();
  if (t < 128)
    partZ[(((size_t)bh * 16 + rb) * 16 + cb) * 128 + t] = red[t][0] + red[t][1];
}

// ---------------------------------------------------------------------------
// Stats pass 2: Z = sum of partials over cb<=rb -> zinv; pd = exp(sd)*zinv.
// ---------------------------------------------------------------------------
__global__ __launch_bounds__(256) void k3_reduce(
    const float* __restrict__ partZ, float* __restrict__ zinv,
    float* __restrict__ pdg) {
  const int R = blockIdx.x * 256 + threadIdx.x;   // 0..BH*S-1
  const int bh = R >> 11, r = R & 2047;
  const int rb = r >> 7, row = r & 127;
  float Z = 0.f;
  for (int c = 0; c <= rb; ++c)
    Z += partZ[(((size_t)bh*16 + rb)*16 + c)*128 + row];
  const float zi = 1.f / Z;
  zinv[R] = zi;
  pdg[R] = __expf(pdg[R]) * zi;
}

// ---------------------------------------------------------------------------
// Per-64-block unit-lower-triangular inverse of (I - N), 256 threads.
// ---------------------------------------------------------------------------
__global__ __launch_bounds__(256) void k4_minv(
    const short* __restrict__ Qhi, const short* __restrict__ Qlo,
    const short* __restrict__ Khi, const short* __restrict__ Klo,
    const float* __restrict__ zinv, float* __restrict__ MinvT) {
  const int bh = blockIdx.y, ib = blockIdx.x;
  const int r0 = ib * 64;
  __shared__ float Nb[64][68];
  __shared__ float X[64][68];
  const int t = threadIdx.x;
  const int w = t >> 6, l = t & 63;     // wave w owns score rows 16w..16w+15
  const int lr = l & 15, lg = l >> 4;

  // Phase A: scores rows [16w,16w+16) x cols [0,64), K=64, MFMA from global
  f32x4 acc[4];
#pragma unroll
  for (int i = 0; i < 4; ++i) acc[i] = (f32x4)0.f;
  const size_t qbase = (((size_t)bh * S + r0 + 16 * w + lr) << 6);
  const size_t kbase = ((size_t)bh * S + r0) << 6;
#pragma unroll
  for (int ks = 0; ks < 2; ++ks) {
    const int k0 = ks * 32 + lg * 8;
    const bf16x8 ah = *(const bf16x8*)(Qhi + qbase + k0);
    const bf16x8 al = *(const bf16x8*)(Qlo + qbase + k0);
#pragma unroll
    for (int ni = 0; ni < 4; ++ni) {
      const size_t kb = kbase + (((size_t)(16 * ni + lr)) << 6) + k0;
      const bf16x8 bhf = *(const bf16x8*)(Khi + kb);
      const bf16x8 blf = *(const bf16x8*)(Klo + kb);
      acc[ni] = __builtin_amdgcn_mfma_f32_16x16x32_bf16(ah, bhf, acc[ni], 0, 0, 0);
      acc[ni] = __builtin_amdgcn_mfma_f32_16x16x32_bf16(al, bhf, acc[ni], 0, 0, 0);
      acc[ni] = __builtin_amdgcn_mfma_f32_16x16x32_bf16(ah, blf, acc[ni], 0, 0, 0);
    }
  }
  // epilogue -> Nb (strict lower exp*zi, else 0)
  {
    const int rloc0 = 16 * w + lg * 4;
    float ziv[4];
#pragma unroll
    for (int i = 0; i < 4; ++i) ziv[i] = zinv[(size_t)bh * S + r0 + rloc0 + i];
#pragma unroll
    for (int ni = 0; ni < 4; ++ni) {
      const int c = 16 * ni + lr;
#pragma unroll
      for (int i = 0; i < 4; ++i) {
        const int r = rloc0 + i;
        Nb[r][c] = (c < r) ? __expf(acc[ni][i]) * ziv[i] : 0.f;
      }
    }
  }
  // Phase B: X = I  (thread (c,g) inits rows 16g..16g+15 of column c)
  {
    const int c = t & 63, g = t >> 6;
#pragma unroll
    for (int i = 0; i < 16; ++i) {
      const int r = 16 * g + i;
      X[r][c] = (r == c) ? 1.f : 0.f;
    }
  }
  __syncthreads();

  // Phase C: panel-blocked forward substitution, X = (I - N)^-1
  const int c = t & 63, g = t >> 6;
  if (w == 0) {
    for (int rr = 1; rr < 16; ++rr) {
      float a = 0.f;
      for (int j = 0; j < rr; ++j) a += Nb[rr][j] * X[j][l];
      X[rr][l] += a;
    }
  }
  __syncthreads();
#pragma unroll
  for (int I = 1; I < 4; ++I) {
    {
      const int rb4 = 16 * I + 4 * g;
      float s0 = 0.f, s1 = 0.f, s2 = 0.f, s3 = 0.f;
      for (int j = 0; j < 16 * I; j += 4) {
        const float4 n0 = *(const float4*)&Nb[rb4 + 0][j];
        const float4 n1 = *(const float4*)&Nb[rb4 + 1][j];
        const float4 n2 = *(const float4*)&Nb[rb4 + 2][j];
        const float4 n3 = *(const float4*)&Nb[rb4 + 3][j];
        const float x0 = X[j + 0][c], x1 = X[j + 1][c];
        const float x2 = X[j + 2][c], x3 = X[j + 3][c];
        s0 += n0.x * x0 + n0.y * x1 + n0.z * x2 + n0.w * x3;
        s1 += n1.x * x0 + n1.y * x1 + n1.z * x2 + n1.w * x3;
        s2 += n2.x * x0 + n2.y * x1 + n2.z * x2 + n2.w * x3;
        s3 += n3.x * x0 + n3.y * x1 + n3.z * x2 + n3.w * x3;
      }
      X[rb4 + 0][c] += s0; X[rb4 + 1][c] += s1;
      X[rb4 + 2][c] += s2; X[rb4 + 3][c] += s3;
    }
    __syncthreads();
    if (w == 0) {
      const int rb = 16 * I;
      for (int rr = 1; rr < 16; ++rr) {
        const int r = rb + rr;
        float a = 0.f;
        for (int j = rb; j < r; ++j) a += Nb[r][j] * X[j][l];
        X[r][l] += a;
      }
    }
    __syncthreads();
  }

  // Phase D: write MinvT[bh][ib][c][r] = X[r][c]
  float* dst = MinvT + (((size_t)bh * 32 + ib) * 64 + c) * 64;
#pragma unroll
  for (int rq = 0; rq < 4; ++rq) {
    const int r = 16 * g + rq * 4;
    float4 o;
    o.x = X[r + 0][c]; o.y = X[r + 1][c]; o.z = X[r + 2][c]; o.w = X[r + 3][c];
    *(float4*)(dst + r) = o;
  }
}

// ---------------------------------------------------------------------------
// Scan step k off-diagonal accumulate, FULL MFMA:
//   upart[bh][j] = P(k-rows x j-block) @ A_j, P = exp(QK^T)*zi.
// QK: split-bf16 MFMA, fragments straight from global (rows contiguous).
// E kept fp32 in LDS, split to bf16 on read.  A_j staged transposed (fp32),
// split on read.  4 waves x 32 rows; two 64-col halves.
// ---------------------------------------------------------------------------
__global__ __launch_bounds__(256) void k5_acc(
    const short* __restrict__ Qhi, const short* __restrict__ Qlo,
    const short* __restrict__ Khi, const short* __restrict__ Klo,
    const float* __restrict__ Abuf, const float* __restrict__ zinv,
    float* __restrict__ upart, int kstep) {
  const int bh = blockIdx.y, j = blockIdx.x;
  __shared__ float Es[128][68];     // E half (fp32), [row][s-col]
  __shared__ float Ats[64][68];     // A_j half transposed (fp32), [d][s-row]
  const int t = threadIdx.x;
  const int w = t >> 6, l = t & 63;
  const int lr = l & 15, lg = l >> 4;
  const int rw = 32 * w;            // wave's output-row offset
  const int base = kstep * 128;

  // Q fragments for rows base+rw+{0,16}+lr, k-slices {0,32}+lg*8 (both halves)
  bf16x8 qfh[2][2], qfl[2][2];
#pragma unroll
  for (int mi = 0; mi < 2; ++mi)
#pragma unroll
    for (int ks = 0; ks < 2; ++ks) {
      const size_t qo = (((size_t)bh * S + base + rw + mi * 16 + lr) << 6) + ks * 32 + lg * 8;
      qfh[mi][ks] = *(const bf16x8*)(Qhi + qo);
      qfl[mi][ks] = *(const bf16x8*)(Qlo + qo);
    }
  float ziv[2][4];
#pragma unroll
  for (int mi = 0; mi < 2; ++mi)
#pragma unroll
    for (int r = 0; r < 4; ++r)
      ziv[mi][r] = zinv[(size_t)bh * S + base + rw + mi * 16 + lg * 4 + r];

  f32x4 out[2][4];                  // PV acc: rows rw+mi*16.., cols d=ni*16+lr
#pragma unroll
  for (int mi = 0; mi < 2; ++mi)
#pragma unroll
    for (int ni = 0; ni < 4; ++ni) out[mi][ni] = (f32x4)0.f;

  for (int h = 0; h < 2; ++h) {
    __syncthreads();                // protect Es/Ats from previous half's reads
    // stage A_j half transposed: Ats[d][s] = A[j*128+h*64+s][d]
    for (int v = t; v < 1024; v += 256) {
      const int d = v & 63, sq = v >> 6;        // sq: 0..15 across iterations
      const size_t ab = ((size_t)bh * S + j * 128 + h * 64 + sq * 4) << 6;
      float4 o;
      o.x = Abuf[ab + d];
      o.y = Abuf[ab + 64 + d];
      o.z = Abuf[ab + 128 + d];
      o.w = Abuf[ab + 192 + d];
      *(float4*)&Ats[d][sq * 4] = o;
    }
    // QK: cols (j*128 + h*64) + ni*16 + lr, K=64
    f32x4 qk[2][4];
#pragma unroll
    for (int mi = 0; mi < 2; ++mi)
#pragma unroll
      for (int ni = 0; ni < 4; ++ni) qk[mi][ni] = (f32x4)0.f;
#pragma unroll
    for (int ks = 0; ks < 2; ++ks) {
#pragma unroll
      for (int ni = 0; ni < 4; ++ni) {
        const size_t ko = (((size_t)bh * S + j * 128 + h * 64 + ni * 16 + lr) << 6) + ks * 32 + lg * 8;
        const bf16x8 kh8 = *(const bf16x8*)(Khi + ko);
        const bf16x8 kl8 = *(const bf16x8*)(Klo + ko);
#pragma unroll
        for (int mi = 0; mi < 2; ++mi) {
          qk[mi][ni] = __builtin_amdgcn_mfma_f32_16x16x32_bf16(
              qfh[mi][ks], kh8, qk[mi][ni], 0, 0, 0);
          qk[mi][ni] = __builtin_amdgcn_mfma_f32_16x16x32_bf16(
              qfl[mi][ks], kh8, qk[mi][ni], 0, 0, 0);
          qk[mi][ni] = __builtin_amdgcn_mfma_f32_16x16x32_bf16(
              qfh[mi][ks], kl8, qk[mi][ni], 0, 0, 0);
        }
      }
    }
    // epilogue: Es[row][col] = exp(qk)*zi
#pragma unroll
    for (int mi = 0; mi < 2; ++mi)
#pragma unroll
      for (int ni = 0; ni < 4; ++ni)
#pragma unroll
        for (int r = 0; r < 4; ++r)
          Es[rw + mi * 16 + lg * 4 + r][ni * 16 + lr] =
              __expf(qk[mi][ni][r]) * ziv[mi][r];
    __syncthreads();
    // PV: out += E(128x64) @ A_half(64x64), split-bf16 on the fly
#pragma unroll
    for (int ks = 0; ks < 2; ++ks) {
      bf16x8 eh[2], el[2];
#pragma unroll
      for (int mi = 0; mi < 2; ++mi) {
        const float* ep = &Es[rw + mi * 16 + lr][ks * 32 + lg * 8];
        split8(*(const float4*)ep, *(const float4*)(ep + 4), eh[mi], el[mi]);
      }
#pragma unroll
      for (int ni = 0; ni < 4; ++ni) {
        const float* ap = &Ats[ni * 16 + lr][ks * 32 + lg * 8];
        bf16x8 ah8, al8;
        split8(*(const float4*)ap, *(const float4*)(ap + 4), ah8, al8);
#pragma unroll
        for (int mi = 0; mi < 2; ++mi) {
          out[mi][ni] = __builtin_amdgcn_mfma_f32_16x16x32_bf16(
              eh[mi], ah8, out[mi][ni], 0, 0, 0);
          out[mi][ni] = __builtin_amdgcn_mfma_f32_16x16x32_bf16(
              el[mi], ah8, out[mi][ni], 0, 0, 0);
          out[mi][ni] = __builtin_amdgcn_mfma_f32_16x16x32_bf16(
              eh[mi], al8, out[mi][ni], 0, 0, 0);
        }
      }
    }
  }
  // write upart: row = rw+mi*16+lg*4+r, col d = ni*16+lr
  float* ub = upart + (((size_t)bh * 15 + j) * 128) * 64;
#pragma unroll
  for (int mi = 0; mi < 2; ++mi)
#pragma unroll
    for (int ni = 0; ni < 4; ++ni)
#pragma unroll
      for (int r = 0; r < 4; ++r)
        ub[(size_t)(rw + mi * 16 + lg * 4 + r) * 64 + ni * 16 + lr] =
            out[mi][ni][r];
}

// ---------------------------------------------------------------------------
// Scan step k finalize, parallel over 16-d chunks (grid 4 x BH):
//   u = pd*v + sum(upart);  A_lo = Minv@u_lo (kept in LDS);
//   u_hi += P(hi,lo)@A_lo;  A_hi = Minv@u_hi.
// ---------------------------------------------------------------------------
__global__ __launch_bounds__(256) void k5_fin(
    const short* __restrict__ Qhi, const short* __restrict__ Qlo,
    const short* __restrict__ Khi, const short* __restrict__ Klo,
    const float* __restrict__ V, const float* __restrict__ pd,
    const float* __restrict__ zinv, const float* __restrict__ upart,
    const float* __restrict__ MinvT, float* __restrict__ Abuf, int kstep) {
  const int dc0 = blockIdx.x * 16;
  const int bh  = blockIdx.y;
  const int t = threadIdx.x;
  const int base = kstep * 128;
  __shared__ float u[128][16];
  __shared__ float alo[64][17];
  __shared__ float kst[64][68];     // MinvT / K staging (sequential reuse)
  __shared__ float pbuf[64][65];

  // phase 0: u = pd*v + sum partials (this d-chunk); stage MinvT(2k)
  for (int v4 = t; v4 < 512; v4 += 256) {
    const int r = v4 >> 2, f = v4 & 3;
    const int R = base + r;
    const float4 x = *(const float4*)(V + (((size_t)bh*S + R) << 6) + dc0 + f*4);
    const float p = pd[bh*S + R];
    float a0 = p*x.x, a1 = p*x.y, a2 = p*x.z, a3 = p*x.w;
    for (int j = 0; j < kstep; ++j) {
      const float4 y = *(const float4*)(upart + ((((size_t)bh*15 + j)*128 + r) << 6) + dc0 + f*4);
      a0 += y.x; a1 += y.y; a2 += y.z; a3 += y.w;
    }
    *(float4*)&u[r][f*4] = make_float4(a0, a1, a2, a3);
  }
  for (int v4 = t; v4 < 1024; v4 += 256) {
    const int j = v4 >> 4, f = v4 & 15;
    *(float4*)&kst[j][f*4] =
      *(const float4*)(MinvT + ((((size_t)bh*32 + kstep*2)*64 + j) << 6) + f*4);
  }
  __syncthreads();
  // phase 1: A_lo = Minv @ u_lo (this d-chunk); keep in LDS + write global
  {
    const int r = t & 63, dq = (t >> 6) * 4;
    float a0=0.f, a1=0.f, a2=0.f, a3=0.f;
    for (int j = 0; j < 64; ++j) {
      const float w = kst[j][r];
      a0 += w*u[j][dq];   a1 += w*u[j][dq+1];
      a2 += w*u[j][dq+2]; a3 += w*u[j][dq+3];
    }
    alo[r][dq] = a0; alo[r][dq+1] = a1; alo[r][dq+2] = a2; alo[r][dq+3] = a3;
    *(float4*)(Abuf + (((size_t)bh*S + base + r) << 6) + dc0 + dq) =
        make_float4(a0, a1, a2, a3);
  }
  __syncthreads();
  for (int v4 = t; v4 < 1024; v4 += 256) {   // stage K rows [base, base+64)
    const int j = v4 >> 4, f = v4 & 15;
    *(float4*)&kst[j][f*4] = ld_hl4(Khi, Klo, (((size_t)bh*S + base + j) << 6) + f*4);
  }
  __syncthreads();
  // phase 2a: pbuf[r][j] = exp(q_{base+64+r} . k_j) * zi  (dots computed once)
  {
    const int rp = t >> 2, c4 = t & 3;
    const int R = base + 64 + rp;
    float q[64];
#pragma unroll
    for (int f = 0; f < 16; ++f) {
      const float4 x = ld_hl4(Qhi, Qlo, (((size_t)bh*S + R) << 6) + f*4);
      q[f*4]=x.x; q[f*4+1]=x.y; q[f*4+2]=x.z; q[f*4+3]=x.w;
    }
    const float zi = zinv[bh*S + R];
    for (int j = c4; j < 64; j += 4) {
      float s = 0.f;
#pragma unroll
      for (int i4 = 0; i4 < 16; ++i4) {
        const float4 kv = *(const float4*)&kst[j][i4*4];
        s += q[i4*4]*kv.x + q[i4*4+1]*kv.y + q[i4*4+2]*kv.z + q[i4*4+3]*kv.w;
      }
      pbuf[rp][j] = __expf(s) * zi;
    }
  }
  __syncthreads();
  // phase 2b: u_hi += P @ A_lo (this d-chunk, A_lo from LDS)
  {
    const int r = t & 63, dq = (t >> 6) * 4;
    float a0=0.f, a1=0.f, a2=0.f, a3=0.f;
    for (int j = 0; j < 64; ++j) {
      const float p = pbuf[r][j];
      a0 += p*alo[j][dq];   a1 += p*alo[j][dq+1];
      a2 += p*alo[j][dq+2]; a3 += p*alo[j][dq+3];
    }
    u[64+r][dq] += a0; u[64+r][dq+1] += a1;
    u[64+r][dq+2] += a2; u[64+r][dq+3] += a3;
  }
  __syncthreads();
  for (int v4 = t; v4 < 1024; v4 += 256) {   // stage MinvT(2k+1)
    const int j = v4 >> 4, f = v4 & 15;
    *(float4*)&kst[j][f*4] =
      *(const float4*)(MinvT + ((((size_t)bh*32 + kstep*2 + 1)*64 + j) << 6) + f*4);
  }
  __syncthreads();
  // phase 3: A_hi = Minv @ u_hi
  {
    const int r = t & 63, dq = (t >> 6) * 4;
    float a0=0.f, a1=0.f, a2=0.f, a3=0.f;
    for (int j = 0; j < 64; ++j) {
      const float w = kst[j][r];
      a0 += w*u[64+j][dq];   a1 += w*u[64+j][dq+1];
      a2 += w*u[64+j][dq+2]; a3 += w*u[64+j][dq+3];
    }
    *(float4*)(Abuf + (((size_t)bh*S + base + 64 + r) << 6) + dc0 + dq) =
        make_float4(a0, a1, a2, a3);
  }
}

} // namespace

extern "C" void kernel_launch(void* const* d_in, const int* in_sizes, int n_in,
                              void* d_out, int out_size, void* d_ws, size_t ws_size,
                              hipStream_t stream) {
  const float* hs   = (const float*)d_in[0];
  const float* Wqkv = (const float*)d_in[1];
  const float* bqkv = (const float*)d_in[2];
  const float* Wd   = (const float*)d_in[3];
  const float* bd   = (const float*)d_in[4];
  float* out = (float*)d_out;
  float* W   = (float*)d_ws;
  if (ws_size < WS_FLOATS * sizeof(float)) return;  // insufficient scratch

  float* qkv   = W + OFF_QKV;
  float* partZ = W + OFF_PART;
  float* MinvT = W + OFF_MINV;
  float* Abuf  = W + OFF_A;
  short* Qhi   = (short*)(W + OFF_Q);
  short* Qlo   = Qhi + 4194304;
  short* Khi   = (short*)(W + OFF_K);
  short* Klo   = Khi + 4194304;
  float* Vb    = W + OFF_V;
  float* zi    = W + OFF_ZI;
  float* pdg   = W + OFF_PD;
  float* up    = W + OFF_UP;

  char* wsb = (char*)d_ws;
  short* Ahi  = (short*)(wsb + 50331648);
  short* Alo  = Ahi + 4194304;                 // 4096x1024
  short* Whi  = (short*)(wsb + 67108864);
  short* Wlo  = Whi + 3145728;                 // 3072x1024
  short* A2hi = (short*)(wsb + 50331648);
  short* A2lo = A2hi + 4194304;
  short* Wdhi = (short*)(wsb + 67108864);
  short* Wdlo = Wdhi + 1048576;                // 1024x1024

  split2<<<dim3(2048), 256, 0, stream>>>(hs, Ahi, Alo, B*S*HID/4);
  split2<<<dim3(2048), 256, 0, stream>>>(Wqkv, Whi, Wlo, 3*HID*HID/4);
  gemm_bf3<<<dim3(24, 32), 256, 0, stream>>>(Ahi, Alo, Whi, Wlo, bqkv, qkv,
                                             B*S, 3*HID, HID);
  k2_rope<<<dim3(BH * S / 256), 256, 0, stream>>>(qkv, Qhi, Qlo, Khi, Klo, Vb);
  k3_scores<<<dim3(16, 16, BH), 256, 0, stream>>>(Qhi, Qlo, Khi, Klo, partZ, pdg);
  k3_reduce<<<dim3(BH * S / 256), 256, 0, stream>>>(partZ, zi, pdg);
  k4_minv<<<dim3(S / 64, BH), 256, 0, stream>>>(Qhi, Qlo, Khi, Klo, zi, MinvT);
  for (int k = 0; k < NSTEP; ++k) {
    if (k > 0)
      k5_acc<<<dim3(k, BH), 256, 0, stream>>>(Qhi, Qlo, Khi, Klo, Abuf, zi, up, k);
    k5_fin<<<dim3(4, BH), 256, 0, stream>>>(Qhi, Qlo, Khi, Klo, Vb, pdg, zi, up,
                                            MinvT, Abuf, k);
  }
  split_gather<<<dim3(2048), 256, 0, stream>>>(Abuf, A2hi, A2lo);
  split2<<<dim3(2048), 256, 0, stream>>>(Wd, Wdhi, Wdlo, HID*HID/4);
  gemm_bf3<<<dim3(8, 32), 256, 0, stream>>>(A2hi, A2lo, Wdhi, Wdlo, bd, out,
                                            B*S, HID, HID);
}

// Round 8
// 738.944 us; speedup vs baseline: 4.5371x; 1.2496x over previous
//
#include <hip/hip_runtime.h>
#include <math.h>

namespace {

constexpr int B  = 2, S = 2048, NH = 16, HD = 64, HID = 1024;
constexpr int BH = B * NH;          // 32
constexpr int NSTEP = 16;           // 128-row scan blocks

// ws layout in floats.
constexpr size_t OFF_QKV  = 0;
constexpr size_t OFF_PART = 0;                 // [BH][16][16][128] Z partials (transient)
constexpr size_t OFF_A    = 4194304;           // [BH][S][HD] fp32
constexpr size_t OFF_Q    = 12582912;          // Qhi/Qlo bf16 pairs
constexpr size_t OFF_K    = 16777216;          // Khi/Klo bf16 pairs
constexpr size_t OFF_V    = 20971520;          // fp32 V
constexpr size_t OFF_ZI   = 25231360;          // [BH*S]
constexpr size_t OFF_PD   = 25296896;          // [BH*S]
constexpr size_t OFF_UP   = 25362432;          // [BH][15][128][64]
constexpr size_t WS_FLOATS = 29294592;         // ~117 MB

typedef __attribute__((ext_vector_type(8))) short bf16x8;
typedef __attribute__((ext_vector_type(4))) float f32x4;

__device__ inline unsigned short bf_rne(float x) {
  const unsigned u = __float_as_uint(x);
  return (unsigned short)((u + 0x7FFFu + ((u >> 16) & 1u)) >> 16);
}
__device__ inline float bf2f(short h) {
  return __uint_as_float((unsigned)(unsigned short)h << 16);
}
__device__ inline float4 ld_hl4(const short* __restrict__ hi,
                                const short* __restrict__ lo, size_t off) {
  const short4 h = *(const short4*)(hi + off);
  const short4 l = *(const short4*)(lo + off);
  return make_float4(bf2f(h.x) + bf2f(l.x), bf2f(h.y) + bf2f(l.y),
                     bf2f(h.z) + bf2f(l.z), bf2f(h.w) + bf2f(l.w));
}
// split 8 fp32 (two float4) into hi/lo bf16x8 fragments
__device__ inline void split8(const float4 a, const float4 b,
                              bf16x8& hi, bf16x8& lo) {
  float v[8] = {a.x, a.y, a.z, a.w, b.x, b.y, b.z, b.w};
#pragma unroll
  for (int i = 0; i < 8; ++i) {
    const unsigned short h = bf_rne(v[i]);
    hi[i] = (short)h;
    lo[i] = (short)bf_rne(v[i] - bf2f((short)h));
  }
}

// ---------------------------------------------------------------------------
__global__ __launch_bounds__(256) void split2(
    const float* __restrict__ in, short* __restrict__ hi,
    short* __restrict__ lo, int n4) {
  for (int g = blockIdx.x * 256 + threadIdx.x; g < n4; g += gridDim.x * 256) {
    const float4 x = *(const float4*)(in + (size_t)g * 4);
    short4 h, l;
    h.x = bf_rne(x.x); h.y = bf_rne(x.y); h.z = bf_rne(x.z); h.w = bf_rne(x.w);
    l.x = bf_rne(x.x - bf2f(h.x));
    l.y = bf_rne(x.y - bf2f(h.y));
    l.z = bf_rne(x.z - bf2f(h.z));
    l.w = bf_rne(x.w - bf2f(h.w));
    *(short4*)(hi + (size_t)g * 4) = h;
    *(short4*)(lo + (size_t)g * 4) = l;
  }
}

// ---------------------------------------------------------------------------
__global__ __launch_bounds__(256) void split_gather(
    const float* __restrict__ Abuf, short* __restrict__ hi,
    short* __restrict__ lo) {
  const int n4 = B * S * HID / 4;
  for (int g = blockIdx.x * 256 + threadIdx.x; g < n4; g += gridDim.x * 256) {
    const int m = g >> 8, q = g & 255;
    const int k0 = q * 4;
    const int b = m >> 11, s = m & (S - 1);
    const int h = k0 >> 6, d = k0 & 63;
    const float4 x = *(const float4*)(Abuf + (((size_t)(b * NH + h) * S + s) << 6) + d);
    short4 hh, ll;
    hh.x = bf_rne(x.x); hh.y = bf_rne(x.y); hh.z = bf_rne(x.z); hh.w = bf_rne(x.w);
    ll.x = bf_rne(x.x - bf2f(hh.x));
    ll.y = bf_rne(x.y - bf2f(hh.y));
    ll.z = bf_rne(x.z - bf2f(hh.z));
    ll.w = bf_rne(x.w - bf2f(hh.w));
    *(short4*)(hi + (size_t)m * HID + k0) = hh;
    *(short4*)(lo + (size_t)m * HID + k0) = ll;
  }
}

// ---------------------------------------------------------------------------
// Split-bf16 MFMA NT GEMM: C = A @ B^T + bias (fp32 via 3 bf16 chains).
// ---------------------------------------------------------------------------
__global__ __launch_bounds__(256) void gemm_bf3(
    const short* __restrict__ Ahi, const short* __restrict__ Alo,
    const short* __restrict__ Bhi, const short* __restrict__ Blo,
    const float* __restrict__ bias, float* __restrict__ C,
    int M, int N, int K) {
  __shared__ short ash[128][40], als[128][40], bsh[128][40], bls[128][40];
  const int t = threadIdx.x;
  const int m0 = blockIdx.y * 128, n0 = blockIdx.x * 128;
  const int w = t >> 6, l = t & 63;
  const int wm = (w >> 1) * 64, wn = (w & 1) * 64;
  const int lr = l & 15, lk = (l >> 4) * 8;
  f32x4 acc[4][4];
#pragma unroll
  for (int i = 0; i < 4; ++i)
#pragma unroll
    for (int j = 0; j < 4; ++j) acc[i][j] = (f32x4)0.f;

  for (int kb = 0; kb < K; kb += 32) {
    __syncthreads();
#pragma unroll
    for (int i = 0; i < 2; ++i) {
      const int idx = t + i * 256;
      const int row = idx >> 2, c8 = (idx & 3) * 8;
      *(uint4*)&ash[row][c8] = *(const uint4*)(Ahi + (size_t)(m0 + row) * K + kb + c8);
      *(uint4*)&als[row][c8] = *(const uint4*)(Alo + (size_t)(m0 + row) * K + kb + c8);
      *(uint4*)&bsh[row][c8] = *(const uint4*)(Bhi + (size_t)(n0 + row) * K + kb + c8);
      *(uint4*)&bls[row][c8] = *(const uint4*)(Blo + (size_t)(n0 + row) * K + kb + c8);
    }
    __syncthreads();
    bf16x8 ah[4], al[4], bh[4], bl[4];
#pragma unroll
    for (int mi = 0; mi < 4; ++mi) {
      ah[mi] = *(const bf16x8*)&ash[wm + mi * 16 + lr][lk];
      al[mi] = *(const bf16x8*)&als[wm + mi * 16 + lr][lk];
    }
#pragma unroll
    for (int ni = 0; ni < 4; ++ni) {
      bh[ni] = *(const bf16x8*)&bsh[wn + ni * 16 + lr][lk];
      bl[ni] = *(const bf16x8*)&bls[wn + ni * 16 + lr][lk];
    }
#pragma unroll
    for (int mi = 0; mi < 4; ++mi)
#pragma unroll
      for (int ni = 0; ni < 4; ++ni) {
        acc[mi][ni] = __builtin_amdgcn_mfma_f32_16x16x32_bf16(
            ah[mi], bh[ni], acc[mi][ni], 0, 0, 0);
        acc[mi][ni] = __builtin_amdgcn_mfma_f32_16x16x32_bf16(
            al[mi], bh[ni], acc[mi][ni], 0, 0, 0);
        acc[mi][ni] = __builtin_amdgcn_mfma_f32_16x16x32_bf16(
            ah[mi], bl[ni], acc[mi][ni], 0, 0, 0);
      }
  }
  const int rq = (l >> 4) * 4;
#pragma unroll
  for (int ni = 0; ni < 4; ++ni) {
    const int col = n0 + wn + ni * 16 + lr;
    const float bv = bias[col];
#pragma unroll
    for (int mi = 0; mi < 4; ++mi)
#pragma unroll
      for (int r = 0; r < 4; ++r) {
        const int row = m0 + wm + mi * 16 + rq + r;
        C[(size_t)row * N + col] = acc[mi][ni][r] + bv;
      }
  }
}

// ---------------------------------------------------------------------------
// RoPE + transpose -> Qhi/Qlo, Khi/Klo (bf16 split, [bh][s][d]) + fp32 V.
// ---------------------------------------------------------------------------
__global__ __launch_bounds__(256) void k2_rope(
    const float* __restrict__ qkv, short* __restrict__ Qhi,
    short* __restrict__ Qlo, short* __restrict__ Khi,
    short* __restrict__ Klo, float* __restrict__ V) {
  const int g  = blockIdx.x * 256 + threadIdx.x;   // (bh, s)
  const int s  = g & (S - 1);
  const int bh = g >> 11;
  const int b  = bh >> 4, h = bh & 15;
  const float* base = qkv + ((size_t)b * S + s) * 3072 + h * 64;
  float q[64], k[64], v[64];
#pragma unroll
  for (int f = 0; f < 16; ++f) {
    const float4 x = *(const float4*)(base + f * 4);
    q[f*4+0]=x.x; q[f*4+1]=x.y; q[f*4+2]=x.z; q[f*4+3]=x.w;
    const float4 y = *(const float4*)(base + 1024 + f * 4);
    k[f*4+0]=y.x; k[f*4+1]=y.y; k[f*4+2]=y.z; k[f*4+3]=y.w;
    const float4 z = *(const float4*)(base + 2048 + f * 4);
    v[f*4+0]=z.x; v[f*4+1]=z.y; v[f*4+2]=z.z; v[f*4+3]=z.w;
  }
  const float PW[8] = {1.0f, 3.1622776601683795f, 10.0f, 31.622776601683793f,
                       100.0f, 316.22776601683796f, 1000.0f, 3162.2776601683795f};
  float qr[16], kr[16];
#pragma unroll
  for (int d = 0; d < 16; ++d) {
    const int j = d & 7;
    const float invf = 1.0f / PW[j];
    const float fr = (float)s * invf;
    float sn, c;
    sincosf(fr, &sn, &c);
    const float rq = (d < 8) ? -q[d + 8] : q[d - 8];
    const float rk = (d < 8) ? -k[d + 8] : k[d - 8];
    qr[d] = q[d] * c + rq * sn;
    kr[d] = k[d] * c + rk * sn;
  }
#pragma unroll
  for (int d = 0; d < 16; ++d) { q[d] = qr[d]; k[d] = kr[d]; }
#pragma unroll
  for (int d = 0; d < 64; ++d) q[d] *= 0.125f;   // fold softmax scale into Q
  const size_t o = ((size_t)bh * S + s) << 6;
  float* vd = V + o;
#pragma unroll
  for (int f = 0; f < 16; ++f) {
    short4 qh, ql, kh, kl;
    const float* qq = q + f * 4;
    const float* kk = k + f * 4;
    qh.x = bf_rne(qq[0]); qh.y = bf_rne(qq[1]); qh.z = bf_rne(qq[2]); qh.w = bf_rne(qq[3]);
    ql.x = bf_rne(qq[0]-bf2f(qh.x)); ql.y = bf_rne(qq[1]-bf2f(qh.y));
    ql.z = bf_rne(qq[2]-bf2f(qh.z)); ql.w = bf_rne(qq[3]-bf2f(qh.w));
    kh.x = bf_rne(kk[0]); kh.y = bf_rne(kk[1]); kh.z = bf_rne(kk[2]); kh.w = bf_rne(kk[3]);
    kl.x = bf_rne(kk[0]-bf2f(kh.x)); kl.y = bf_rne(kk[1]-bf2f(kh.y));
    kl.z = bf_rne(kk[2]-bf2f(kh.z)); kl.w = bf_rne(kk[3]-bf2f(kh.w));
    *(short4*)(Qhi + o + f*4) = qh;
    *(short4*)(Qlo + o + f*4) = ql;
    *(short4*)(Khi + o + f*4) = kh;
    *(short4*)(Klo + o + f*4) = kl;
    *(float4*)(vd + f*4) = make_float4(v[f*4], v[f*4+1], v[f*4+2], v[f*4+3]);
  }
}

// ---------------------------------------------------------------------------
// MFMA score pass: per 128x128 causal block, rowsum(exp(QK^T)) -> partZ,
// raw diag score -> sdg.
// ---------------------------------------------------------------------------
__global__ __launch_bounds__(256) void k3_scores(
    const short* __restrict__ Qhi, const short* __restrict__ Qlo,
    const short* __restrict__ Khi, const short* __restrict__ Klo,
    float* __restrict__ partZ, float* __restrict__ sdg) {
  const int cb = blockIdx.x, rb = blockIdx.y, bh = blockIdx.z;
  if (cb > rb) return;
  __shared__ short qh[128][72], ql[128][72], kh[128][72], kl[128][72];
  __shared__ float red[128][2];
  const int t = threadIdx.x;
  const int w = t >> 6, l = t & 63;
  const int wm = (w >> 1) * 64, wn = (w & 1) * 64;
  const int lr = l & 15, lg = l >> 4;
  for (int v = t; v < 1024; v += 256) {
    const int r = v >> 3, c8 = (v & 7) * 8;
    const size_t gq = (((size_t)bh * S + rb * 128 + r) << 6) + c8;
    const size_t gk = (((size_t)bh * S + cb * 128 + r) << 6) + c8;
    *(uint4*)&qh[r][c8] = *(const uint4*)(Qhi + gq);
    *(uint4*)&ql[r][c8] = *(const uint4*)(Qlo + gq);
    *(uint4*)&kh[r][c8] = *(const uint4*)(Khi + gk);
    *(uint4*)&kl[r][c8] = *(const uint4*)(Klo + gk);
  }
  __syncthreads();
  f32x4 acc[4][4];
#pragma unroll
  for (int i = 0; i < 4; ++i)
#pragma unroll
    for (int j = 0; j < 4; ++j) acc[i][j] = (f32x4)0.f;
#pragma unroll
  for (int ks = 0; ks < 2; ++ks) {
    const int lk = ks * 32 + lg * 8;
    bf16x8 ah[4], al[4], bhf[4], blf[4];
#pragma unroll
    for (int mi = 0; mi < 4; ++mi) {
      ah[mi] = *(const bf16x8*)&qh[wm + mi * 16 + lr][lk];
      al[mi] = *(const bf16x8*)&ql[wm + mi * 16 + lr][lk];
    }
#pragma unroll
    for (int ni = 0; ni < 4; ++ni) {
      bhf[ni] = *(const bf16x8*)&kh[wn + ni * 16 + lr][lk];
      blf[ni] = *(const bf16x8*)&kl[wn + ni * 16 + lr][lk];
    }
#pragma unroll
    for (int mi = 0; mi < 4; ++mi)
#pragma unroll
      for (int ni = 0; ni < 4; ++ni) {
        acc[mi][ni] = __builtin_amdgcn_mfma_f32_16x16x32_bf16(
            ah[mi], bhf[ni], acc[mi][ni], 0, 0, 0);
        acc[mi][ni] = __builtin_amdgcn_mfma_f32_16x16x32_bf16(
            al[mi], bhf[ni], acc[mi][ni], 0, 0, 0);
        acc[mi][ni] = __builtin_amdgcn_mfma_f32_16x16x32_bf16(
            ah[mi], blf[ni], acc[mi][ni], 0, 0, 0);
      }
  }
  const int rq = lg * 4;
  const int rowbase = rb * 128 + wm, colbase = cb * 128 + wn;
  float rp[4][4];
#pragma unroll
  for (int mi = 0; mi < 4; ++mi)
#pragma unroll
    for (int r = 0; r < 4; ++r) rp[mi][r] = 0.f;
#pragma unroll
  for (int mi = 0; mi < 4; ++mi)
#pragma unroll
    for (int ni = 0; ni < 4; ++ni)
#pragma unroll
      for (int r = 0; r < 4; ++r) {
        const int rG = rowbase + mi * 16 + rq + r;
        const int cG = colbase + ni * 16 + lr;
        if (cG <= rG) rp[mi][r] += __expf(acc[mi][ni][r]);
        if (cG == rG) sdg[(size_t)bh * S + rG] = acc[mi][ni][r];
      }
#pragma unroll
  for (int off = 1; off < 16; off <<= 1)
#pragma unroll
    for (int mi = 0; mi < 4; ++mi)
#pragma unroll
      for (int r = 0; r < 4; ++r)
        rp[mi][r] += __shfl_xor(rp[mi][r], off, 64);
  if (lr == 0)
#pragma unroll
    for (int mi = 0; mi < 4; ++mi)
#pragma unroll
      for (int r = 0; r < 4; ++r)
        red[wm + mi * 16 + rq + r][w & 1] = rp[mi][r];
  __syncthreads();
  if (t < 128)
    partZ[(((size_t)bh * 16 + rb) * 16 + cb) * 128 + t] = red[t][0] + red[t][1];
}

// ---------------------------------------------------------------------------
__global__ __launch_bounds__(256) void k3_reduce(
    const float* __restrict__ partZ, float* __restrict__ zinv,
    float* __restrict__ pdg) {
  const int R = blockIdx.x * 256 + threadIdx.x;
  const int bh = R >> 11, r = R & 2047;
  const int rb = r >> 7, row = r & 127;
  float Z = 0.f;
  for (int c = 0; c <= rb; ++c)
    Z += partZ[(((size_t)bh*16 + rb)*16 + c)*128 + row];
  const float zi = 1.f / Z;
  zinv[R] = zi;
  pdg[R] = __expf(pdg[R]) * zi;
}

// ---------------------------------------------------------------------------
// Per-64-block unit-lower-triangular inverse of (I - N), 256 threads.
// Emits Minv64 ROW-MAJOR split-bf16 (Mrh/Mrl).  For odd 64-blocks also emits
// the intra-128-step coupling P10 = exp(S[odd rows, even cols])*zi, split-bf16.
// ---------------------------------------------------------------------------
__global__ __launch_bounds__(256) void k4_minv(
    const short* __restrict__ Qhi, const short* __restrict__ Qlo,
    const short* __restrict__ Khi, const short* __restrict__ Klo,
    const float* __restrict__ zinv, short* __restrict__ Mrh,
    short* __restrict__ Mrl, short* __restrict__ P10h,
    short* __restrict__ P10l) {
  const int bh = blockIdx.y, ib = blockIdx.x;
  const int r0 = ib * 64;
  __shared__ float Nb[64][68];
  __shared__ float X[64][68];
  const int t = threadIdx.x;
  const int w = t >> 6, l = t & 63;
  const int lr = l & 15, lg = l >> 4;

  // Q fragments (rows r0 + 16w + lr), reused for diag scores and P10
  bf16x8 qfh[2], qfl[2];
  const size_t qbase = (((size_t)bh * S + r0 + 16 * w + lr) << 6);
#pragma unroll
  for (int ks = 0; ks < 2; ++ks) {
    qfh[ks] = *(const bf16x8*)(Qhi + qbase + ks * 32 + lg * 8);
    qfl[ks] = *(const bf16x8*)(Qlo + qbase + ks * 32 + lg * 8);
  }
  const int rloc0 = 16 * w + lg * 4;
  float ziv[4];
#pragma unroll
  for (int i = 0; i < 4; ++i) ziv[i] = zinv[(size_t)bh * S + r0 + rloc0 + i];

  // Phase A: diag scores -> Nb (strict lower exp*zi, else 0)
  {
    f32x4 acc[4];
#pragma unroll
    for (int i = 0; i < 4; ++i) acc[i] = (f32x4)0.f;
    const size_t kbase = ((size_t)bh * S + r0) << 6;
#pragma unroll
    for (int ks = 0; ks < 2; ++ks) {
#pragma unroll
      for (int ni = 0; ni < 4; ++ni) {
        const size_t kb = kbase + (((size_t)(16 * ni + lr)) << 6) + ks * 32 + lg * 8;
        const bf16x8 bhf = *(const bf16x8*)(Khi + kb);
        const bf16x8 blf = *(const bf16x8*)(Klo + kb);
        acc[ni] = __builtin_amdgcn_mfma_f32_16x16x32_bf16(qfh[ks], bhf, acc[ni], 0, 0, 0);
        acc[ni] = __builtin_amdgcn_mfma_f32_16x16x32_bf16(qfl[ks], bhf, acc[ni], 0, 0, 0);
        acc[ni] = __builtin_amdgcn_mfma_f32_16x16x32_bf16(qfh[ks], blf, acc[ni], 0, 0, 0);
      }
    }
#pragma unroll
    for (int ni = 0; ni < 4; ++ni) {
      const int c = 16 * ni + lr;
#pragma unroll
      for (int i = 0; i < 4; ++i) {
        const int r = rloc0 + i;
        Nb[r][c] = (c < r) ? __expf(acc[ni][i]) * ziv[i] : 0.f;
      }
    }
  }
  // P10 for odd blocks: rows = this block, cols = previous 64-block (all causal)
  if (ib & 1) {
    f32x4 p[4];
#pragma unroll
    for (int i = 0; i < 4; ++i) p[i] = (f32x4)0.f;
    const size_t kbase = ((size_t)bh * S + r0 - 64) << 6;
#pragma unroll
    for (int ks = 0; ks < 2; ++ks) {
#pragma unroll
      for (int ni = 0; ni < 4; ++ni) {
        const size_t kb = kbase + (((size_t)(16 * ni + lr)) << 6) + ks * 32 + lg * 8;
        const bf16x8 bhf = *(const bf16x8*)(Khi + kb);
        const bf16x8 blf = *(const bf16x8*)(Klo + kb);
        p[ni] = __builtin_amdgcn_mfma_f32_16x16x32_bf16(qfh[ks], bhf, p[ni], 0, 0, 0);
        p[ni] = __builtin_amdgcn_mfma_f32_16x16x32_bf16(qfl[ks], bhf, p[ni], 0, 0, 0);
        p[ni] = __builtin_amdgcn_mfma_f32_16x16x32_bf16(qfh[ks], blf, p[ni], 0, 0, 0);
      }
    }
    const size_t pbase = (((size_t)bh * 16 + (ib >> 1)) * 64) * 64;
#pragma unroll
    for (int ni = 0; ni < 4; ++ni) {
      const int c = 16 * ni + lr;
#pragma unroll
      for (int i = 0; i < 4; ++i) {
        const float val = __expf(p[ni][i]) * ziv[i];
        const unsigned short h = bf_rne(val);
        P10h[pbase + (size_t)(rloc0 + i) * 64 + c] = (short)h;
        P10l[pbase + (size_t)(rloc0 + i) * 64 + c] = (short)bf_rne(val - bf2f((short)h));
      }
    }
  }
  // Phase B: X = I
  {
    const int c = t & 63, g = t >> 6;
#pragma unroll
    for (int i = 0; i < 16; ++i) {
      const int r = 16 * g + i;
      X[r][c] = (r == c) ? 1.f : 0.f;
    }
  }
  __syncthreads();

  // Phase C: panel-blocked forward substitution, X = (I - N)^-1
  const int c = t & 63, g = t >> 6;
  if (w == 0) {
    for (int rr = 1; rr < 16; ++rr) {
      float a = 0.f;
      for (int j = 0; j < rr; ++j) a += Nb[rr][j] * X[j][l];
      X[rr][l] += a;
    }
  }
  __syncthreads();
#pragma unroll
  for (int I = 1; I < 4; ++I) {
    {
      const int rb4 = 16 * I + 4 * g;
      float s0 = 0.f, s1 = 0.f, s2 = 0.f, s3 = 0.f;
      for (int j = 0; j < 16 * I; j += 4) {
        const float4 n0 = *(const float4*)&Nb[rb4 + 0][j];
        const float4 n1 = *(const float4*)&Nb[rb4 + 1][j];
        const float4 n2 = *(const float4*)&Nb[rb4 + 2][j];
        const float4 n3 = *(const float4*)&Nb[rb4 + 3][j];
        const float x0 = X[j + 0][c], x1 = X[j + 1][c];
        const float x2 = X[j + 2][c], x3 = X[j + 3][c];
        s0 += n0.x * x0 + n0.y * x1 + n0.z * x2 + n0.w * x3;
        s1 += n1.x * x0 + n1.y * x1 + n1.z * x2 + n1.w * x3;
        s2 += n2.x * x0 + n2.y * x1 + n2.z * x2 + n2.w * x3;
        s3 += n3.x * x0 + n3.y * x1 + n3.z * x2 + n3.w * x3;
      }
      X[rb4 + 0][c] += s0; X[rb4 + 1][c] += s1;
      X[rb4 + 2][c] += s2; X[rb4 + 3][c] += s3;
    }
    __syncthreads();
    if (w == 0) {
      const int rb = 16 * I;
      for (int rr = 1; rr < 16; ++rr) {
        const int r = rb + rr;
        float a = 0.f;
        for (int j = rb; j < r; ++j) a += Nb[r][j] * X[j][l];
        X[r][l] += a;
      }
    }
    __syncthreads();
  }

  // Phase D: write Minv64 row-major split-bf16
  const size_t mb = (((size_t)bh * 32 + ib) * 64) * 64;
  for (int v = t; v < 4096; v += 256) {
    const int r = v >> 6, cc = v & 63;
    const float x = X[r][cc];
    const unsigned short h = bf_rne(x);
    Mrh[mb + v] = (short)h;
    Mrl[mb + v] = (short)bf_rne(x - bf2f((short)h));
  }
}

// ---------------------------------------------------------------------------
// Scan step k off-diagonal accumulate, FULL MFMA (unchanged from R6).
// ---------------------------------------------------------------------------
__global__ __launch_bounds__(256) void k5_acc(
    const short* __restrict__ Qhi, const short* __restrict__ Qlo,
    const short* __restrict__ Khi, const short* __restrict__ Klo,
    const float* __restrict__ Abuf, const float* __restrict__ zinv,
    float* __restrict__ upart, int kstep) {
  const int bh = blockIdx.y, j = blockIdx.x;
  __shared__ float Es[128][68];
  __shared__ float Ats[64][68];
  const int t = threadIdx.x;
  const int w = t >> 6, l = t & 63;
  const int lr = l & 15, lg = l >> 4;
  const int rw = 32 * w;
  const int base = kstep * 128;

  bf16x8 qfh[2][2], qfl[2][2];
#pragma unroll
  for (int mi = 0; mi < 2; ++mi)
#pragma unroll
    for (int ks = 0; ks < 2; ++ks) {
      const size_t qo = (((size_t)bh * S + base + rw + mi * 16 + lr) << 6) + ks * 32 + lg * 8;
      qfh[mi][ks] = *(const bf16x8*)(Qhi + qo);
      qfl[mi][ks] = *(const bf16x8*)(Qlo + qo);
    }
  float ziv[2][4];
#pragma unroll
  for (int mi = 0; mi < 2; ++mi)
#pragma unroll
    for (int r = 0; r < 4; ++r)
      ziv[mi][r] = zinv[(size_t)bh * S + base + rw + mi * 16 + lg * 4 + r];

  f32x4 out[2][4];
#pragma unroll
  for (int mi = 0; mi < 2; ++mi)
#pragma unroll
    for (int ni = 0; ni < 4; ++ni) out[mi][ni] = (f32x4)0.f;

  for (int h = 0; h < 2; ++h) {
    __syncthreads();
    for (int v = t; v < 1024; v += 256) {
      const int d = v & 63, sq = v >> 6;
      const size_t ab = ((size_t)bh * S + j * 128 + h * 64 + sq * 4) << 6;
      float4 o;
      o.x = Abuf[ab + d];
      o.y = Abuf[ab + 64 + d];
      o.z = Abuf[ab + 128 + d];
      o.w = Abuf[ab + 192 + d];
      *(float4*)&Ats[d][sq * 4] = o;
    }
    f32x4 qk[2][4];
#pragma unroll
    for (int mi = 0; mi < 2; ++mi)
#pragma unroll
      for (int ni = 0; ni < 4; ++ni) qk[mi][ni] = (f32x4)0.f;
#pragma unroll
    for (int ks = 0; ks < 2; ++ks) {
#pragma unroll
      for (int ni = 0; ni < 4; ++ni) {
        const size_t ko = (((size_t)bh * S + j * 128 + h * 64 + ni * 16 + lr) << 6) + ks * 32 + lg * 8;
        const bf16x8 kh8 = *(const bf16x8*)(Khi + ko);
        const bf16x8 kl8 = *(const bf16x8*)(Klo + ko);
#pragma unroll
        for (int mi = 0; mi < 2; ++mi) {
          qk[mi][ni] = __builtin_amdgcn_mfma_f32_16x16x32_bf16(
              qfh[mi][ks], kh8, qk[mi][ni], 0, 0, 0);
          qk[mi][ni] = __builtin_amdgcn_mfma_f32_16x16x32_bf16(
              qfl[mi][ks], kh8, qk[mi][ni], 0, 0, 0);
          qk[mi][ni] = __builtin_amdgcn_mfma_f32_16x16x32_bf16(
              qfh[mi][ks], kl8, qk[mi][ni], 0, 0, 0);
        }
      }
    }
#pragma unroll
    for (int mi = 0; mi < 2; ++mi)
#pragma unroll
      for (int ni = 0; ni < 4; ++ni)
#pragma unroll
        for (int r = 0; r < 4; ++r)
          Es[rw + mi * 16 + lg * 4 + r][ni * 16 + lr] =
              __expf(qk[mi][ni][r]) * ziv[mi][r];
    __syncthreads();
#pragma unroll
    for (int ks = 0; ks < 2; ++ks) {
      bf16x8 eh[2], el[2];
#pragma unroll
      for (int mi = 0; mi < 2; ++mi) {
        const float* ep = &Es[rw + mi * 16 + lr][ks * 32 + lg * 8];
        split8(*(const float4*)ep, *(const float4*)(ep + 4), eh[mi], el[mi]);
      }
#pragma unroll
      for (int ni = 0; ni < 4; ++ni) {
        const float* ap = &Ats[ni * 16 + lr][ks * 32 + lg * 8];
        bf16x8 ah8, al8;
        split8(*(const float4*)ap, *(const float4*)(ap + 4), ah8, al8);
#pragma unroll
        for (int mi = 0; mi < 2; ++mi) {
          out[mi][ni] = __builtin_amdgcn_mfma_f32_16x16x32_bf16(
              eh[mi], ah8, out[mi][ni], 0, 0, 0);
          out[mi][ni] = __builtin_amdgcn_mfma_f32_16x16x32_bf16(
              el[mi], ah8, out[mi][ni], 0, 0, 0);
          out[mi][ni] = __builtin_amdgcn_mfma_f32_16x16x32_bf16(
              eh[mi], al8, out[mi][ni], 0, 0, 0);
        }
      }
    }
  }
  float* ub = upart + (((size_t)bh * 15 + j) * 128) * 64;
#pragma unroll
  for (int mi = 0; mi < 2; ++mi)
#pragma unroll
    for (int ni = 0; ni < 4; ++ni)
#pragma unroll
      for (int r = 0; r < 4; ++r)
        ub[(size_t)(rw + mi * 16 + lg * 4 + r) * 64 + ni * 16 + lr] =
            out[mi][ni][r];
}

// ---------------------------------------------------------------------------
// Scan step k finalize, MFMA (grid 4 x BH, d-quads of 16):
//   uT = pd*v + sum(upart)  (transposed in LDS);
//   A_lo = Minv64(2k) @ u_lo;  u_hi += P10 @ A_lo;  A_hi = Minv64(2k+1) @ u_hi.
// Minv64 / P10 fragments read from global split-bf16; u/A split on the fly.
// ---------------------------------------------------------------------------
__global__ __launch_bounds__(256) void k5_fin(
    const float* __restrict__ V, const float* __restrict__ pd,
    const float* __restrict__ upart, const short* __restrict__ Mrh,
    const short* __restrict__ Mrl, const short* __restrict__ P10h,
    const short* __restrict__ P10l, float* __restrict__ Abuf, int kstep) {
  const int d0 = blockIdx.x * 16;
  const int bh = blockIdx.y;
  const int t = threadIdx.x;
  const int w = t >> 6, l = t & 63;
  const int lr = l & 15, lg = l >> 4;
  const int base = kstep * 128;
  __shared__ float uT[16][132];     // [dd][r], r = 0..127
  __shared__ float aT[16][68];      // A_lo transposed [dd][r]

  // phase 0: uT[dd][r] = pd*v + sum of partials (this d-quad)
  for (int v = t; v < 512; v += 256) {
    const int r = v >> 2, f = v & 3;
    const int R = base + r;
    const float4 x = *(const float4*)(V + (((size_t)bh * S + R) << 6) + d0 + f * 4);
    const float p = pd[(size_t)bh * S + R];
    float a0 = p * x.x, a1 = p * x.y, a2 = p * x.z, a3 = p * x.w;
    for (int j = 0; j < kstep; ++j) {
      const float4 y = *(const float4*)(
          upart + ((((size_t)bh * 15 + j) * 128 + r) << 6) + d0 + f * 4);
      a0 += y.x; a1 += y.y; a2 += y.z; a3 += y.w;
    }
    uT[f * 4 + 0][r] = a0; uT[f * 4 + 1][r] = a1;
    uT[f * 4 + 2][r] = a2; uT[f * 4 + 3][r] = a3;
  }
  __syncthreads();
  // phase 1: A_lo = Minv64(2k) @ u_lo  (rows 16w.., cols d0+lr)
  {
    f32x4 o = (f32x4)0.f;
    const size_t mb = (((size_t)bh * 32 + kstep * 2) * 64 + 16 * w + lr) * 64;
#pragma unroll
    for (int ks = 0; ks < 2; ++ks) {
      const bf16x8 mh = *(const bf16x8*)(Mrh + mb + ks * 32 + lg * 8);
      const bf16x8 ml = *(const bf16x8*)(Mrl + mb + ks * 32 + lg * 8);
      const float* up_ = &uT[lr][ks * 32 + lg * 8];
      bf16x8 uh, ul;
      split8(*(const float4*)up_, *(const float4*)(up_ + 4), uh, ul);
      o = __builtin_amdgcn_mfma_f32_16x16x32_bf16(mh, uh, o, 0, 0, 0);
      o = __builtin_amdgcn_mfma_f32_16x16x32_bf16(ml, uh, o, 0, 0, 0);
      o = __builtin_amdgcn_mfma_f32_16x16x32_bf16(mh, ul, o, 0, 0, 0);
    }
#pragma unroll
    for (int i = 0; i < 4; ++i) {
      const int r = 16 * w + lg * 4 + i;
      Abuf[(((size_t)bh * S + base + r) << 6) + d0 + lr] = o[i];
      aT[lr][r] = o[i];
    }
  }
  __syncthreads();
  // phase 2: u_hi += P10 @ A_lo
  {
    f32x4 o = (f32x4)0.f;
    const size_t pb = (((size_t)bh * 16 + kstep) * 64 + 16 * w + lr) * 64;
#pragma unroll
    for (int ks = 0; ks < 2; ++ks) {
      const bf16x8 ph = *(const bf16x8*)(P10h + pb + ks * 32 + lg * 8);
      const bf16x8 pl = *(const bf16x8*)(P10l + pb + ks * 32 + lg * 8);
      const float* ap = &aT[lr][ks * 32 + lg * 8];
      bf16x8 ah, al;
      split8(*(const float4*)ap, *(const float4*)(ap + 4), ah, al);
      o = __builtin_amdgcn_mfma_f32_16x16x32_bf16(ph, ah, o, 0, 0, 0);
      o = __builtin_amdgcn_mfma_f32_16x16x32_bf16(pl, ah, o, 0, 0, 0);
      o = __builtin_amdgcn_mfma_f32_16x16x32_bf16(ph, al, o, 0, 0, 0);
    }
#pragma unroll
    for (int i = 0; i < 4; ++i)
      uT[lr][64 + 16 * w + lg * 4 + i] += o[i];
  }
  __syncthreads();
  // phase 3: A_hi = Minv64(2k+1) @ u_hi
  {
    f32x4 o = (f32x4)0.f;
    const size_t mb = (((size_t)bh * 32 + kstep * 2 + 1) * 64 + 16 * w + lr) * 64;
#pragma unroll
    for (int ks = 0; ks < 2; ++ks) {
      const bf16x8 mh = *(const bf16x8*)(Mrh + mb + ks * 32 + lg * 8);
      const bf16x8 ml = *(const bf16x8*)(Mrl + mb + ks * 32 + lg * 8);
      const float* up_ = &uT[lr][64 + ks * 32 + lg * 8];
      bf16x8 uh, ul;
      split8(*(const float4*)up_, *(const float4*)(up_ + 4), uh, ul);
      o = __builtin_amdgcn_mfma_f32_16x16x32_bf16(mh, uh, o, 0, 0, 0);
      o = __builtin_amdgcn_mfma_f32_16x16x32_bf16(ml, uh, o, 0, 0, 0);
      o = __builtin_amdgcn_mfma_f32_16x16x32_bf16(mh, ul, o, 0, 0, 0);
    }
#pragma unroll
    for (int i = 0; i < 4; ++i) {
      const int r = 16 * w + lg * 4 + i;
      Abuf[(((size_t)bh * S + base + 64 + r) << 6) + d0 + lr] = o[i];
    }
  }
}

} // namespace

extern "C" void kernel_launch(void* const* d_in, const int* in_sizes, int n_in,
                              void* d_out, int out_size, void* d_ws, size_t ws_size,
                              hipStream_t stream) {
  const float* hs   = (const float*)d_in[0];
  const float* Wqkv = (const float*)d_in[1];
  const float* bqkv = (const float*)d_in[2];
  const float* Wd   = (const float*)d_in[3];
  const float* bd   = (const float*)d_in[4];
  float* out = (float*)d_out;
  float* W   = (float*)d_ws;
  if (ws_size < WS_FLOATS * sizeof(float)) return;  // insufficient scratch

  float* qkv   = W + OFF_QKV;
  float* partZ = W + OFF_PART;
  float* Abuf  = W + OFF_A;
  short* Qhi   = (short*)(W + OFF_Q);
  short* Qlo   = Qhi + 4194304;
  short* Khi   = (short*)(W + OFF_K);
  short* Klo   = Khi + 4194304;
  float* Vb    = W + OFF_V;
  float* zi    = W + OFF_ZI;
  float* pdg   = W + OFF_PD;
  float* up    = W + OFF_UP;

  char* wsb = (char*)d_ws;
  // bf16 split scratch in regions dead at time of use
  short* Ahi  = (short*)(wsb + 50331648);      // pre-rope: Q region
  short* Alo  = Ahi + 4194304;
  short* Whi  = (short*)(wsb + 67108864);      // pre-rope: K region
  short* Wlo  = Whi + 3145728;
  short* A2hi = (short*)(wsb + 50331648);      // post-scan: Q region
  short* A2lo = A2hi + 4194304;
  short* Wdhi = (short*)(wsb + 67108864);
  short* Wdlo = Wdhi + 1048576;
  // scan-phase operands (dead zones during scan)
  short* P10h = (short*)(wsb);                 // 0..4.2MB (partZ/qkv dead)
  short* P10l = P10h + 2097152;                // 4.2..8.4MB
  short* Mrh  = (short*)(wsb + 33554432);      // 33.5..41.9MB
  short* Mrl  = Mrh + 4194304;                 // 41.9..50.3MB

  split2<<<dim3(2048), 256, 0, stream>>>(hs, Ahi, Alo, B*S*HID/4);
  split2<<<dim3(2048), 256, 0, stream>>>(Wqkv, Whi, Wlo, 3*HID*HID/4);
  gemm_bf3<<<dim3(24, 32), 256, 0, stream>>>(Ahi, Alo, Whi, Wlo, bqkv, qkv,
                                             B*S, 3*HID, HID);
  k2_rope<<<dim3(BH * S / 256), 256, 0, stream>>>(qkv, Qhi, Qlo, Khi, Klo, Vb);
  k3_scores<<<dim3(16, 16, BH), 256, 0, stream>>>(Qhi, Qlo, Khi, Klo, partZ, pdg);
  k3_reduce<<<dim3(BH * S / 256), 256, 0, stream>>>(partZ, zi, pdg);
  k4_minv<<<dim3(S / 64, BH), 256, 0, stream>>>(Qhi, Qlo, Khi, Klo, zi,
                                                Mrh, Mrl, P10h, P10l);
  for (int k = 0; k < NSTEP; ++k) {
    if (k > 0)
      k5_acc<<<dim3(k, BH), 256, 0, stream>>>(Qhi, Qlo, Khi, Klo, Abuf, zi, up, k);
    k5_fin<<<dim3(4, BH), 256, 0, stream>>>(Vb, pdg, up, Mrh, Mrl, P10h, P10l,
                                            Abuf, k);
  }
  split_gather<<<dim3(2048), 256, 0, stream>>>(Abuf, A2hi, A2lo);
  split2<<<dim3(2048), 256, 0, stream>>>(Wd, Wdhi, Wdlo, HID*HID/4);
  gemm_bf3<<<dim3(8, 32), 256, 0, stream>>>(A2hi, A2lo, Wdhi, Wdlo, bd, out,
                                            B*S, HID, HID);
}

// Round 10
// 692.505 us; speedup vs baseline: 4.8414x; 1.0671x over previous
//
#include <hip/hip_runtime.h>
#include <math.h>

namespace {

constexpr int B  = 2, S = 2048, NH = 16, HD = 64, HID = 1024;
constexpr int BH = B * NH;          // 32
constexpr int NSTEP2 = 8;           // 256-row scan steps

// ws layout in floats.
constexpr size_t OFF_A    = 4194304;           // [BH][S][HD] fp32 (bytes 16.8..33.5MB)
constexpr size_t OFF_Q    = 12582912;          // Qhi/Qlo bf16 pairs
constexpr size_t OFF_K    = 16777216;          // Khi/Klo bf16 pairs
constexpr size_t OFF_V    = 20971520;          // fp32 V
constexpr size_t OFF_ZI   = 25231360;          // [BH*S]
constexpr size_t OFF_PD   = 25296896;          // [BH*S]
constexpr size_t OFF_UP   = 25362432;          // [BH][7][2][128][64] = 3.67M floats
constexpr size_t WS_FLOATS = 29294592;         // ~117 MB

typedef __attribute__((ext_vector_type(8))) short bf16x8;
typedef __attribute__((ext_vector_type(4))) float f32x4;

__device__ inline unsigned short bf_rne(float x) {
  const unsigned u = __float_as_uint(x);
  return (unsigned short)((u + 0x7FFFu + ((u >> 16) & 1u)) >> 16);
}
__device__ inline float bf2f(short h) {
  return __uint_as_float((unsigned)(unsigned short)h << 16);
}
// split 8 fp32 (two float4) into hi/lo bf16x8 fragments
__device__ inline void split8(const float4 a, const float4 b,
                              bf16x8& hi, bf16x8& lo) {
  float v[8] = {a.x, a.y, a.z, a.w, b.x, b.y, b.z, b.w};
#pragma unroll
  for (int i = 0; i < 8; ++i) {
    const unsigned short h = bf_rne(v[i]);
    hi[i] = (short)h;
    lo[i] = (short)bf_rne(v[i] - bf2f((short)h));
  }
}
// 3-chain split-bf16 64-apply: A-operand rows from global hi/lo (already
// offset to this lane's row*64), B-operand 64-vector slice from LDS row ptr.
__device__ inline f32x4 apply3(const short* __restrict__ mh_,
                               const short* __restrict__ ml_,
                               const float* __restrict__ brow, int lg) {
  f32x4 o = (f32x4)0.f;
#pragma unroll
  for (int ks = 0; ks < 2; ++ks) {
    const bf16x8 mh = *(const bf16x8*)(mh_ + ks * 32 + lg * 8);
    const bf16x8 ml = *(const bf16x8*)(ml_ + ks * 32 + lg * 8);
    const float* bp = brow + ks * 32 + lg * 8;
    bf16x8 bh, bl;
    split8(*(const float4*)bp, *(const float4*)(bp + 4), bh, bl);
    o = __builtin_amdgcn_mfma_f32_16x16x32_bf16(mh, bh, o, 0, 0, 0);
    o = __builtin_amdgcn_mfma_f32_16x16x32_bf16(ml, bh, o, 0, 0, 0);
    o = __builtin_amdgcn_mfma_f32_16x16x32_bf16(mh, bl, o, 0, 0, 0);
  }
  return o;
}

// ---------------------------------------------------------------------------
// Fused pre-GEMM splits: hs -> Ahi/Alo, Wqkv -> Whi/Wlo.
// ---------------------------------------------------------------------------
__global__ __launch_bounds__(256) void split_pre(
    const float* __restrict__ hs, short* __restrict__ h1, short* __restrict__ l1,
    const float* __restrict__ wq, short* __restrict__ h2, short* __restrict__ l2) {
  const int n1 = B * S * HID / 4;          // 1048576
  const int n2 = 3 * HID * HID / 4;        // 786432
  for (int g = blockIdx.x * 256 + threadIdx.x; g < n1 + n2; g += gridDim.x * 256) {
    const bool first = g < n1;
    const int idx = first ? g : g - n1;
    const float4 x = first ? *(const float4*)(hs + (size_t)idx * 4)
                           : *(const float4*)(wq + (size_t)idx * 4);
    short4 h, l;
    h.x = bf_rne(x.x); h.y = bf_rne(x.y); h.z = bf_rne(x.z); h.w = bf_rne(x.w);
    l.x = bf_rne(x.x - bf2f(h.x));
    l.y = bf_rne(x.y - bf2f(h.y));
    l.z = bf_rne(x.z - bf2f(h.z));
    l.w = bf_rne(x.w - bf2f(h.w));
    if (first) {
      *(short4*)(h1 + (size_t)idx * 4) = h;
      *(short4*)(l1 + (size_t)idx * 4) = l;
    } else {
      *(short4*)(h2 + (size_t)idx * 4) = h;
      *(short4*)(l2 + (size_t)idx * 4) = l;
    }
  }
}

// ---------------------------------------------------------------------------
// Fused post-scan splits: Abuf (gathered) -> A2hi/A2lo, Wd -> Wdhi/Wdlo.
// ---------------------------------------------------------------------------
__global__ __launch_bounds__(256) void split_post(
    const float* __restrict__ Abuf, short* __restrict__ h1, short* __restrict__ l1,
    const float* __restrict__ wd, short* __restrict__ h2, short* __restrict__ l2) {
  const int n1 = B * S * HID / 4;          // 1048576 (gather range)
  const int n2 = HID * HID / 4;            // 262144
  for (int g = blockIdx.x * 256 + threadIdx.x; g < n1 + n2; g += gridDim.x * 256) {
    float4 x;
    if (g < n1) {
      const int m = g >> 8, q = g & 255;
      const int k0 = q * 4;
      const int b = m >> 11, s = m & (S - 1);
      const int h = k0 >> 6, d = k0 & 63;
      x = *(const float4*)(Abuf + (((size_t)(b * NH + h) * S + s) << 6) + d);
    } else {
      x = *(const float4*)(wd + (size_t)(g - n1) * 4);
    }
    short4 h, l;
    h.x = bf_rne(x.x); h.y = bf_rne(x.y); h.z = bf_rne(x.z); h.w = bf_rne(x.w);
    l.x = bf_rne(x.x - bf2f(h.x));
    l.y = bf_rne(x.y - bf2f(h.y));
    l.z = bf_rne(x.z - bf2f(h.z));
    l.w = bf_rne(x.w - bf2f(h.w));
    if (g < n1) {
      *(short4*)(h1 + (size_t)g * 4) = h;
      *(short4*)(l1 + (size_t)g * 4) = l;
    } else {
      *(short4*)(h2 + (size_t)(g - n1) * 4) = h;
      *(short4*)(l2 + (size_t)(g - n1) * 4) = l;
    }
  }
}

// ---------------------------------------------------------------------------
// Split-bf16 MFMA NT GEMM: C = A @ B^T + bias (fp32 via 3 bf16 chains).
// ---------------------------------------------------------------------------
__global__ __launch_bounds__(256) void gemm_bf3(
    const short* __restrict__ Ahi, const short* __restrict__ Alo,
    const short* __restrict__ Bhi, const short* __restrict__ Blo,
    const float* __restrict__ bias, float* __restrict__ C,
    int M, int N, int K) {
  __shared__ short ash[128][40], als[128][40], bsh[128][40], bls[128][40];
  const int t = threadIdx.x;
  const int m0 = blockIdx.y * 128, n0 = blockIdx.x * 128;
  const int w = t >> 6, l = t & 63;
  const int wm = (w >> 1) * 64, wn = (w & 1) * 64;
  const int lr = l & 15, lk = (l >> 4) * 8;
  f32x4 acc[4][4];
#pragma unroll
  for (int i = 0; i < 4; ++i)
#pragma unroll
    for (int j = 0; j < 4; ++j) acc[i][j] = (f32x4)0.f;

  for (int kb = 0; kb < K; kb += 32) {
    __syncthreads();
#pragma unroll
    for (int i = 0; i < 2; ++i) {
      const int idx = t + i * 256;
      const int row = idx >> 2, c8 = (idx & 3) * 8;
      *(uint4*)&ash[row][c8] = *(const uint4*)(Ahi + (size_t)(m0 + row) * K + kb + c8);
      *(uint4*)&als[row][c8] = *(const uint4*)(Alo + (size_t)(m0 + row) * K + kb + c8);
      *(uint4*)&bsh[row][c8] = *(const uint4*)(Bhi + (size_t)(n0 + row) * K + kb + c8);
      *(uint4*)&bls[row][c8] = *(const uint4*)(Blo + (size_t)(n0 + row) * K + kb + c8);
    }
    __syncthreads();
    bf16x8 ah[4], al[4], bh[4], bl[4];
#pragma unroll
    for (int mi = 0; mi < 4; ++mi) {
      ah[mi] = *(const bf16x8*)&ash[wm + mi * 16 + lr][lk];
      al[mi] = *(const bf16x8*)&als[wm + mi * 16 + lr][lk];
    }
#pragma unroll
    for (int ni = 0; ni < 4; ++ni) {
      bh[ni] = *(const bf16x8*)&bsh[wn + ni * 16 + lr][lk];
      bl[ni] = *(const bf16x8*)&bls[wn + ni * 16 + lr][lk];
    }
#pragma unroll
    for (int mi = 0; mi < 4; ++mi)
#pragma unroll
      for (int ni = 0; ni < 4; ++ni) {
        acc[mi][ni] = __builtin_amdgcn_mfma_f32_16x16x32_bf16(
            ah[mi], bh[ni], acc[mi][ni], 0, 0, 0);
        acc[mi][ni] = __builtin_amdgcn_mfma_f32_16x16x32_bf16(
            al[mi], bh[ni], acc[mi][ni], 0, 0, 0);
        acc[mi][ni] = __builtin_amdgcn_mfma_f32_16x16x32_bf16(
            ah[mi], bl[ni], acc[mi][ni], 0, 0, 0);
      }
  }
  const int rq = (l >> 4) * 4;
#pragma unroll
  for (int ni = 0; ni < 4; ++ni) {
    const int col = n0 + wn + ni * 16 + lr;
    const float bv = bias[col];
#pragma unroll
    for (int mi = 0; mi < 4; ++mi)
#pragma unroll
      for (int r = 0; r < 4; ++r) {
        const int row = m0 + wm + mi * 16 + rq + r;
        C[(size_t)row * N + col] = acc[mi][ni][r] + bv;
      }
  }
}

// ---------------------------------------------------------------------------
// RoPE + transpose -> Qhi/Qlo, Khi/Klo (bf16 split, [bh][s][d]) + fp32 V.
// ---------------------------------------------------------------------------
__global__ __launch_bounds__(256) void k2_rope(
    const float* __restrict__ qkv, short* __restrict__ Qhi,
    short* __restrict__ Qlo, short* __restrict__ Khi,
    short* __restrict__ Klo, float* __restrict__ V) {
  const int g  = blockIdx.x * 256 + threadIdx.x;   // (bh, s)
  const int s  = g & (S - 1);
  const int bh = g >> 11;
  const int b  = bh >> 4, h = bh & 15;
  const float* base = qkv + ((size_t)b * S + s) * 3072 + h * 64;
  float q[64], k[64], v[64];
#pragma unroll
  for (int f = 0; f < 16; ++f) {
    const float4 x = *(const float4*)(base + f * 4);
    q[f*4+0]=x.x; q[f*4+1]=x.y; q[f*4+2]=x.z; q[f*4+3]=x.w;
    const float4 y = *(const float4*)(base + 1024 + f * 4);
    k[f*4+0]=y.x; k[f*4+1]=y.y; k[f*4+2]=y.z; k[f*4+3]=y.w;
    const float4 z = *(const float4*)(base + 2048 + f * 4);
    v[f*4+0]=z.x; v[f*4+1]=z.y; v[f*4+2]=z.z; v[f*4+3]=z.w;
  }
  const float PW[8] = {1.0f, 3.1622776601683795f, 10.0f, 31.622776601683793f,
                       100.0f, 316.22776601683796f, 1000.0f, 3162.2776601683795f};
  float qr[16], kr[16];
#pragma unroll
  for (int d = 0; d < 16; ++d) {
    const int j = d & 7;
    const float invf = 1.0f / PW[j];
    const float fr = (float)s * invf;
    float sn, c;
    sincosf(fr, &sn, &c);
    const float rq = (d < 8) ? -q[d + 8] : q[d - 8];
    const float rk = (d < 8) ? -k[d + 8] : k[d - 8];
    qr[d] = q[d] * c + rq * sn;
    kr[d] = k[d] * c + rk * sn;
  }
#pragma unroll
  for (int d = 0; d < 16; ++d) { q[d] = qr[d]; k[d] = kr[d]; }
#pragma unroll
  for (int d = 0; d < 64; ++d) q[d] *= 0.125f;   // fold softmax scale into Q
  const size_t o = ((size_t)bh * S + s) << 6;
  float* vd = V + o;
#pragma unroll
  for (int f = 0; f < 16; ++f) {
    short4 qh, ql, kh, kl;
    const float* qq = q + f * 4;
    const float* kk = k + f * 4;
    qh.x = bf_rne(qq[0]); qh.y = bf_rne(qq[1]); qh.z = bf_rne(qq[2]); qh.w = bf_rne(qq[3]);
    ql.x = bf_rne(qq[0]-bf2f(qh.x)); ql.y = bf_rne(qq[1]-bf2f(qh.y));
    ql.z = bf_rne(qq[2]-bf2f(qh.z)); ql.w = bf_rne(qq[3]-bf2f(qh.w));
    kh.x = bf_rne(kk[0]); kh.y = bf_rne(kk[1]); kh.z = bf_rne(kk[2]); kh.w = bf_rne(kk[3]);
    kl.x = bf_rne(kk[0]-bf2f(kh.x)); kl.y = bf_rne(kk[1]-bf2f(kh.y));
    kl.z = bf_rne(kk[2]-bf2f(kh.z)); kl.w = bf_rne(kk[3]-bf2f(kh.w));
    *(short4*)(Qhi + o + f*4) = qh;
    *(short4*)(Qlo + o + f*4) = ql;
    *(short4*)(Khi + o + f*4) = kh;
    *(short4*)(Klo + o + f*4) = kl;
    *(float4*)(vd + f*4) = make_float4(v[f*4], v[f*4+1], v[f*4+2], v[f*4+3]);
  }
}

// ---------------------------------------------------------------------------
// MFMA score pass: per 128x128 causal block, rowsum(exp(QK^T)) -> partZ,
// raw diag score -> sdg.
// ---------------------------------------------------------------------------
__global__ __launch_bounds__(256) void k3_scores(
    const short* __restrict__ Qhi, const short* __restrict__ Qlo,
    const short* __restrict__ Khi, const short* __restrict__ Klo,
    float* __restrict__ partZ, float* __restrict__ sdg) {
  const int cb = blockIdx.x, rb = blockIdx.y, bh = blockIdx.z;
  if (cb > rb) return;
  __shared__ short qh[128][72], ql[128][72], kh[128][72], kl[128][72];
  __shared__ float red[128][2];
  const int t = threadIdx.x;
  const int w = t >> 6, l = t & 63;
  const int wm = (w >> 1) * 64, wn = (w & 1) * 64;
  const int lr = l & 15, lg = l >> 4;
  for (int v = t; v < 1024; v += 256) {
    const int r = v >> 3, c8 = (v & 7) * 8;
    const size_t gq = (((size_t)bh * S + rb * 128 + r) << 6) + c8;
    const size_t gk = (((size_t)bh * S + cb * 128 + r) << 6) + c8;
    *(uint4*)&qh[r][c8] = *(const uint4*)(Qhi + gq);
    *(uint4*)&ql[r][c8] = *(const uint4*)(Qlo + gq);
    *(uint4*)&kh[r][c8] = *(const uint4*)(Khi + gk);
    *(uint4*)&kl[r][c8] = *(const uint4*)(Klo + gk);
  }
  __syncthreads();
  f32x4 acc[4][4];
#pragma unroll
  for (int i = 0; i < 4; ++i)
#pragma unroll
    for (int j = 0; j < 4; ++j) acc[i][j] = (f32x4)0.f;
#pragma unroll
  for (int ks = 0; ks < 2; ++ks) {
    const int lk = ks * 32 + lg * 8;
    bf16x8 ah[4], al[4], bhf[4], blf[4];
#pragma unroll
    for (int mi = 0; mi < 4; ++mi) {
      ah[mi] = *(const bf16x8*)&qh[wm + mi * 16 + lr][lk];
      al[mi] = *(const bf16x8*)&ql[wm + mi * 16 + lr][lk];
    }
#pragma unroll
    for (int ni = 0; ni < 4; ++ni) {
      bhf[ni] = *(const bf16x8*)&kh[wn + ni * 16 + lr][lk];
      blf[ni] = *(const bf16x8*)&kl[wn + ni * 16 + lr][lk];
    }
#pragma unroll
    for (int mi = 0; mi < 4; ++mi)
#pragma unroll
      for (int ni = 0; ni < 4; ++ni) {
        acc[mi][ni] = __builtin_amdgcn_mfma_f32_16x16x32_bf16(
            ah[mi], bhf[ni], acc[mi][ni], 0, 0, 0);
        acc[mi][ni] = __builtin_amdgcn_mfma_f32_16x16x32_bf16(
            al[mi], bhf[ni], acc[mi][ni], 0, 0, 0);
        acc[mi][ni] = __builtin_amdgcn_mfma_f32_16x16x32_bf16(
            ah[mi], blf[ni], acc[mi][ni], 0, 0, 0);
      }
  }
  const int rq = lg * 4;
  const int rowbase = rb * 128 + wm, colbase = cb * 128 + wn;
  float rp[4][4];
#pragma unroll
  for (int mi = 0; mi < 4; ++mi)
#pragma unroll
    for (int r = 0; r < 4; ++r) rp[mi][r] = 0.f;
#pragma unroll
  for (int mi = 0; mi < 4; ++mi)
#pragma unroll
    for (int ni = 0; ni < 4; ++ni)
#pragma unroll
      for (int r = 0; r < 4; ++r) {
        const int rG = rowbase + mi * 16 + rq + r;
        const int cG = colbase + ni * 16 + lr;
        if (cG <= rG) rp[mi][r] += __expf(acc[mi][ni][r]);
        if (cG == rG) sdg[(size_t)bh * S + rG] = acc[mi][ni][r];
      }
#pragma unroll
  for (int off = 1; off < 16; off <<= 1)
#pragma unroll
    for (int mi = 0; mi < 4; ++mi)
#pragma unroll
      for (int r = 0; r < 4; ++r)
        rp[mi][r] += __shfl_xor(rp[mi][r], off, 64);
  if (lr == 0)
#pragma unroll
    for (int mi = 0; mi < 4; ++mi)
#pragma unroll
      for (int r = 0; r < 4; ++r)
        red[wm + mi * 16 + rq + r][w & 1] = rp[mi][r];
  __syncthreads();
  if (t < 128)
    partZ[(((size_t)bh * 16 + rb) * 16 + cb) * 128 + t] = red[t][0] + red[t][1];
}

// ---------------------------------------------------------------------------
__global__ __launch_bounds__(256) void k3_reduce(
    const float* __restrict__ partZ, float* __restrict__ zinv,
    float* __restrict__ pdg) {
  const int R = blockIdx.x * 256 + threadIdx.x;
  const int bh = R >> 11, r = R & 2047;
  const int rb = r >> 7, row = r & 127;
  float Z = 0.f;
  for (int c = 0; c <= rb; ++c)
    Z += partZ[(((size_t)bh*16 + rb)*16 + c)*128 + row];
  const float zi = 1.f / Z;
  zinv[R] = zi;
  pdg[R] = __expf(pdg[R]) * zi;
}

// ---------------------------------------------------------------------------
// Per-64-block unit-lower-triangular inverse of (I - N), 256 threads.
// Emits Minv64 ROW-MAJOR split-bf16 (Mrh/Mrl).  For odd 64-blocks also emits
// the intra-128 coupling P10 = exp(S[odd rows, even cols])*zi, split-bf16.
// ---------------------------------------------------------------------------
__global__ __launch_bounds__(256) void k4_minv(
    const short* __restrict__ Qhi, const short* __restrict__ Qlo,
    const short* __restrict__ Khi, const short* __restrict__ Klo,
    const float* __restrict__ zinv, short* __restrict__ Mrh,
    short* __restrict__ Mrl, short* __restrict__ P10h,
    short* __restrict__ P10l) {
  const int bh = blockIdx.y, ib = blockIdx.x;
  const int r0 = ib * 64;
  __shared__ float Nb[64][68];
  __shared__ float X[64][68];
  const int t = threadIdx.x;
  const int w = t >> 6, l = t & 63;
  const int lr = l & 15, lg = l >> 4;

  bf16x8 qfh[2], qfl[2];
  const size_t qbase = (((size_t)bh * S + r0 + 16 * w + lr) << 6);
#pragma unroll
  for (int ks = 0; ks < 2; ++ks) {
    qfh[ks] = *(const bf16x8*)(Qhi + qbase + ks * 32 + lg * 8);
    qfl[ks] = *(const bf16x8*)(Qlo + qbase + ks * 32 + lg * 8);
  }
  const int rloc0 = 16 * w + lg * 4;
  float ziv[4];
#pragma unroll
  for (int i = 0; i < 4; ++i) ziv[i] = zinv[(size_t)bh * S + r0 + rloc0 + i];

  // Phase A: diag scores -> Nb (strict lower exp*zi, else 0)
  {
    f32x4 acc[4];
#pragma unroll
    for (int i = 0; i < 4; ++i) acc[i] = (f32x4)0.f;
    const size_t kbase = ((size_t)bh * S + r0) << 6;
#pragma unroll
    for (int ks = 0; ks < 2; ++ks) {
#pragma unroll
      for (int ni = 0; ni < 4; ++ni) {
        const size_t kb = kbase + (((size_t)(16 * ni + lr)) << 6) + ks * 32 + lg * 8;
        const bf16x8 bhf = *(const bf16x8*)(Khi + kb);
        const bf16x8 blf = *(const bf16x8*)(Klo + kb);
        acc[ni] = __builtin_amdgcn_mfma_f32_16x16x32_bf16(qfh[ks], bhf, acc[ni], 0, 0, 0);
        acc[ni] = __builtin_amdgcn_mfma_f32_16x16x32_bf16(qfl[ks], bhf, acc[ni], 0, 0, 0);
        acc[ni] = __builtin_amdgcn_mfma_f32_16x16x32_bf16(qfh[ks], blf, acc[ni], 0, 0, 0);
      }
    }
#pragma unroll
    for (int ni = 0; ni < 4; ++ni) {
      const int c = 16 * ni + lr;
#pragma unroll
      for (int i = 0; i < 4; ++i) {
        const int r = rloc0 + i;
        Nb[r][c] = (c < r) ? __expf(acc[ni][i]) * ziv[i] : 0.f;
      }
    }
  }
  // P10 for odd blocks: rows = this block, cols = previous 64-block
  if (ib & 1) {
    f32x4 p[4];
#pragma unroll
    for (int i = 0; i < 4; ++i) p[i] = (f32x4)0.f;
    const size_t kbase = ((size_t)bh * S + r0 - 64) << 6;
#pragma unroll
    for (int ks = 0; ks < 2; ++ks) {
#pragma unroll
      for (int ni = 0; ni < 4; ++ni) {
        const size_t kb = kbase + (((size_t)(16 * ni + lr)) << 6) + ks * 32 + lg * 8;
        const bf16x8 bhf = *(const bf16x8*)(Khi + kb);
        const bf16x8 blf = *(const bf16x8*)(Klo + kb);
        p[ni] = __builtin_amdgcn_mfma_f32_16x16x32_bf16(qfh[ks], bhf, p[ni], 0, 0, 0);
        p[ni] = __builtin_amdgcn_mfma_f32_16x16x32_bf16(qfl[ks], bhf, p[ni], 0, 0, 0);
        p[ni] = __builtin_amdgcn_mfma_f32_16x16x32_bf16(qfh[ks], blf, p[ni], 0, 0, 0);
      }
    }
    const size_t pbase = (((size_t)bh * 16 + (ib >> 1)) * 64) * 64;
#pragma unroll
    for (int ni = 0; ni < 4; ++ni) {
      const int c = 16 * ni + lr;
#pragma unroll
      for (int i = 0; i < 4; ++i) {
        const float val = __expf(p[ni][i]) * ziv[i];
        const unsigned short h = bf_rne(val);
        P10h[pbase + (size_t)(rloc0 + i) * 64 + c] = (short)h;
        P10l[pbase + (size_t)(rloc0 + i) * 64 + c] = (short)bf_rne(val - bf2f((short)h));
      }
    }
  }
  // Phase B: X = I
  {
    const int c = t & 63, g = t >> 6;
#pragma unroll
    for (int i = 0; i < 16; ++i) {
      const int r = 16 * g + i;
      X[r][c] = (r == c) ? 1.f : 0.f;
    }
  }
  __syncthreads();

  // Phase C: panel-blocked forward substitution, X = (I - N)^-1
  const int c = t & 63, g = t >> 6;
  if (w == 0) {
    for (int rr = 1; rr < 16; ++rr) {
      float a = 0.f;
      for (int j = 0; j < rr; ++j) a += Nb[rr][j] * X[j][l];
      X[rr][l] += a;
    }
  }
  __syncthreads();
#pragma unroll
  for (int I = 1; I < 4; ++I) {
    {
      const int rb4 = 16 * I + 4 * g;
      float s0 = 0.f, s1 = 0.f, s2 = 0.f, s3 = 0.f;
      for (int j = 0; j < 16 * I; j += 4) {
        const float4 n0 = *(const float4*)&Nb[rb4 + 0][j];
        const float4 n1 = *(const float4*)&Nb[rb4 + 1][j];
        const float4 n2 = *(const float4*)&Nb[rb4 + 2][j];
        const float4 n3 = *(const float4*)&Nb[rb4 + 3][j];
        const float x0 = X[j + 0][c], x1 = X[j + 1][c];
        const float x2 = X[j + 2][c], x3 = X[j + 3][c];
        s0 += n0.x * x0 + n0.y * x1 + n0.z * x2 + n0.w * x3;
        s1 += n1.x * x0 + n1.y * x1 + n1.z * x2 + n1.w * x3;
        s2 += n2.x * x0 + n2.y * x1 + n2.z * x2 + n2.w * x3;
        s3 += n3.x * x0 + n3.y * x1 + n3.z * x2 + n3.w * x3;
      }
      X[rb4 + 0][c] += s0; X[rb4 + 1][c] += s1;
      X[rb4 + 2][c] += s2; X[rb4 + 3][c] += s3;
    }
    __syncthreads();
    if (w == 0) {
      const int rb = 16 * I;
      for (int rr = 1; rr < 16; ++rr) {
        const int r = rb + rr;
        float a = 0.f;
        for (int j = rb; j < r; ++j) a += Nb[r][j] * X[j][l];
        X[r][l] += a;
      }
    }
    __syncthreads();
  }

  // Phase D: write Minv64 row-major split-bf16
  const size_t mb = (((size_t)bh * 32 + ib) * 64) * 64;
  for (int v = t; v < 4096; v += 256) {
    const int r = v >> 6, cc = v & 63;
    const float x = X[r][cc];
    const unsigned short h = bf_rne(x);
    Mrh[mb + v] = (short)h;
    Mrl[mb + v] = (short)bf_rne(x - bf2f((short)h));
  }
}

// ---------------------------------------------------------------------------
// Scan step s (256 rows) off-diagonal accumulate, FULL MFMA.
// Grid (g < min(2s,7), rh, bh).  WG owns rows s*256+rh*128..+128 and loops
// col-blocks j = g, g+7, ... (< 2s), accumulating into one up-slot.
// ---------------------------------------------------------------------------
__global__ __launch_bounds__(256) void k5_acc(
    const short* __restrict__ Qhi, const short* __restrict__ Qlo,
    const short* __restrict__ Khi, const short* __restrict__ Klo,
    const float* __restrict__ Abuf, const float* __restrict__ zinv,
    float* __restrict__ up, int s) {
  const int bh = blockIdx.z, rh = blockIdx.y, g = blockIdx.x;
  __shared__ float Es[128][68];
  __shared__ float Ats[64][68];
  const int t = threadIdx.x;
  const int w = t >> 6, l = t & 63;
  const int lr = l & 15, lg = l >> 4;
  const int rw = 32 * w;
  const int base = s * 256 + rh * 128;

  bf16x8 qfh[2][2], qfl[2][2];
#pragma unroll
  for (int mi = 0; mi < 2; ++mi)
#pragma unroll
    for (int ks = 0; ks < 2; ++ks) {
      const size_t qo = (((size_t)bh * S + base + rw + mi * 16 + lr) << 6) + ks * 32 + lg * 8;
      qfh[mi][ks] = *(const bf16x8*)(Qhi + qo);
      qfl[mi][ks] = *(const bf16x8*)(Qlo + qo);
    }
  float ziv[2][4];
#pragma unroll
  for (int mi = 0; mi < 2; ++mi)
#pragma unroll
    for (int r = 0; r < 4; ++r)
      ziv[mi][r] = zinv[(size_t)bh * S + base + rw + mi * 16 + lg * 4 + r];

  f32x4 out[2][4];
#pragma unroll
  for (int mi = 0; mi < 2; ++mi)
#pragma unroll
    for (int ni = 0; ni < 4; ++ni) out[mi][ni] = (f32x4)0.f;

  for (int j = g; j < 2 * s; j += 7) {
    for (int h = 0; h < 2; ++h) {
      __syncthreads();
      for (int v = t; v < 1024; v += 256) {
        const int d = v & 63, sq = v >> 6;
        const size_t ab = ((size_t)bh * S + j * 128 + h * 64 + sq * 4) << 6;
        float4 o;
        o.x = Abuf[ab + d];
        o.y = Abuf[ab + 64 + d];
        o.z = Abuf[ab + 128 + d];
        o.w = Abuf[ab + 192 + d];
        *(float4*)&Ats[d][sq * 4] = o;
      }
      f32x4 qk[2][4];
#pragma unroll
      for (int mi = 0; mi < 2; ++mi)
#pragma unroll
        for (int ni = 0; ni < 4; ++ni) qk[mi][ni] = (f32x4)0.f;
#pragma unroll
      for (int ks = 0; ks < 2; ++ks) {
#pragma unroll
        for (int ni = 0; ni < 4; ++ni) {
          const size_t ko = (((size_t)bh * S + j * 128 + h * 64 + ni * 16 + lr) << 6) + ks * 32 + lg * 8;
          const bf16x8 kh8 = *(const bf16x8*)(Khi + ko);
          const bf16x8 kl8 = *(const bf16x8*)(Klo + ko);
#pragma unroll
          for (int mi = 0; mi < 2; ++mi) {
            qk[mi][ni] = __builtin_amdgcn_mfma_f32_16x16x32_bf16(
                qfh[mi][ks], kh8, qk[mi][ni], 0, 0, 0);
            qk[mi][ni] = __builtin_amdgcn_mfma_f32_16x16x32_bf16(
                qfl[mi][ks], kh8, qk[mi][ni], 0, 0, 0);
            qk[mi][ni] = __builtin_amdgcn_mfma_f32_16x16x32_bf16(
                qfh[mi][ks], kl8, qk[mi][ni], 0, 0, 0);
          }
        }
      }
#pragma unroll
      for (int mi = 0; mi < 2; ++mi)
#pragma unroll
        for (int ni = 0; ni < 4; ++ni)
#pragma unroll
          for (int r = 0; r < 4; ++r)
            Es[rw + mi * 16 + lg * 4 + r][ni * 16 + lr] =
                __expf(qk[mi][ni][r]) * ziv[mi][r];
      __syncthreads();
#pragma unroll
      for (int ks = 0; ks < 2; ++ks) {
        bf16x8 eh[2], el[2];
#pragma unroll
        for (int mi = 0; mi < 2; ++mi) {
          const float* ep = &Es[rw + mi * 16 + lr][ks * 32 + lg * 8];
          split8(*(const float4*)ep, *(const float4*)(ep + 4), eh[mi], el[mi]);
        }
#pragma unroll
        for (int ni = 0; ni < 4; ++ni) {
          const float* ap = &Ats[ni * 16 + lr][ks * 32 + lg * 8];
          bf16x8 ah8, al8;
          split8(*(const float4*)ap, *(const float4*)(ap + 4), ah8, al8);
#pragma unroll
          for (int mi = 0; mi < 2; ++mi) {
            out[mi][ni] = __builtin_amdgcn_mfma_f32_16x16x32_bf16(
                eh[mi], ah8, out[mi][ni], 0, 0, 0);
            out[mi][ni] = __builtin_amdgcn_mfma_f32_16x16x32_bf16(
                el[mi], ah8, out[mi][ni], 0, 0, 0);
            out[mi][ni] = __builtin_amdgcn_mfma_f32_16x16x32_bf16(
                eh[mi], al8, out[mi][ni], 0, 0, 0);
          }
        }
      }
    }
  }
  float* ub = up + (((size_t)(bh * 7 + g) * 2 + rh) << 13);
#pragma unroll
  for (int mi = 0; mi < 2; ++mi)
#pragma unroll
    for (int ni = 0; ni < 4; ++ni)
#pragma unroll
      for (int r = 0; r < 4; ++r)
        ub[(size_t)(rw + mi * 16 + lg * 4 + r) * 64 + ni * 16 + lr] =
            out[mi][ni][r];
}

// ---------------------------------------------------------------------------
// Scan step s finalize (256 rows), one dispatch per step, grid (4, BH):
//  u = pd*v + sum(up groups);
//  A0=M(4s)u0; u1+=P10[2s]A0; A1=M(4s+1)u1;
//  cross-128 coupling in TWO 64-col halves (Es stays in bounds):
//    for ch in {0,1}: E = exp(Q[hi128] K[base+ch*64..]^T)*zi; u_{2,3} += E @ A_ch;
//  A2=M(4s+2)u2; u3+=P10[2s+1]A2; A3=M(4s+3)u3.
// ---------------------------------------------------------------------------
__global__ __launch_bounds__(256) void k5_fin(
    const short* __restrict__ Qhi, const short* __restrict__ Qlo,
    const short* __restrict__ Khi, const short* __restrict__ Klo,
    const float* __restrict__ V, const float* __restrict__ pd,
    const float* __restrict__ zinv, const float* __restrict__ up,
    const short* __restrict__ Mrh, const short* __restrict__ Mrl,
    const short* __restrict__ P10h, const short* __restrict__ P10l,
    float* __restrict__ Abuf, int s) {
  const int d0 = blockIdx.x * 16;
  const int bh = blockIdx.y;
  const int t = threadIdx.x;
  const int w = t >> 6, l = t & 63;
  const int lr = l & 15, lg = l >> 4;
  const int base = s * 256;
  __shared__ float uT[16][260];     // [dd][r 0..255]
  __shared__ float aT[16][132];     // A0|A1 transposed (A2 reuses [0..63])
  __shared__ float Es[128][68];     // cross-128 coupling probs, 64 cols/half
  const int ng = (2 * s < 7) ? 2 * s : 7;

  // phase 0: uT = pd*v + sum of up groups (this d-quad)
  for (int v = t; v < 1024; v += 256) {
    const int r = v >> 2, f = v & 3;
    const int R = base + r;
    const float4 x = *(const float4*)(V + (((size_t)bh * S + R) << 6) + d0 + f * 4);
    const float p = pd[(size_t)bh * S + R];
    float a0 = p * x.x, a1 = p * x.y, a2 = p * x.z, a3 = p * x.w;
    const int rh = r >> 7, rr = r & 127;
    for (int g = 0; g < ng; ++g) {
      const float4 y = *(const float4*)(
          up + (((size_t)(bh * 7 + g) * 2 + rh) << 13) + (rr << 6) + d0 + f * 4);
      a0 += y.x; a1 += y.y; a2 += y.z; a3 += y.w;
    }
    uT[f * 4 + 0][r] = a0; uT[f * 4 + 1][r] = a1;
    uT[f * 4 + 2][r] = a2; uT[f * 4 + 3][r] = a3;
  }
  __syncthreads();
  const size_t mstep = (size_t)bh * 32 + s * 4;
  // 1: A0 = M(4s) @ u0
  {
    const size_t mb = ((mstep + 0) * 64 + 16 * w + lr) * 64;
    const f32x4 o = apply3(Mrh + mb, Mrl + mb, &uT[lr][0], lg);
#pragma unroll
    for (int i = 0; i < 4; ++i) {
      const int r = 16 * w + lg * 4 + i;
      Abuf[(((size_t)bh * S + base + r) << 6) + d0 + lr] = o[i];
      aT[lr][r] = o[i];
    }
  }
  __syncthreads();
  // 2: u1 += P10[2s] @ A0
  {
    const size_t pb = (((size_t)bh * 16 + 2 * s) * 64 + 16 * w + lr) * 64;
    const f32x4 o = apply3(P10h + pb, P10l + pb, &aT[lr][0], lg);
#pragma unroll
    for (int i = 0; i < 4; ++i)
      uT[lr][64 + 16 * w + lg * 4 + i] += o[i];
  }
  __syncthreads();
  // 3: A1 = M(4s+1) @ u1
  {
    const size_t mb = ((mstep + 1) * 64 + 16 * w + lr) * 64;
    const f32x4 o = apply3(Mrh + mb, Mrl + mb, &uT[lr][64], lg);
#pragma unroll
    for (int i = 0; i < 4; ++i) {
      const int r = 16 * w + lg * 4 + i;
      Abuf[(((size_t)bh * S + base + 64 + r) << 6) + d0 + lr] = o[i];
      aT[lr][64 + r] = o[i];
    }
  }
  // 4+5: cross-128 coupling, two 64-col halves; u_{2,3} += E_ch @ A_ch
  {
    const int rw = 32 * w;
    bf16x8 qh_[2][2], ql_[2][2];
#pragma unroll
    for (int mi = 0; mi < 2; ++mi)
#pragma unroll
      for (int ks = 0; ks < 2; ++ks) {
        const size_t qo = (((size_t)bh * S + base + 128 + rw + mi * 16 + lr) << 6) + ks * 32 + lg * 8;
        qh_[mi][ks] = *(const bf16x8*)(Qhi + qo);
        ql_[mi][ks] = *(const bf16x8*)(Qlo + qo);
      }
    float zv[2][4];
#pragma unroll
    for (int mi = 0; mi < 2; ++mi)
#pragma unroll
      for (int i = 0; i < 4; ++i)
        zv[mi][i] = zinv[(size_t)bh * S + base + 128 + rw + mi * 16 + lg * 4 + i];
    for (int ch = 0; ch < 2; ++ch) {
      __syncthreads();   // aT(ch==0) ready / protect Es from prev half's reads
      f32x4 qk[2][4];
#pragma unroll
      for (int mi = 0; mi < 2; ++mi)
#pragma unroll
        for (int ni = 0; ni < 4; ++ni) qk[mi][ni] = (f32x4)0.f;
#pragma unroll
      for (int ks = 0; ks < 2; ++ks) {
#pragma unroll
        for (int ni = 0; ni < 4; ++ni) {
          const size_t ko = (((size_t)bh * S + base + ch * 64 + ni * 16 + lr) << 6) + ks * 32 + lg * 8;
          const bf16x8 kh8 = *(const bf16x8*)(Khi + ko);
          const bf16x8 kl8 = *(const bf16x8*)(Klo + ko);
#pragma unroll
          for (int mi = 0; mi < 2; ++mi) {
            qk[mi][ni] = __builtin_amdgcn_mfma_f32_16x16x32_bf16(
                qh_[mi][ks], kh8, qk[mi][ni], 0, 0, 0);
            qk[mi][ni] = __builtin_amdgcn_mfma_f32_16x16x32_bf16(
                ql_[mi][ks], kh8, qk[mi][ni], 0, 0, 0);
            qk[mi][ni] = __builtin_amdgcn_mfma_f32_16x16x32_bf16(
                qh_[mi][ks], kl8, qk[mi][ni], 0, 0, 0);
          }
        }
      }
#pragma unroll
      for (int mi = 0; mi < 2; ++mi)
#pragma unroll
        for (int ni = 0; ni < 4; ++ni)
#pragma unroll
          for (int i = 0; i < 4; ++i)
            Es[rw + mi * 16 + lg * 4 + i][ni * 16 + lr] =
                __expf(qk[mi][ni][i]) * zv[mi][i];
      __syncthreads();
#pragma unroll
      for (int mi = 0; mi < 2; ++mi) {
        f32x4 o = (f32x4)0.f;
#pragma unroll
        for (int kq = 0; kq < 2; ++kq) {
          const float* ep = &Es[rw + mi * 16 + lr][kq * 32 + lg * 8];
          bf16x8 eh, el;
          split8(*(const float4*)ep, *(const float4*)(ep + 4), eh, el);
          const float* ap = &aT[lr][ch * 64 + kq * 32 + lg * 8];
          bf16x8 ah, al;
          split8(*(const float4*)ap, *(const float4*)(ap + 4), ah, al);
          o = __builtin_amdgcn_mfma_f32_16x16x32_bf16(eh, ah, o, 0, 0, 0);
          o = __builtin_amdgcn_mfma_f32_16x16x32_bf16(el, ah, o, 0, 0, 0);
          o = __builtin_amdgcn_mfma_f32_16x16x32_bf16(eh, al, o, 0, 0, 0);
        }
#pragma unroll
        for (int i = 0; i < 4; ++i)
          uT[lr][128 + rw + mi * 16 + lg * 4 + i] += o[i];
      }
    }
  }
  __syncthreads();
  // 6: A2 = M(4s+2) @ u2   (aT[0..63] reused for A2)
  {
    const size_t mb = ((mstep + 2) * 64 + 16 * w + lr) * 64;
    const f32x4 o = apply3(Mrh + mb, Mrl + mb, &uT[lr][128], lg);
#pragma unroll
    for (int i = 0; i < 4; ++i) {
      const int r = 16 * w + lg * 4 + i;
      Abuf[(((size_t)bh * S + base + 128 + r) << 6) + d0 + lr] = o[i];
      aT[lr][r] = o[i];
    }
  }
  __syncthreads();
  // 7: u3 += P10[2s+1] @ A2
  {
    const size_t pb = (((size_t)bh * 16 + 2 * s + 1) * 64 + 16 * w + lr) * 64;
    const f32x4 o = apply3(P10h + pb, P10l + pb, &aT[lr][0], lg);
#pragma unroll
    for (int i = 0; i < 4; ++i)
      uT[lr][192 + 16 * w + lg * 4 + i] += o[i];
  }
  __syncthreads();
  // 8: A3 = M(4s+3) @ u3
  {
    const size_t mb = ((mstep + 3) * 64 + 16 * w + lr) * 64;
    const f32x4 o = apply3(Mrh + mb, Mrl + mb, &uT[lr][192], lg);
#pragma unroll
    for (int i = 0; i < 4; ++i) {
      const int r = 16 * w + lg * 4 + i;
      Abuf[(((size_t)bh * S + base + 192 + r) << 6) + d0 + lr] = o[i];
    }
  }
}

} // namespace

extern "C" void kernel_launch(void* const* d_in, const int* in_sizes, int n_in,
                              void* d_out, int out_size, void* d_ws, size_t ws_size,
                              hipStream_t stream) {
  const float* hs   = (const float*)d_in[0];
  const float* Wqkv = (const float*)d_in[1];
  const float* bqkv = (const float*)d_in[2];
  const float* Wd   = (const float*)d_in[3];
  const float* bd   = (const float*)d_in[4];
  float* out = (float*)d_out;
  float* W   = (float*)d_ws;
  if (ws_size < WS_FLOATS * sizeof(float)) return;  // insufficient scratch

  float* qkv   = W;               // bytes 0..50.3MB (dead after rope)
  float* partZ = W;               // transient (scores->reduce)
  float* Abuf  = W + OFF_A;
  short* Qhi   = (short*)(W + OFF_Q);
  short* Qlo   = Qhi + 4194304;
  short* Khi   = (short*)(W + OFF_K);
  short* Klo   = Khi + 4194304;
  float* Vb    = W + OFF_V;
  float* zi    = W + OFF_ZI;
  float* pdg   = W + OFF_PD;
  float* up    = W + OFF_UP;

  char* wsb = (char*)d_ws;
  short* Ahi  = (short*)(wsb + 50331648);      // pre-rope: Q region
  short* Alo  = Ahi + 4194304;
  short* Whi  = (short*)(wsb + 67108864);      // pre-rope: K region
  short* Wlo  = Whi + 3145728;
  short* A2hi = (short*)(wsb + 50331648);      // post-scan: Q region
  short* A2lo = A2hi + 4194304;
  short* Wdhi = (short*)(wsb + 67108864);
  short* Wdlo = Wdhi + 1048576;
  // scan-phase operands in the dead qkv region (bytes 0..16.78MB)
  short* P10h = (short*)(wsb);                 // 0..4.2MB
  short* P10l = P10h + 2097152;                // 4.2..8.4MB
  short* Mrh  = (short*)(wsb + 33554432);      // 33.5..41.9MB
  short* Mrl  = Mrh + 4194304;                 // 41.9..50.3MB

  split_pre<<<dim3(2048), 256, 0, stream>>>(hs, Ahi, Alo, Wqkv, Whi, Wlo);
  gemm_bf3<<<dim3(24, 32), 256, 0, stream>>>(Ahi, Alo, Whi, Wlo, bqkv, qkv,
                                             B*S, 3*HID, HID);
  k2_rope<<<dim3(BH * S / 256), 256, 0, stream>>>(qkv, Qhi, Qlo, Khi, Klo, Vb);
  k3_scores<<<dim3(16, 16, BH), 256, 0, stream>>>(Qhi, Qlo, Khi, Klo, partZ, pdg);
  k3_reduce<<<dim3(BH * S / 256), 256, 0, stream>>>(partZ, zi, pdg);
  k4_minv<<<dim3(S / 64, BH), 256, 0, stream>>>(Qhi, Qlo, Khi, Klo, zi,
                                                Mrh, Mrl, P10h, P10l);
  for (int s = 0; s < NSTEP2; ++s) {
    if (s > 0) {
      const int ng = (2 * s < 7) ? 2 * s : 7;
      k5_acc<<<dim3(ng, 2, BH), 256, 0, stream>>>(Qhi, Qlo, Khi, Klo, Abuf, zi,
                                                  up, s);
    }
    k5_fin<<<dim3(4, BH), 256, 0, stream>>>(Qhi, Qlo, Khi, Klo, Vb, pdg, zi, up,
                                            Mrh, Mrl, P10h, P10l, Abuf, s);
  }
  split_post<<<dim3(2048), 256, 0, stream>>>(Abuf, A2hi, A2lo, Wd, Wdhi, Wdlo);
  gemm_bf3<<<dim3(8, 32), 256, 0, stream>>>(A2hi, A2lo, Wdhi, Wdlo, bd, out,
                                            B*S, HID, HID);
}